// Round 16
// baseline (753.228 us; speedup 1.0000x reference)
//
#include <hip/hip_runtime.h>
#include <math.h>

// PNA-EGNN forward, MI355X, round 16:
//  - bondcomp: 2 edge-tiles (256 edges) per block, B panel staged ONCE per block.
//    Grid 1000 (200 bond + 800 comp). Doubles block lifetime -> sustained ~4
//    blocks/CU residency; halves panel staging. Same 512-thr (512,4) shape.
//  - post-GEMM split-K=3 + fused reduce (r13); h bf16 planes (r9); fusion (r15).
// hcat agg plane stored as bf16-hi ushort [12800][1024]: [aggB(512)|aggC(512)].

#define N_NODES 12800
#define GRAPHS 128

typedef __attribute__((ext_vector_type(8))) short short8;
typedef __attribute__((ext_vector_type(4))) float f32x4;
#define MFMA16(a, b, c) __builtin_amdgcn_mfma_f32_16x16x32_bf16(a, b, c, 0, 0, 0)

static __device__ __forceinline__ float relu_f(float v) { return v > 0.0f ? v : 0.0f; }

static __device__ __forceinline__ unsigned short bf16rn(float x) {
  union { float f; unsigned u; } a; a.f = x;
  return (unsigned short)((a.u + 0x7fffu + ((a.u >> 16) & 1u)) >> 16);
}
static __device__ __forceinline__ float bf16tof(unsigned short h) {
  union { unsigned u; float f; } a; a.u = ((unsigned)h) << 16;
  return a.f;
}
static __device__ __forceinline__ void cvt_hl(float x, unsigned short& h, unsigned short& l) {
  h = bf16rn(x);
  l = bf16rn(x - bf16tof(h));
}

// packed 2xbf16 conversion: v_cvt_pk_bf16_f32 (no builtin on gfx950 -> inline asm)
static __device__ __forceinline__ unsigned pk2(float a, float b) {
  unsigned r;
  asm("v_cvt_pk_bf16_f32 %0, %1, %2" : "=v"(r) : "v"(a), "v"(b));
  return r;
}
static __device__ __forceinline__ float pk_lo_f(unsigned p) {
  union { unsigned u; float f; } a; a.u = p << 16; return a.f;
}
static __device__ __forceinline__ float pk_hi_f(unsigned p) {
  union { unsigned u; float f; } a; a.u = p & 0xffff0000u; return a.f;
}
// float4 -> hi-plane uint2 (4 bf16) + lo-plane uint2 (residuals)
static __device__ __forceinline__ void cvt4(float4 v, uint2& h, uint2& l) {
  h.x = pk2(v.x, v.y);
  h.y = pk2(v.z, v.w);
  l.x = pk2(v.x - pk_lo_f(h.x), v.y - pk_hi_f(h.x));
  l.y = pk2(v.z - pk_lo_f(h.y), v.w - pk_hi_f(h.y));
}

union U16 {
  uint4 u4;
  uint2 u2[2];
  short8 s8;
};
static __device__ __forceinline__ short8 mk_s8(uint2 a, uint2 b) {
  U16 t; t.u2[0] = a; t.u2[1] = b; return t.s8;
}
static __device__ __forceinline__ short8 ld_s8(const uint4* p) {
  U16 t; t.u4 = *p; return t.s8;
}

// Stage 128x128 ushort hi-plane into fragment-major LDS (2048 uint4 slots = 32KB):
// slot = (ni*4+kb)*64 + quad*16 + l15
template <int NT>
static __device__ __forceinline__ void stage_Bh(
    const unsigned short* __restrict__ Wh, uint4* __restrict__ Bf, int tid) {
  uint4 tmp[2048 / NT];
#pragma unroll
  for (int i = 0; i < 2048 / NT; ++i) {
    int slot = tid + i * NT;
    int l15n = slot & 15;
    int quad_s = (slot >> 4) & 3;
    int kbni = slot >> 6;
    int kb_s = kbni & 3;
    int ni_s = kbni >> 2;
    int n = ni_s * 16 + l15n;
    int k8 = kb_s * 4 + quad_s;
    tmp[i] = *(const uint4*)&Wh[n * 128 + k8 * 8];
  }
#pragma unroll
  for (int i = 0; i < 2048 / NT; ++i) Bf[tid + i * NT] = tmp[i];
}

// ---------------- fp32 [12800][128] -> bf16 hi/lo planes ------------------------------
__global__ __launch_bounds__(256) void h2planes(
    const float* __restrict__ X, unsigned short* __restrict__ Yh,
    unsigned short* __restrict__ Yl) {
  int idx = blockIdx.x * 256 + threadIdx.x;  // 409600 float4s
  float4 v = *(const float4*)&X[(size_t)idx * 4];
  uint2 h, l;
  cvt4(v, h, l);
  *(uint2*)&Yh[(size_t)idx * 4] = h;
  *(uint2*)&Yl[(size_t)idx * 4] = l;
}

// ---------------- split-K reduce: Y = p0+p1+p2 + bias + resid; planes out -------------
__global__ __launch_bounds__(256) void ksplit_reduce(
    const float* __restrict__ p, const float* __restrict__ bias,
    const float* __restrict__ resid, float* __restrict__ Y,
    unsigned short* __restrict__ Yh, unsigned short* __restrict__ Yl) {
  int idx = blockIdx.x * 256 + threadIdx.x;  // 409600 float4s
  const float4* p4 = (const float4*)p;
  float4 a = p4[idx];
  float4 b = p4[idx + 409600];
  float4 c = p4[idx + 819200];
  float4 rr = *(const float4*)&resid[(size_t)idx * 4];
  float4 bb = *(const float4*)&bias[(idx & 31) * 4];
  float4 v;
  v.x = a.x + b.x + c.x + rr.x + bb.x;
  v.y = a.y + b.y + c.y + rr.y + bb.y;
  v.z = a.z + b.z + c.z + rr.z + bb.z;
  v.w = a.w + b.w + c.w + rr.w + bb.w;
  *(float4*)&Y[(size_t)idx * 4] = v;
  uint2 h, l;
  cvt4(v, h, l);
  ((uint2*)Yh)[idx] = h;
  ((uint2*)Yl)[idx] = l;
}

// ---------------- edge input projection, tiled: Yh = bf16hi(relu(X@W + b)) ------------
// X [51200][16], W [16][128]. 32 rows/block, 16 outputs/thread, K=16 unrolled.
__global__ __launch_bounds__(256) void edge_proj_kernel(
    const float* __restrict__ X, const float* __restrict__ W,
    const float* __restrict__ bias, unsigned short* __restrict__ Yh) {
  __shared__ float Xs[32][17];
  __shared__ float Ws[16][128];
  int tid = threadIdx.x;
  int row0 = blockIdx.x * 32;
  for (int i = tid; i < 512; i += 256) {
    int r = i >> 4, k = i & 15;
    Xs[r][k] = X[(size_t)(row0 + r) * 16 + k];
  }
  for (int i = tid; i < 2048; i += 256) Ws[i >> 7][i & 127] = W[i];
  __syncthreads();
  int rg = tid >> 5;         // 4 rows each
  int c0 = (tid & 31) * 4;   // 4 cols
  float bj0 = bias[c0], bj1 = bias[c0 + 1], bj2 = bias[c0 + 2], bj3 = bias[c0 + 3];
#pragma unroll
  for (int rr = 0; rr < 4; ++rr) {
    int r = rg * 4 + rr;
    float a0 = bj0, a1 = bj1, a2 = bj2, a3 = bj3;
#pragma unroll
    for (int k = 0; k < 16; ++k) {
      float x = Xs[r][k];
      float4 w = *(const float4*)&Ws[k][c0];
      a0 += x * w.x; a1 += x * w.y; a2 += x * w.z; a3 += x * w.w;
    }
    uint2 h;
    h.x = pk2(relu_f(a0), relu_f(a1));
    h.y = pk2(relu_f(a2), relu_f(a3));
    *(uint2*)&Yh[(size_t)(row0 + r) * 128 + c0] = h;
  }
}

// ---------------- per-layer hproj bias: [5][512] = [0 | pre_b | 0 | pc_b1] ------------
__global__ __launch_bounds__(256) void bias_kernel(
    const float* __restrict__ pre_b, const float* __restrict__ pc_b1,
    float* __restrict__ biasf) {
  int idx = blockIdx.x * 256 + threadIdx.x;  // 2560
  if (idx >= 2560) return;
  int l = idx >> 9, c = idx & 511;
  float v = 0.f;
  if (c >= 128 && c < 256) v = pre_b[l * 128 + (c - 128)];
  else if (c >= 384) v = pc_b1[l * 128 + (c - 384)];
  biasf[idx] = v;
}

// ---------------- weight prep: fold scalers + transpose + hi/lo split -----------
// ushort plane offsets (per layer stride 491520):
//  hprojT_hi 0 / lo 65536           [512][128]
//  WcT_hi 131072 / lo 147456        [128][128]
//  W2T_hi 163840 / lo 180224        [128][128]
//  WfoldT_hi 196608 / lo 344064     [128][1152]
//  outn1T_hi 2457600 / lo 2473984; outn2T_hi 2490368 / lo 2506752
__global__ __launch_bounds__(256) void fold_kernel(
    const float* __restrict__ pre_W, const float* __restrict__ pc_W1,
    const float* __restrict__ pc_W2, const float* __restrict__ post_W,
    const float* __restrict__ outn_W1, const float* __restrict__ outn_W2,
    unsigned short* __restrict__ wb) {
  int idx = blockIdx.x * 256 + threadIdx.x;  // 1,261,568 total
  const float C1 = 1.6094379124341003f;   // log 5
  const float C2 = 2.8332133440562162f;   // log 17
  float val;
  size_t ohi, olo;
  if (idx < 1228800) {
    int l = idx / 245760;
    int r = idx % 245760;
    size_t lb = (size_t)l * 491520;
    if (r < 65536) {  // hprojT [n=512][k=128]
      int n = r >> 7, k = r & 127;
      if (n < 128) val = pre_W[(size_t)l * 49152 + k * 128 + n];
      else if (n < 256) val = pre_W[(size_t)l * 49152 + (128 + k) * 128 + (n - 128)];
      else if (n < 384) val = pc_W1[(size_t)l * 32768 + k * 128 + (n - 256)];
      else val = pc_W1[(size_t)l * 32768 + (128 + k) * 128 + (n - 384)];
      ohi = lb + r; olo = ohi + 65536;
    } else if (r < 81920) {  // WcT
      int r2 = r - 65536; int n = r2 >> 7, k = r2 & 127;
      val = pre_W[(size_t)l * 49152 + (256 + k) * 128 + n];
      ohi = lb + 131072 + r2; olo = ohi + 16384;
    } else if (r < 98304) {  // W2T
      int r2 = r - 81920; int n = r2 >> 7, k = r2 & 127;
      val = pc_W2[(size_t)l * 16384 + k * 128 + n];
      ohi = lb + 163840 + r2; olo = ohi + 16384;
    } else {  // WfoldT [n=128][kk=1152]
      int r2 = r - 98304;
      int n = r2 / 1152, kk = r2 % 1152;
      const float* Wl = post_W + (size_t)l * 409600;
      if (kk < 128) val = Wl[kk * 128 + n];
      else if (kk < 640) {
        int j = kk - 128;
        val = Wl[(128 + j) * 128 + n] + C1 * Wl[(640 + j) * 128 + n] +
              (1.0f / C1) * Wl[(1152 + j) * 128 + n];
      } else {
        int j = kk - 640;
        val = Wl[(1664 + j) * 128 + n] + C2 * Wl[(2176 + j) * 128 + n] +
              (1.0f / C2) * Wl[(2688 + j) * 128 + n];
      }
      ohi = lb + 196608 + r2; olo = ohi + 147456;
    }
  } else {
    int r = idx - 1228800;
    if (r < 16384) {
      int n = r >> 7, k = r & 127;
      val = outn_W1[k * 128 + n];
      ohi = 2457600 + r; olo = ohi + 16384;
    } else {
      int r2 = r - 16384; int n = r2 >> 7, k = r2 & 127;
      val = outn_W2[k * 128 + n];
      ohi = 2490368 + r2; olo = ohi + 16384;
    }
  }
  unsigned short h, l2;
  cvt_hl(val, h, l2);
  wb[ohi] = h;
  wb[olo] = l2;
}

// ---------------- dense MFMA GEMM: Y[M,ntot] = X @ Wt^T (+bias)(+resid)(relu) ---------
// 256 threads / 4 waves; wave w owns cols [w*32, w*32+32).
// AMODE 0: A from fp32 X0 (cvt4).  AMODE 1: A from hi/lo planes.
// AMODE 2: k<K0 from hi/lo planes, k>=K0 from X1h (hi only).
// WPLANES: epilogue also emits Y as bf16 hi/lo planes (stride 128).
// KSPLIT>1: blockIdx.y = k-chunk; writes raw fp32 partials (no bias/resid/planes).
template <int BM, int AMODE, bool RELU, bool RESID, bool WPLANES, int KSPLIT>
__global__ __launch_bounds__(256) void mgemm(
    const float* __restrict__ X0, int xs0,
    const unsigned short* __restrict__ Ah, const unsigned short* __restrict__ Al,
    int ahs, int K0,
    const unsigned short* __restrict__ X1h, int xs1,
    const unsigned short* __restrict__ Wth, const unsigned short* __restrict__ Wtl,
    const float* __restrict__ bias, const float* __restrict__ resid, int rstride,
    float* __restrict__ Y, int ystride,
    unsigned short* __restrict__ Yh, unsigned short* __restrict__ Yl, int K) {
  __shared__ unsigned short As_h[BM][40], As_l[BM][40];
  __shared__ unsigned short Bs_h[128][40], Bs_l[128][40];
  int tid = threadIdx.x;
  int wave = tid >> 6, lane = tid & 63, quad = lane >> 4, l15 = lane & 15;
  int row0 = blockIdx.x * BM;
  int n0, kbeg, kend;
  float* Yout = Y;
  if (KSPLIT > 1) {
    n0 = 0;
    int kc = K / KSPLIT;
    kbeg = blockIdx.y * kc;
    kend = kbeg + kc;
    Yout = Y + (size_t)blockIdx.y * N_NODES * 128;
  } else {
    n0 = blockIdx.y * 128;
    kbeg = 0;
    kend = K;
  }
  f32x4 acc[BM / 16][2];
#pragma unroll
  for (int mi = 0; mi < BM / 16; ++mi)
#pragma unroll
    for (int ni = 0; ni < 2; ++ni) acc[mi][ni] = (f32x4){0.f, 0.f, 0.f, 0.f};
  for (int kb = kbeg; kb < kend; kb += 32) {
    if (kb != kbeg) __syncthreads();
    bool haslo = (AMODE != 2) || (kb < K0);
    if (AMODE == 0) {
      for (int i = tid; i < BM * 8; i += 256) {
        int r = i >> 3, kq = i & 7;
        float4 v = *(const float4*)&X0[(size_t)(row0 + r) * xs0 + kb + kq * 4];
        uint2 th, tl;
        cvt4(v, th, tl);
        *(uint2*)&As_h[r][kq * 4] = th;
        *(uint2*)&As_l[r][kq * 4] = tl;
      }
    } else if (haslo) {
      for (int i = tid; i < BM * 4; i += 256) {
        int r = i >> 2, q = i & 3;
        size_t o = (size_t)(row0 + r) * ahs + kb + q * 8;
        *(uint4*)&As_h[r][q * 8] = *(const uint4*)&Ah[o];
        *(uint4*)&As_l[r][q * 8] = *(const uint4*)&Al[o];
      }
    } else {
      for (int i = tid; i < BM * 4; i += 256) {
        int r = i >> 2, q = i & 3;
        *(uint4*)&As_h[r][q * 8] =
            *(const uint4*)&X1h[(size_t)(row0 + r) * xs1 + (kb - K0) + q * 8];
      }
    }
    for (int i = tid; i < 512; i += 256) {
      int r = i >> 2, q = i & 3;
      size_t o = (size_t)(n0 + r) * K + kb + q * 8;
      *(uint4*)&Bs_h[r][q * 8] = *(const uint4*)&Wth[o];
      *(uint4*)&Bs_l[r][q * 8] = *(const uint4*)&Wtl[o];
    }
    __syncthreads();
    short8 bh[2], bl[2], ah[BM / 16], al[BM / 16];
#pragma unroll
    for (int ni = 0; ni < 2; ++ni) {
      bh[ni] = *(const short8*)&Bs_h[wave * 32 + ni * 16 + l15][quad * 8];
      bl[ni] = *(const short8*)&Bs_l[wave * 32 + ni * 16 + l15][quad * 8];
    }
#pragma unroll
    for (int mi = 0; mi < BM / 16; ++mi)
      ah[mi] = *(const short8*)&As_h[mi * 16 + l15][quad * 8];
    if (haslo) {
#pragma unroll
      for (int mi = 0; mi < BM / 16; ++mi)
        al[mi] = *(const short8*)&As_l[mi * 16 + l15][quad * 8];
    }
#pragma unroll
    for (int mi = 0; mi < BM / 16; ++mi)
#pragma unroll
      for (int ni = 0; ni < 2; ++ni) {
        acc[mi][ni] = MFMA16(ah[mi], bh[ni], acc[mi][ni]);
        acc[mi][ni] = MFMA16(ah[mi], bl[ni], acc[mi][ni]);
      }
    if (haslo) {
#pragma unroll
      for (int mi = 0; mi < BM / 16; ++mi)
#pragma unroll
        for (int ni = 0; ni < 2; ++ni)
          acc[mi][ni] = MFMA16(al[mi], bh[ni], acc[mi][ni]);
    }
  }
#pragma unroll
  for (int mi = 0; mi < BM / 16; ++mi)
#pragma unroll
    for (int ni = 0; ni < 2; ++ni) {
      int col = n0 + wave * 32 + ni * 16 + l15;
      if (KSPLIT > 1) {
#pragma unroll
        for (int r = 0; r < 4; ++r) {
          int row = row0 + mi * 16 + quad * 4 + r;
          Yout[(size_t)row * ystride + col] = acc[mi][ni][r];
        }
      } else {
        float bj = bias ? bias[col] : 0.f;
#pragma unroll
        for (int r = 0; r < 4; ++r) {
          int row = row0 + mi * 16 + quad * 4 + r;
          float v = acc[mi][ni][r] + bj;
          if (RESID) v += resid[(size_t)row * rstride + col];
          if (RELU) v = relu_f(v);
          Y[(size_t)row * ystride + col] = v;
          if (WPLANES) {
            unsigned short hh, ll;
            cvt_hl(v, hh, ll);
            Yh[(size_t)row * 128 + col] = hh;
            Yl[(size_t)row * 128 + col] = ll;
          }
        }
      }
    }
}

// ---------------- fused bond+comp: 1000 blocks x 2 edge-tiles -------------------------
// Blocks [0,200): bond path (256 bond edges each). Blocks [200,1000): comp path
// (256 comp edges each). Both: 512 thr / 8 waves x 16 edges/tile, B-hi panel staged
// ONCE into 32KB fragment-major LDS, then 2 tiles processed (A in regs per tile).
#define BOND_BLOCKS 200
__global__ __launch_bounds__(512, 4) void bondcomp_mfma(
    const unsigned short* __restrict__ efph,
    const float* __restrict__ hproj,
    const unsigned short* __restrict__ Wch, const unsigned short* __restrict__ W2h,
    const float* __restrict__ b2,
    const float* __restrict__ seW, const float* __restrict__ seb,
    const int* __restrict__ bond_src, const int* __restrict__ comp_src,
    unsigned short* __restrict__ aggp) {
  __shared__ uint4 Bf[2048];  // 32KB fragment-major B hi
  int tid = threadIdx.x;
  int wave = tid >> 6, lane = tid & 63, quad = lane >> 4, l15 = lane & 15;
  if (blockIdx.x < BOND_BLOCKS) {
    // ---------------- bond path: 2 tiles of 128 edges ----------------
    stage_Bh<512>(Wch, Bf, tid);
    __syncthreads();
    for (int t = 0; t < 2; ++t) {
      int ew = blockIdx.x * 256 + t * 128 + wave * 16;
      short8 ah[4];
#pragma unroll
      for (int kb = 0; kb < 4; ++kb) {
        size_t o = (size_t)(ew + l15) * 128 + kb * 32 + quad * 8;
        ah[kb] = ld_s8((const uint4*)&efph[o]);
      }
      f32x4 acc[8];
#pragma unroll
      for (int ni = 0; ni < 8; ++ni) acc[ni] = (f32x4){0.f, 0.f, 0.f, 0.f};
#pragma unroll
      for (int kb = 0; kb < 4; ++kb) {
#pragma unroll
        for (int ni = 0; ni < 8; ++ni) {
          short8 bh = ld_s8(&Bf[(ni * 4 + kb) * 64 + lane]);
          acc[ni] = MFMA16(ah[kb], bh, acc[ni]);
        }
      }
      int node = (ew >> 2) + quad;
      int src_r[4];
#pragma unroll
      for (int r = 0; r < 4; ++r) src_r[r] = bond_src[ew + quad * 4 + r];
#pragma unroll
      for (int ni = 0; ni < 8; ++ni) {
        int c = ni * 16 + l15;
        float wbv = hproj[(size_t)node * 512 + 128 + c];  // includes pre_b
        float s = 0.f, sq = 0.f, mx = -1e30f, mn = 1e30f;
#pragma unroll
        for (int r = 0; r < 4; ++r) {
          float v = acc[ni][r] + wbv + hproj[(size_t)src_r[r] * 512 + c];
          s += v; sq += v * v; mx = fmaxf(mx, v); mn = fminf(mn, v);
        }
        float mean = s * 0.25f;
        float var = relu_f(sq * 0.25f - mean * mean);
        size_t base = (size_t)node * 1024 + c;
        aggp[base] = bf16rn(mean);
        aggp[base + 128] = bf16rn(mx);
        aggp[base + 256] = bf16rn(mn);
        aggp[base + 384] = bf16rn(sqrtf(var + 1e-5f));
      }
    }
  } else {
    // ---------------- comp path: 2 tiles of 128 edges ----------------
    stage_Bh<512>(W2h, Bf, tid);
    __syncthreads();
    float b2v[8], swv[8];
#pragma unroll
    for (int ni = 0; ni < 8; ++ni) {
      int c = ni * 16 + l15;
      b2v[ni] = b2[c];
      swv[ni] = seW[c];
    }
    float seb0 = seb[0];
    for (int t = 0; t < 2; ++t) {
      int e = (blockIdx.x - BOND_BLOCKS) * 256 + t * 128 + wave * 16 + l15;
      int src = comp_src[e];
      int node = e >> 4;  // same node for whole wave
      const float* pa = hproj + (size_t)src * 512 + 256;
      const float* pb = hproj + (size_t)node * 512 + 384;
      short8 ah[4];
#pragma unroll
      for (int kb = 0; kb < 4; ++kb) {
        int k0 = kb * 32 + quad * 8;
        float4 va0 = *(const float4*)&pa[k0], va1 = *(const float4*)&pa[k0 + 4];
        float4 vb0 = *(const float4*)&pb[k0], vb1 = *(const float4*)&pb[k0 + 4];
        uint2 h0, h1;
        h0.x = pk2(relu_f(va0.x + vb0.x), relu_f(va0.y + vb0.y));
        h0.y = pk2(relu_f(va0.z + vb0.z), relu_f(va0.w + vb0.w));
        h1.x = pk2(relu_f(va1.x + vb1.x), relu_f(va1.y + vb1.y));
        h1.y = pk2(relu_f(va1.z + vb1.z), relu_f(va1.w + vb1.w));
        ah[kb] = mk_s8(h0, h1);
      }
      f32x4 acc[8];
#pragma unroll
      for (int ni = 0; ni < 8; ++ni) acc[ni] = (f32x4){0.f, 0.f, 0.f, 0.f};
#pragma unroll
      for (int kb = 0; kb < 4; ++kb) {
#pragma unroll
        for (int ni = 0; ni < 8; ++ni) {
          short8 bh = ld_s8(&Bf[(ni * 4 + kb) * 64 + lane]);
          acc[ni] = MFMA16(ah[kb], bh, acc[ni]);
        }
      }
      float gate[4];
#pragma unroll
      for (int r = 0; r < 4; ++r) {
        float p = 0.f;
#pragma unroll
        for (int ni = 0; ni < 8; ++ni) p += (acc[ni][r] + b2v[ni]) * swv[ni];
        p += __shfl_xor(p, 1, 64);
        p += __shfl_xor(p, 2, 64);
        p += __shfl_xor(p, 4, 64);
        p += __shfl_xor(p, 8, 64);
        gate[r] = 1.f / (1.f + expf(-(p + seb0)));
      }
#pragma unroll
      for (int ni = 0; ni < 8; ++ni) {
        float s = 0.f, sq = 0.f, mx = -1e30f, mn = 1e30f;
#pragma unroll
        for (int r = 0; r < 4; ++r) {
          float v = (acc[ni][r] + b2v[ni]) * gate[r];
          s += v; sq += v * v; mx = fmaxf(mx, v); mn = fminf(mn, v);
        }
        s += __shfl_xor(s, 16, 64); sq += __shfl_xor(sq, 16, 64);
        mx = fmaxf(mx, __shfl_xor(mx, 16, 64)); mn = fminf(mn, __shfl_xor(mn, 16, 64));
        s += __shfl_xor(s, 32, 64); sq += __shfl_xor(sq, 32, 64);
        mx = fmaxf(mx, __shfl_xor(mx, 32, 64)); mn = fminf(mn, __shfl_xor(mn, 32, 64));
        if (quad == 0) {
          int c = ni * 16 + l15;
          float mean = s * 0.0625f;
          float var = relu_f(sq * 0.0625f - mean * mean);
          size_t base = (size_t)node * 1024 + 512 + c;
          aggp[base] = bf16rn(mean);
          aggp[base + 128] = bf16rn(mx);
          aggp[base + 256] = bf16rn(mn);
          aggp[base + 384] = bf16rn(sqrtf(var + 1e-5f));
        }
      }
    }
  }
}

// ---------------- vector GEMM (readout MLP + node input projection) -------------------
template <bool RELU, bool RESID>
__global__ __launch_bounds__(256) void gemm_rrr(
    const float* __restrict__ X, int xstride, const float* __restrict__ W,
    const float* __restrict__ bias, const float* __restrict__ resid, int rstride,
    float* __restrict__ Y, int ystride, int Ktot) {
  __shared__ __align__(16) float Xs[32][68];
  __shared__ __align__(16) float Ws[64][128];
  int tid = threadIdx.x;
  int row0 = blockIdx.x * 32;
  int rg = tid >> 5;
  int c0 = (tid & 31) * 4;
  float acc[4][4] = {};
  for (int kb = 0; kb < Ktot; kb += 64) {
    __syncthreads();
    for (int i = tid; i < 32 * 64; i += 256) {
      int r = i >> 6, k = i & 63;
      Xs[r][k] = X[(size_t)(row0 + r) * xstride + kb + k];
    }
    for (int i = tid; i < 64 * 128; i += 256) {
      int k = i >> 7, c = i & 127;
      Ws[k][c] = W[(size_t)(kb + k) * 128 + c];
    }
    __syncthreads();
#pragma unroll
    for (int k4 = 0; k4 < 16; ++k4) {
      float4 w0 = *(const float4*)&Ws[k4 * 4 + 0][c0];
      float4 w1 = *(const float4*)&Ws[k4 * 4 + 1][c0];
      float4 w2 = *(const float4*)&Ws[k4 * 4 + 2][c0];
      float4 w3 = *(const float4*)&Ws[k4 * 4 + 3][c0];
#pragma unroll
      for (int r = 0; r < 4; ++r) {
        float4 x = *(const float4*)&Xs[rg * 4 + r][k4 * 4];
        acc[r][0] += x.x * w0.x + x.y * w1.x + x.z * w2.x + x.w * w3.x;
        acc[r][1] += x.x * w0.y + x.y * w1.y + x.z * w2.y + x.w * w3.y;
        acc[r][2] += x.x * w0.z + x.y * w1.z + x.z * w2.z + x.w * w3.z;
        acc[r][3] += x.x * w0.w + x.y * w1.w + x.z * w2.w + x.w * w3.w;
      }
    }
  }
  float bj[4] = {0.f, 0.f, 0.f, 0.f};
  if (bias) {
    bj[0] = bias[c0]; bj[1] = bias[c0 + 1]; bj[2] = bias[c0 + 2]; bj[3] = bias[c0 + 3];
  }
#pragma unroll
  for (int r = 0; r < 4; ++r) {
    int row = row0 + rg * 4 + r;
    float4 o;
    float* po = &o.x;
#pragma unroll
    for (int j = 0; j < 4; ++j) {
      float v = acc[r][j] + bj[j];
      if (RESID) v += resid[(size_t)row * rstride + c0 + j];
      if (RELU) v = relu_f(v);
      po[j] = v;
    }
    *(float4*)&Y[(size_t)row * ystride + c0] = o;
  }
}

// ---------------- readout + final ----------------------------------------------------
__global__ __launch_bounds__(128) void readout_kernel(const float* __restrict__ nodeout,
                                                      float* __restrict__ r) {
  int g = blockIdx.x, c = threadIdx.x;
  float s = 0.f, mx = -1e30f;
  for (int i = 0; i < 100; ++i) {
    float v = nodeout[(size_t)(g * 100 + i) * 128 + c];
    s += v; mx = fmaxf(mx, v);
  }
  r[g * 384 + c] = s;
  r[g * 384 + 128 + c] = s * 0.01f;
  r[g * 384 + 256 + c] = mx;
}

__global__ __launch_bounds__(256) void final_kernel(const float* __restrict__ roh,
                                                    const float* __restrict__ W2,
                                                    const float* __restrict__ b2,
                                                    float* __restrict__ out) {
  int idx = blockIdx.x * 256 + threadIdx.x;  // 4096
  int g = idx >> 5, c = idx & 31;
  float acc = b2[c];
  for (int k = 0; k < 128; ++k) acc += roh[g * 128 + k] * W2[k * 32 + c];
  out[idx] = acc;
}

extern "C" void kernel_launch(void* const* d_in, const int* in_sizes, int n_in,
                              void* d_out, int out_size, void* d_ws, size_t ws_size,
                              hipStream_t stream) {
  const float* node_feat = (const float*)d_in[0];
  const float* edge_feat = (const float*)d_in[1];
  const int* bond_src = (const int*)d_in[2];
  const int* comp_src = (const int*)d_in[4];
  const float* in_W = (const float*)d_in[7];
  const float* in_b = (const float*)d_in[8];
  const float* ein_W = (const float*)d_in[9];
  const float* ein_b = (const float*)d_in[10];
  const float* pre_W = (const float*)d_in[11];
  const float* pre_b = (const float*)d_in[12];
  const float* pc_W1 = (const float*)d_in[13];
  const float* pc_b1 = (const float*)d_in[14];
  const float* pc_W2 = (const float*)d_in[15];
  const float* pc_b2 = (const float*)d_in[16];
  const float* se_W = (const float*)d_in[17];
  const float* se_b = (const float*)d_in[18];
  const float* post_W = (const float*)d_in[19];
  const float* post_b = (const float*)d_in[20];
  const float* outn_W1 = (const float*)d_in[21];
  const float* outn_b1 = (const float*)d_in[22];
  const float* outn_W2 = (const float*)d_in[23];
  const float* outn_b2 = (const float*)d_in[24];
  const float* ro_W1 = (const float*)d_in[25];
  const float* ro_b1 = (const float*)d_in[26];
  const float* ro_W2 = (const float*)d_in[27];
  const float* ro_b2 = (const float*)d_in[28];

  float* ws = (float*)d_ws;
  float* hbuf = ws;                                    // 1,638,400
  float* hnew = ws + 1638400;                          // 1,638,400
  unsigned short* hcatp = (unsigned short*)(ws + 3276800);  // [12800][1024] ushort
  unsigned short* efph = (unsigned short*)(ws + 9830400);   // [51200][128] ushort
  float* hproj = ws + 16384000;                        // 6,553,600  [12800][512]
                                                       //   (also split-K partials:
                                                       //    3 x 1,638,400 fp32)
  unsigned short* wb = (unsigned short*)(ws + 22937600);    // 2,523,136 ushort
  float* tmp1 = ws + 24199168;                         // 1,638,400 (planesA in layers;
                                                       //   outn stage after)
  float* nodeout = ws + 25837568;                      // 1,638,400 (planesB in layers)
  float* rbuf = ws + 27475968;                         // 49,152 (biasf in layers)
  float* roh = ws + 27525120;                          // 16,384
  float* biasf = rbuf;                                 // [5][512] during layer loop only
  float* partials = hproj;                             // hproj dead when post runs
  unsigned short* pAh = (unsigned short*)tmp1;         // [12800][128]
  unsigned short* pAl = pAh + 1638400;
  unsigned short* pBh = (unsigned short*)nodeout;
  unsigned short* pBl = pBh + 1638400;

  // node proj: tiled vector GEMM, then split to bf16 hi/lo planes
  gemm_rrr<true, false><<<400, 256, 0, stream>>>(node_feat, 64, in_W, in_b, nullptr, 0,
                                                 hbuf, 128, 64);
  h2planes<<<1600, 256, 0, stream>>>(hbuf, pAh, pAl);
  // edge proj: tiled, K=16 unrolled, bf16 hi plane only
  edge_proj_kernel<<<1600, 256, 0, stream>>>(edge_feat, ein_W, ein_b, efph);
  fold_kernel<<<4928, 256, 0, stream>>>(pre_W, pc_W1, pc_W2, post_W, outn_W1, outn_W2, wb);
  bias_kernel<<<10, 256, 0, stream>>>(pre_b, pc_b1, biasf);

  float* cur = hbuf;
  float* nxt = hnew;
  unsigned short *curh = pAh, *curl = pAl, *nxth = pBh, *nxtl = pBl;
  for (int l = 0; l < 5; ++l) {
    size_t lb = (size_t)l * 491520;
    const unsigned short* hpT_h = wb + lb;
    const unsigned short* hpT_l = wb + lb + 65536;
    const unsigned short* WcT_h = wb + lb + 131072;
    const unsigned short* W2T_h = wb + lb + 163840;
    const unsigned short* WfT_h = wb + lb + 196608;
    const unsigned short* WfT_l = wb + lb + 344064;

    mgemm<64, 1, false, false, false, 1><<<dim3(200, 4), 256, 0, stream>>>(
        nullptr, 0, curh, curl, 128, 128, nullptr, 0, hpT_h, hpT_l,
        biasf + l * 512, nullptr, 0, hproj, 512, nullptr, nullptr, 128);
    bondcomp_mfma<<<1000, 512, 0, stream>>>(efph, hproj, WcT_h, W2T_h,
                                            pc_b2 + l * 128, se_W + l * 128, se_b + l,
                                            bond_src, comp_src, hcatp);
    // post-GEMM split-K=3: partials, then fused reduce (+bias+resid+planes)
    mgemm<32, 2, false, false, false, 3><<<dim3(400, 3), 256, 0, stream>>>(
        nullptr, 0, curh, curl, 128, 128, hcatp, 1024, WfT_h, WfT_l,
        nullptr, nullptr, 0, partials, 128, nullptr, nullptr, 1152);
    ksplit_reduce<<<1600, 256, 0, stream>>>(partials, post_b + l * 128, cur,
                                            nxt, nxth, nxtl);
    float* t = cur; cur = nxt; nxt = t;
    unsigned short* th = curh; curh = nxth; nxth = th;
    unsigned short* tl = curl; curl = nxtl; nxtl = tl;
  }
  mgemm<64, 0, true, false, false, 1><<<dim3(200, 1), 256, 0, stream>>>(
      cur, 128, nullptr, nullptr, 0, 128, nullptr, 0, wb + 2457600, wb + 2473984,
      outn_b1, nullptr, 0, tmp1, 128, nullptr, nullptr, 128);
  mgemm<64, 0, false, false, false, 1><<<dim3(200, 1), 256, 0, stream>>>(
      tmp1, 128, nullptr, nullptr, 0, 128, nullptr, 0, wb + 2490368, wb + 2506752,
      outn_b2, nullptr, 0, nodeout, 128, nullptr, nullptr, 128);
  readout_kernel<<<GRAPHS, 128, 0, stream>>>(nodeout, rbuf);
  gemm_rrr<true, false><<<4, 256, 0, stream>>>(rbuf, 384, ro_W1, ro_b1, nullptr, 0,
                                               roh, 128, 384);
  final_kernel<<<16, 256, 0, stream>>>(roh, ro_W2, ro_b2, (float*)d_out);
}

// Round 17
// 654.618 us; speedup vs baseline: 1.1506x; 1.1506x over previous
//
#include <hip/hip_runtime.h>
#include <math.h>

// PNA-EGNN forward, MI355X, round 17:
//  - r16 regression reverted (2-tile loop spilled: WRITE 25.8->57MB). bondcomp back
//    to r15 single-tile form (2000 blocks, 512 thr, 47.2us proven).
//  - outn GEMMs: BM 64->32, grid 400 (grid-starvation fix, shape proven in r13).
//  - post-GEMM split-K=3 + fused reduce (r13); h bf16 planes (r9); fusion (r15).
// hcat agg plane stored as bf16-hi ushort [12800][1024]: [aggB(512)|aggC(512)].

#define N_NODES 12800
#define GRAPHS 128

typedef __attribute__((ext_vector_type(8))) short short8;
typedef __attribute__((ext_vector_type(4))) float f32x4;
#define MFMA16(a, b, c) __builtin_amdgcn_mfma_f32_16x16x32_bf16(a, b, c, 0, 0, 0)

static __device__ __forceinline__ float relu_f(float v) { return v > 0.0f ? v : 0.0f; }

static __device__ __forceinline__ unsigned short bf16rn(float x) {
  union { float f; unsigned u; } a; a.f = x;
  return (unsigned short)((a.u + 0x7fffu + ((a.u >> 16) & 1u)) >> 16);
}
static __device__ __forceinline__ float bf16tof(unsigned short h) {
  union { unsigned u; float f; } a; a.u = ((unsigned)h) << 16;
  return a.f;
}
static __device__ __forceinline__ void cvt_hl(float x, unsigned short& h, unsigned short& l) {
  h = bf16rn(x);
  l = bf16rn(x - bf16tof(h));
}

// packed 2xbf16 conversion: v_cvt_pk_bf16_f32 (no builtin on gfx950 -> inline asm)
static __device__ __forceinline__ unsigned pk2(float a, float b) {
  unsigned r;
  asm("v_cvt_pk_bf16_f32 %0, %1, %2" : "=v"(r) : "v"(a), "v"(b));
  return r;
}
static __device__ __forceinline__ float pk_lo_f(unsigned p) {
  union { unsigned u; float f; } a; a.u = p << 16; return a.f;
}
static __device__ __forceinline__ float pk_hi_f(unsigned p) {
  union { unsigned u; float f; } a; a.u = p & 0xffff0000u; return a.f;
}
// float4 -> hi-plane uint2 (4 bf16) + lo-plane uint2 (residuals)
static __device__ __forceinline__ void cvt4(float4 v, uint2& h, uint2& l) {
  h.x = pk2(v.x, v.y);
  h.y = pk2(v.z, v.w);
  l.x = pk2(v.x - pk_lo_f(h.x), v.y - pk_hi_f(h.x));
  l.y = pk2(v.z - pk_lo_f(h.y), v.w - pk_hi_f(h.y));
}

union U16 {
  uint4 u4;
  uint2 u2[2];
  short8 s8;
};
static __device__ __forceinline__ short8 mk_s8(uint2 a, uint2 b) {
  U16 t; t.u2[0] = a; t.u2[1] = b; return t.s8;
}
static __device__ __forceinline__ short8 ld_s8(const uint4* p) {
  U16 t; t.u4 = *p; return t.s8;
}

// Stage 128x128 ushort hi-plane into fragment-major LDS (2048 uint4 slots = 32KB):
// slot = (ni*4+kb)*64 + quad*16 + l15
template <int NT>
static __device__ __forceinline__ void stage_Bh(
    const unsigned short* __restrict__ Wh, uint4* __restrict__ Bf, int tid) {
  uint4 tmp[2048 / NT];
#pragma unroll
  for (int i = 0; i < 2048 / NT; ++i) {
    int slot = tid + i * NT;
    int l15n = slot & 15;
    int quad_s = (slot >> 4) & 3;
    int kbni = slot >> 6;
    int kb_s = kbni & 3;
    int ni_s = kbni >> 2;
    int n = ni_s * 16 + l15n;
    int k8 = kb_s * 4 + quad_s;
    tmp[i] = *(const uint4*)&Wh[n * 128 + k8 * 8];
  }
#pragma unroll
  for (int i = 0; i < 2048 / NT; ++i) Bf[tid + i * NT] = tmp[i];
}

// ---------------- fp32 [12800][128] -> bf16 hi/lo planes ------------------------------
__global__ __launch_bounds__(256) void h2planes(
    const float* __restrict__ X, unsigned short* __restrict__ Yh,
    unsigned short* __restrict__ Yl) {
  int idx = blockIdx.x * 256 + threadIdx.x;  // 409600 float4s
  float4 v = *(const float4*)&X[(size_t)idx * 4];
  uint2 h, l;
  cvt4(v, h, l);
  *(uint2*)&Yh[(size_t)idx * 4] = h;
  *(uint2*)&Yl[(size_t)idx * 4] = l;
}

// ---------------- split-K reduce: Y = p0+p1+p2 + bias + resid; planes out -------------
__global__ __launch_bounds__(256) void ksplit_reduce(
    const float* __restrict__ p, const float* __restrict__ bias,
    const float* __restrict__ resid, float* __restrict__ Y,
    unsigned short* __restrict__ Yh, unsigned short* __restrict__ Yl) {
  int idx = blockIdx.x * 256 + threadIdx.x;  // 409600 float4s
  const float4* p4 = (const float4*)p;
  float4 a = p4[idx];
  float4 b = p4[idx + 409600];
  float4 c = p4[idx + 819200];
  float4 rr = *(const float4*)&resid[(size_t)idx * 4];
  float4 bb = *(const float4*)&bias[(idx & 31) * 4];
  float4 v;
  v.x = a.x + b.x + c.x + rr.x + bb.x;
  v.y = a.y + b.y + c.y + rr.y + bb.y;
  v.z = a.z + b.z + c.z + rr.z + bb.z;
  v.w = a.w + b.w + c.w + rr.w + bb.w;
  *(float4*)&Y[(size_t)idx * 4] = v;
  uint2 h, l;
  cvt4(v, h, l);
  ((uint2*)Yh)[idx] = h;
  ((uint2*)Yl)[idx] = l;
}

// ---------------- edge input projection, tiled: Yh = bf16hi(relu(X@W + b)) ------------
// X [51200][16], W [16][128]. 32 rows/block, 16 outputs/thread, K=16 unrolled.
__global__ __launch_bounds__(256) void edge_proj_kernel(
    const float* __restrict__ X, const float* __restrict__ W,
    const float* __restrict__ bias, unsigned short* __restrict__ Yh) {
  __shared__ float Xs[32][17];
  __shared__ float Ws[16][128];
  int tid = threadIdx.x;
  int row0 = blockIdx.x * 32;
  for (int i = tid; i < 512; i += 256) {
    int r = i >> 4, k = i & 15;
    Xs[r][k] = X[(size_t)(row0 + r) * 16 + k];
  }
  for (int i = tid; i < 2048; i += 256) Ws[i >> 7][i & 127] = W[i];
  __syncthreads();
  int rg = tid >> 5;         // 4 rows each
  int c0 = (tid & 31) * 4;   // 4 cols
  float bj0 = bias[c0], bj1 = bias[c0 + 1], bj2 = bias[c0 + 2], bj3 = bias[c0 + 3];
#pragma unroll
  for (int rr = 0; rr < 4; ++rr) {
    int r = rg * 4 + rr;
    float a0 = bj0, a1 = bj1, a2 = bj2, a3 = bj3;
#pragma unroll
    for (int k = 0; k < 16; ++k) {
      float x = Xs[r][k];
      float4 w = *(const float4*)&Ws[k][c0];
      a0 += x * w.x; a1 += x * w.y; a2 += x * w.z; a3 += x * w.w;
    }
    uint2 h;
    h.x = pk2(relu_f(a0), relu_f(a1));
    h.y = pk2(relu_f(a2), relu_f(a3));
    *(uint2*)&Yh[(size_t)(row0 + r) * 128 + c0] = h;
  }
}

// ---------------- per-layer hproj bias: [5][512] = [0 | pre_b | 0 | pc_b1] ------------
__global__ __launch_bounds__(256) void bias_kernel(
    const float* __restrict__ pre_b, const float* __restrict__ pc_b1,
    float* __restrict__ biasf) {
  int idx = blockIdx.x * 256 + threadIdx.x;  // 2560
  if (idx >= 2560) return;
  int l = idx >> 9, c = idx & 511;
  float v = 0.f;
  if (c >= 128 && c < 256) v = pre_b[l * 128 + (c - 128)];
  else if (c >= 384) v = pc_b1[l * 128 + (c - 384)];
  biasf[idx] = v;
}

// ---------------- weight prep: fold scalers + transpose + hi/lo split -----------
// ushort plane offsets (per layer stride 491520):
//  hprojT_hi 0 / lo 65536           [512][128]
//  WcT_hi 131072 / lo 147456        [128][128]
//  W2T_hi 163840 / lo 180224        [128][128]
//  WfoldT_hi 196608 / lo 344064     [128][1152]
//  outn1T_hi 2457600 / lo 2473984; outn2T_hi 2490368 / lo 2506752
__global__ __launch_bounds__(256) void fold_kernel(
    const float* __restrict__ pre_W, const float* __restrict__ pc_W1,
    const float* __restrict__ pc_W2, const float* __restrict__ post_W,
    const float* __restrict__ outn_W1, const float* __restrict__ outn_W2,
    unsigned short* __restrict__ wb) {
  int idx = blockIdx.x * 256 + threadIdx.x;  // 1,261,568 total
  const float C1 = 1.6094379124341003f;   // log 5
  const float C2 = 2.8332133440562162f;   // log 17
  float val;
  size_t ohi, olo;
  if (idx < 1228800) {
    int l = idx / 245760;
    int r = idx % 245760;
    size_t lb = (size_t)l * 491520;
    if (r < 65536) {  // hprojT [n=512][k=128]
      int n = r >> 7, k = r & 127;
      if (n < 128) val = pre_W[(size_t)l * 49152 + k * 128 + n];
      else if (n < 256) val = pre_W[(size_t)l * 49152 + (128 + k) * 128 + (n - 128)];
      else if (n < 384) val = pc_W1[(size_t)l * 32768 + k * 128 + (n - 256)];
      else val = pc_W1[(size_t)l * 32768 + (128 + k) * 128 + (n - 384)];
      ohi = lb + r; olo = ohi + 65536;
    } else if (r < 81920) {  // WcT
      int r2 = r - 65536; int n = r2 >> 7, k = r2 & 127;
      val = pre_W[(size_t)l * 49152 + (256 + k) * 128 + n];
      ohi = lb + 131072 + r2; olo = ohi + 16384;
    } else if (r < 98304) {  // W2T
      int r2 = r - 81920; int n = r2 >> 7, k = r2 & 127;
      val = pc_W2[(size_t)l * 16384 + k * 128 + n];
      ohi = lb + 163840 + r2; olo = ohi + 16384;
    } else {  // WfoldT [n=128][kk=1152]
      int r2 = r - 98304;
      int n = r2 / 1152, kk = r2 % 1152;
      const float* Wl = post_W + (size_t)l * 409600;
      if (kk < 128) val = Wl[kk * 128 + n];
      else if (kk < 640) {
        int j = kk - 128;
        val = Wl[(128 + j) * 128 + n] + C1 * Wl[(640 + j) * 128 + n] +
              (1.0f / C1) * Wl[(1152 + j) * 128 + n];
      } else {
        int j = kk - 640;
        val = Wl[(1664 + j) * 128 + n] + C2 * Wl[(2176 + j) * 128 + n] +
              (1.0f / C2) * Wl[(2688 + j) * 128 + n];
      }
      ohi = lb + 196608 + r2; olo = ohi + 147456;
    }
  } else {
    int r = idx - 1228800;
    if (r < 16384) {
      int n = r >> 7, k = r & 127;
      val = outn_W1[k * 128 + n];
      ohi = 2457600 + r; olo = ohi + 16384;
    } else {
      int r2 = r - 16384; int n = r2 >> 7, k = r2 & 127;
      val = outn_W2[k * 128 + n];
      ohi = 2490368 + r2; olo = ohi + 16384;
    }
  }
  unsigned short h, l2;
  cvt_hl(val, h, l2);
  wb[ohi] = h;
  wb[olo] = l2;
}

// ---------------- dense MFMA GEMM: Y[M,ntot] = X @ Wt^T (+bias)(+resid)(relu) ---------
// 256 threads / 4 waves; wave w owns cols [w*32, w*32+32).
// AMODE 0: A from fp32 X0 (cvt4).  AMODE 1: A from hi/lo planes.
// AMODE 2: k<K0 from hi/lo planes, k>=K0 from X1h (hi only).
// WPLANES: epilogue also emits Y as bf16 hi/lo planes (stride 128).
// KSPLIT>1: blockIdx.y = k-chunk; writes raw fp32 partials (no bias/resid/planes).
template <int BM, int AMODE, bool RELU, bool RESID, bool WPLANES, int KSPLIT>
__global__ __launch_bounds__(256) void mgemm(
    const float* __restrict__ X0, int xs0,
    const unsigned short* __restrict__ Ah, const unsigned short* __restrict__ Al,
    int ahs, int K0,
    const unsigned short* __restrict__ X1h, int xs1,
    const unsigned short* __restrict__ Wth, const unsigned short* __restrict__ Wtl,
    const float* __restrict__ bias, const float* __restrict__ resid, int rstride,
    float* __restrict__ Y, int ystride,
    unsigned short* __restrict__ Yh, unsigned short* __restrict__ Yl, int K) {
  __shared__ unsigned short As_h[BM][40], As_l[BM][40];
  __shared__ unsigned short Bs_h[128][40], Bs_l[128][40];
  int tid = threadIdx.x;
  int wave = tid >> 6, lane = tid & 63, quad = lane >> 4, l15 = lane & 15;
  int row0 = blockIdx.x * BM;
  int n0, kbeg, kend;
  float* Yout = Y;
  if (KSPLIT > 1) {
    n0 = 0;
    int kc = K / KSPLIT;
    kbeg = blockIdx.y * kc;
    kend = kbeg + kc;
    Yout = Y + (size_t)blockIdx.y * N_NODES * 128;
  } else {
    n0 = blockIdx.y * 128;
    kbeg = 0;
    kend = K;
  }
  f32x4 acc[BM / 16][2];
#pragma unroll
  for (int mi = 0; mi < BM / 16; ++mi)
#pragma unroll
    for (int ni = 0; ni < 2; ++ni) acc[mi][ni] = (f32x4){0.f, 0.f, 0.f, 0.f};
  for (int kb = kbeg; kb < kend; kb += 32) {
    if (kb != kbeg) __syncthreads();
    bool haslo = (AMODE != 2) || (kb < K0);
    if (AMODE == 0) {
      for (int i = tid; i < BM * 8; i += 256) {
        int r = i >> 3, kq = i & 7;
        float4 v = *(const float4*)&X0[(size_t)(row0 + r) * xs0 + kb + kq * 4];
        uint2 th, tl;
        cvt4(v, th, tl);
        *(uint2*)&As_h[r][kq * 4] = th;
        *(uint2*)&As_l[r][kq * 4] = tl;
      }
    } else if (haslo) {
      for (int i = tid; i < BM * 4; i += 256) {
        int r = i >> 2, q = i & 3;
        size_t o = (size_t)(row0 + r) * ahs + kb + q * 8;
        *(uint4*)&As_h[r][q * 8] = *(const uint4*)&Ah[o];
        *(uint4*)&As_l[r][q * 8] = *(const uint4*)&Al[o];
      }
    } else {
      for (int i = tid; i < BM * 4; i += 256) {
        int r = i >> 2, q = i & 3;
        *(uint4*)&As_h[r][q * 8] =
            *(const uint4*)&X1h[(size_t)(row0 + r) * xs1 + (kb - K0) + q * 8];
      }
    }
    for (int i = tid; i < 512; i += 256) {
      int r = i >> 2, q = i & 3;
      size_t o = (size_t)(n0 + r) * K + kb + q * 8;
      *(uint4*)&Bs_h[r][q * 8] = *(const uint4*)&Wth[o];
      *(uint4*)&Bs_l[r][q * 8] = *(const uint4*)&Wtl[o];
    }
    __syncthreads();
    short8 bh[2], bl[2], ah[BM / 16], al[BM / 16];
#pragma unroll
    for (int ni = 0; ni < 2; ++ni) {
      bh[ni] = *(const short8*)&Bs_h[wave * 32 + ni * 16 + l15][quad * 8];
      bl[ni] = *(const short8*)&Bs_l[wave * 32 + ni * 16 + l15][quad * 8];
    }
#pragma unroll
    for (int mi = 0; mi < BM / 16; ++mi)
      ah[mi] = *(const short8*)&As_h[mi * 16 + l15][quad * 8];
    if (haslo) {
#pragma unroll
      for (int mi = 0; mi < BM / 16; ++mi)
        al[mi] = *(const short8*)&As_l[mi * 16 + l15][quad * 8];
    }
#pragma unroll
    for (int mi = 0; mi < BM / 16; ++mi)
#pragma unroll
      for (int ni = 0; ni < 2; ++ni) {
        acc[mi][ni] = MFMA16(ah[mi], bh[ni], acc[mi][ni]);
        acc[mi][ni] = MFMA16(ah[mi], bl[ni], acc[mi][ni]);
      }
    if (haslo) {
#pragma unroll
      for (int mi = 0; mi < BM / 16; ++mi)
#pragma unroll
        for (int ni = 0; ni < 2; ++ni)
          acc[mi][ni] = MFMA16(al[mi], bh[ni], acc[mi][ni]);
    }
  }
#pragma unroll
  for (int mi = 0; mi < BM / 16; ++mi)
#pragma unroll
    for (int ni = 0; ni < 2; ++ni) {
      int col = n0 + wave * 32 + ni * 16 + l15;
      if (KSPLIT > 1) {
#pragma unroll
        for (int r = 0; r < 4; ++r) {
          int row = row0 + mi * 16 + quad * 4 + r;
          Yout[(size_t)row * ystride + col] = acc[mi][ni][r];
        }
      } else {
        float bj = bias ? bias[col] : 0.f;
#pragma unroll
        for (int r = 0; r < 4; ++r) {
          int row = row0 + mi * 16 + quad * 4 + r;
          float v = acc[mi][ni][r] + bj;
          if (RESID) v += resid[(size_t)row * rstride + col];
          if (RELU) v = relu_f(v);
          Y[(size_t)row * ystride + col] = v;
          if (WPLANES) {
            unsigned short hh, ll;
            cvt_hl(v, hh, ll);
            Yh[(size_t)row * 128 + col] = hh;
            Yl[(size_t)row * 128 + col] = ll;
          }
        }
      }
    }
}

// ---------------- fused bond+comp: one dispatch, 2000 blocks --------------------------
// Blocks [0,400): bond path (128 bond edges each). Blocks [400,2000): comp path
// (128 comp edges each). Both: 512 thr / 8 waves x 16 edges, B-hi panel in 32KB
// fragment-major LDS, A bf16-hi in regs, 32 MFMA/wave, wave-local epilogues.
#define BOND_BLOCKS 400
__global__ __launch_bounds__(512, 4) void bondcomp_mfma(
    const unsigned short* __restrict__ efph,
    const float* __restrict__ hproj,
    const unsigned short* __restrict__ Wch, const unsigned short* __restrict__ W2h,
    const float* __restrict__ b2,
    const float* __restrict__ seW, const float* __restrict__ seb,
    const int* __restrict__ bond_src, const int* __restrict__ comp_src,
    unsigned short* __restrict__ aggp) {
  __shared__ uint4 Bf[2048];  // 32KB fragment-major B hi
  int tid = threadIdx.x;
  int wave = tid >> 6, lane = tid & 63, quad = lane >> 4, l15 = lane & 15;
  if (blockIdx.x < BOND_BLOCKS) {
    // ---------------- bond path ----------------
    int e0 = blockIdx.x * 128;
    int ew = e0 + wave * 16;
    short8 ah[4];
#pragma unroll
    for (int kb = 0; kb < 4; ++kb) {
      size_t o = (size_t)(ew + l15) * 128 + kb * 32 + quad * 8;
      ah[kb] = ld_s8((const uint4*)&efph[o]);
    }
    stage_Bh<512>(Wch, Bf, tid);
    __syncthreads();
    f32x4 acc[8];
#pragma unroll
    for (int ni = 0; ni < 8; ++ni) acc[ni] = (f32x4){0.f, 0.f, 0.f, 0.f};
#pragma unroll
    for (int kb = 0; kb < 4; ++kb) {
#pragma unroll
      for (int ni = 0; ni < 8; ++ni) {
        short8 bh = ld_s8(&Bf[(ni * 4 + kb) * 64 + lane]);
        acc[ni] = MFMA16(ah[kb], bh, acc[ni]);
      }
    }
    int node = (ew >> 2) + quad;
    int src_r[4];
#pragma unroll
    for (int r = 0; r < 4; ++r) src_r[r] = bond_src[ew + quad * 4 + r];
#pragma unroll
    for (int ni = 0; ni < 8; ++ni) {
      int c = ni * 16 + l15;
      float wbv = hproj[(size_t)node * 512 + 128 + c];  // includes pre_b
      float s = 0.f, sq = 0.f, mx = -1e30f, mn = 1e30f;
#pragma unroll
      for (int r = 0; r < 4; ++r) {
        float v = acc[ni][r] + wbv + hproj[(size_t)src_r[r] * 512 + c];
        s += v; sq += v * v; mx = fmaxf(mx, v); mn = fminf(mn, v);
      }
      float mean = s * 0.25f;
      float var = relu_f(sq * 0.25f - mean * mean);
      size_t base = (size_t)node * 1024 + c;
      aggp[base] = bf16rn(mean);
      aggp[base + 128] = bf16rn(mx);
      aggp[base + 256] = bf16rn(mn);
      aggp[base + 384] = bf16rn(sqrtf(var + 1e-5f));
    }
  } else {
    // ---------------- comp path ----------------
    int e0 = (blockIdx.x - BOND_BLOCKS) * 128;
    int e = e0 + wave * 16 + l15;
    int src = comp_src[e];
    int node = e >> 4;  // same node for whole wave
    const float* pa = hproj + (size_t)src * 512 + 256;
    const float* pb = hproj + (size_t)node * 512 + 384;
    short8 ah[4];
#pragma unroll
    for (int kb = 0; kb < 4; ++kb) {
      int k0 = kb * 32 + quad * 8;
      float4 va0 = *(const float4*)&pa[k0], va1 = *(const float4*)&pa[k0 + 4];
      float4 vb0 = *(const float4*)&pb[k0], vb1 = *(const float4*)&pb[k0 + 4];
      uint2 h0, h1;
      h0.x = pk2(relu_f(va0.x + vb0.x), relu_f(va0.y + vb0.y));
      h0.y = pk2(relu_f(va0.z + vb0.z), relu_f(va0.w + vb0.w));
      h1.x = pk2(relu_f(va1.x + vb1.x), relu_f(va1.y + vb1.y));
      h1.y = pk2(relu_f(va1.z + vb1.z), relu_f(va1.w + vb1.w));
      ah[kb] = mk_s8(h0, h1);
    }
    stage_Bh<512>(W2h, Bf, tid);
    __syncthreads();
    f32x4 acc[8];
#pragma unroll
    for (int ni = 0; ni < 8; ++ni) acc[ni] = (f32x4){0.f, 0.f, 0.f, 0.f};
#pragma unroll
    for (int kb = 0; kb < 4; ++kb) {
#pragma unroll
      for (int ni = 0; ni < 8; ++ni) {
        short8 bh = ld_s8(&Bf[(ni * 4 + kb) * 64 + lane]);
        acc[ni] = MFMA16(ah[kb], bh, acc[ni]);
      }
    }
    float b2v[8], swv[8];
#pragma unroll
    for (int ni = 0; ni < 8; ++ni) {
      int c = ni * 16 + l15;
      b2v[ni] = b2[c];
      swv[ni] = seW[c];
    }
    float seb0 = seb[0];
    float gate[4];
#pragma unroll
    for (int r = 0; r < 4; ++r) {
      float p = 0.f;
#pragma unroll
      for (int ni = 0; ni < 8; ++ni) p += (acc[ni][r] + b2v[ni]) * swv[ni];
      p += __shfl_xor(p, 1, 64);
      p += __shfl_xor(p, 2, 64);
      p += __shfl_xor(p, 4, 64);
      p += __shfl_xor(p, 8, 64);
      gate[r] = 1.f / (1.f + expf(-(p + seb0)));
    }
#pragma unroll
    for (int ni = 0; ni < 8; ++ni) {
      float s = 0.f, sq = 0.f, mx = -1e30f, mn = 1e30f;
#pragma unroll
      for (int r = 0; r < 4; ++r) {
        float v = (acc[ni][r] + b2v[ni]) * gate[r];
        s += v; sq += v * v; mx = fmaxf(mx, v); mn = fminf(mn, v);
      }
      s += __shfl_xor(s, 16, 64); sq += __shfl_xor(sq, 16, 64);
      mx = fmaxf(mx, __shfl_xor(mx, 16, 64)); mn = fminf(mn, __shfl_xor(mn, 16, 64));
      s += __shfl_xor(s, 32, 64); sq += __shfl_xor(sq, 32, 64);
      mx = fmaxf(mx, __shfl_xor(mx, 32, 64)); mn = fminf(mn, __shfl_xor(mn, 32, 64));
      if (quad == 0) {
        int c = ni * 16 + l15;
        float mean = s * 0.0625f;
        float var = relu_f(sq * 0.0625f - mean * mean);
        size_t base = (size_t)node * 1024 + 512 + c;
        aggp[base] = bf16rn(mean);
        aggp[base + 128] = bf16rn(mx);
        aggp[base + 256] = bf16rn(mn);
        aggp[base + 384] = bf16rn(sqrtf(var + 1e-5f));
      }
    }
  }
}

// ---------------- vector GEMM (readout MLP + node input projection) -------------------
template <bool RELU, bool RESID>
__global__ __launch_bounds__(256) void gemm_rrr(
    const float* __restrict__ X, int xstride, const float* __restrict__ W,
    const float* __restrict__ bias, const float* __restrict__ resid, int rstride,
    float* __restrict__ Y, int ystride, int Ktot) {
  __shared__ __align__(16) float Xs[32][68];
  __shared__ __align__(16) float Ws[64][128];
  int tid = threadIdx.x;
  int row0 = blockIdx.x * 32;
  int rg = tid >> 5;
  int c0 = (tid & 31) * 4;
  float acc[4][4] = {};
  for (int kb = 0; kb < Ktot; kb += 64) {
    __syncthreads();
    for (int i = tid; i < 32 * 64; i += 256) {
      int r = i >> 6, k = i & 63;
      Xs[r][k] = X[(size_t)(row0 + r) * xstride + kb + k];
    }
    for (int i = tid; i < 64 * 128; i += 256) {
      int k = i >> 7, c = i & 127;
      Ws[k][c] = W[(size_t)(kb + k) * 128 + c];
    }
    __syncthreads();
#pragma unroll
    for (int k4 = 0; k4 < 16; ++k4) {
      float4 w0 = *(const float4*)&Ws[k4 * 4 + 0][c0];
      float4 w1 = *(const float4*)&Ws[k4 * 4 + 1][c0];
      float4 w2 = *(const float4*)&Ws[k4 * 4 + 2][c0];
      float4 w3 = *(const float4*)&Ws[k4 * 4 + 3][c0];
#pragma unroll
      for (int r = 0; r < 4; ++r) {
        float4 x = *(const float4*)&Xs[rg * 4 + r][k4 * 4];
        acc[r][0] += x.x * w0.x + x.y * w1.x + x.z * w2.x + x.w * w3.x;
        acc[r][1] += x.x * w0.y + x.y * w1.y + x.z * w2.y + x.w * w3.y;
        acc[r][2] += x.x * w0.z + x.y * w1.z + x.z * w2.z + x.w * w3.z;
        acc[r][3] += x.x * w0.w + x.y * w1.w + x.z * w2.w + x.w * w3.w;
      }
    }
  }
  float bj[4] = {0.f, 0.f, 0.f, 0.f};
  if (bias) {
    bj[0] = bias[c0]; bj[1] = bias[c0 + 1]; bj[2] = bias[c0 + 2]; bj[3] = bias[c0 + 3];
  }
#pragma unroll
  for (int r = 0; r < 4; ++r) {
    int row = row0 + rg * 4 + r;
    float4 o;
    float* po = &o.x;
#pragma unroll
    for (int j = 0; j < 4; ++j) {
      float v = acc[r][j] + bj[j];
      if (RESID) v += resid[(size_t)row * rstride + c0 + j];
      if (RELU) v = relu_f(v);
      po[j] = v;
    }
    *(float4*)&Y[(size_t)row * ystride + c0] = o;
  }
}

// ---------------- readout + final ----------------------------------------------------
__global__ __launch_bounds__(128) void readout_kernel(const float* __restrict__ nodeout,
                                                      float* __restrict__ r) {
  int g = blockIdx.x, c = threadIdx.x;
  float s = 0.f, mx = -1e30f;
  for (int i = 0; i < 100; ++i) {
    float v = nodeout[(size_t)(g * 100 + i) * 128 + c];
    s += v; mx = fmaxf(mx, v);
  }
  r[g * 384 + c] = s;
  r[g * 384 + 128 + c] = s * 0.01f;
  r[g * 384 + 256 + c] = mx;
}

__global__ __launch_bounds__(256) void final_kernel(const float* __restrict__ roh,
                                                    const float* __restrict__ W2,
                                                    const float* __restrict__ b2,
                                                    float* __restrict__ out) {
  int idx = blockIdx.x * 256 + threadIdx.x;  // 4096
  int g = idx >> 5, c = idx & 31;
  float acc = b2[c];
  for (int k = 0; k < 128; ++k) acc += roh[g * 128 + k] * W2[k * 32 + c];
  out[idx] = acc;
}

extern "C" void kernel_launch(void* const* d_in, const int* in_sizes, int n_in,
                              void* d_out, int out_size, void* d_ws, size_t ws_size,
                              hipStream_t stream) {
  const float* node_feat = (const float*)d_in[0];
  const float* edge_feat = (const float*)d_in[1];
  const int* bond_src = (const int*)d_in[2];
  const int* comp_src = (const int*)d_in[4];
  const float* in_W = (const float*)d_in[7];
  const float* in_b = (const float*)d_in[8];
  const float* ein_W = (const float*)d_in[9];
  const float* ein_b = (const float*)d_in[10];
  const float* pre_W = (const float*)d_in[11];
  const float* pre_b = (const float*)d_in[12];
  const float* pc_W1 = (const float*)d_in[13];
  const float* pc_b1 = (const float*)d_in[14];
  const float* pc_W2 = (const float*)d_in[15];
  const float* pc_b2 = (const float*)d_in[16];
  const float* se_W = (const float*)d_in[17];
  const float* se_b = (const float*)d_in[18];
  const float* post_W = (const float*)d_in[19];
  const float* post_b = (const float*)d_in[20];
  const float* outn_W1 = (const float*)d_in[21];
  const float* outn_b1 = (const float*)d_in[22];
  const float* outn_W2 = (const float*)d_in[23];
  const float* outn_b2 = (const float*)d_in[24];
  const float* ro_W1 = (const float*)d_in[25];
  const float* ro_b1 = (const float*)d_in[26];
  const float* ro_W2 = (const float*)d_in[27];
  const float* ro_b2 = (const float*)d_in[28];

  float* ws = (float*)d_ws;
  float* hbuf = ws;                                    // 1,638,400
  float* hnew = ws + 1638400;                          // 1,638,400
  unsigned short* hcatp = (unsigned short*)(ws + 3276800);  // [12800][1024] ushort
  unsigned short* efph = (unsigned short*)(ws + 9830400);   // [51200][128] ushort
  float* hproj = ws + 16384000;                        // 6,553,600  [12800][512]
                                                       //   (also split-K partials:
                                                       //    3 x 1,638,400 fp32)
  unsigned short* wb = (unsigned short*)(ws + 22937600);    // 2,523,136 ushort
  float* tmp1 = ws + 24199168;                         // 1,638,400 (planesA in layers;
                                                       //   outn stage after)
  float* nodeout = ws + 25837568;                      // 1,638,400 (planesB in layers)
  float* rbuf = ws + 27475968;                         // 49,152 (biasf in layers)
  float* roh = ws + 27525120;                          // 16,384
  float* biasf = rbuf;                                 // [5][512] during layer loop only
  float* partials = hproj;                             // hproj dead when post runs
  unsigned short* pAh = (unsigned short*)tmp1;         // [12800][128]
  unsigned short* pAl = pAh + 1638400;
  unsigned short* pBh = (unsigned short*)nodeout;
  unsigned short* pBl = pBh + 1638400;

  // node proj: tiled vector GEMM, then split to bf16 hi/lo planes
  gemm_rrr<true, false><<<400, 256, 0, stream>>>(node_feat, 64, in_W, in_b, nullptr, 0,
                                                 hbuf, 128, 64);
  h2planes<<<1600, 256, 0, stream>>>(hbuf, pAh, pAl);
  // edge proj: tiled, K=16 unrolled, bf16 hi plane only
  edge_proj_kernel<<<1600, 256, 0, stream>>>(edge_feat, ein_W, ein_b, efph);
  fold_kernel<<<4928, 256, 0, stream>>>(pre_W, pc_W1, pc_W2, post_W, outn_W1, outn_W2, wb);
  bias_kernel<<<10, 256, 0, stream>>>(pre_b, pc_b1, biasf);

  float* cur = hbuf;
  float* nxt = hnew;
  unsigned short *curh = pAh, *curl = pAl, *nxth = pBh, *nxtl = pBl;
  for (int l = 0; l < 5; ++l) {
    size_t lb = (size_t)l * 491520;
    const unsigned short* hpT_h = wb + lb;
    const unsigned short* hpT_l = wb + lb + 65536;
    const unsigned short* WcT_h = wb + lb + 131072;
    const unsigned short* W2T_h = wb + lb + 163840;
    const unsigned short* WfT_h = wb + lb + 196608;
    const unsigned short* WfT_l = wb + lb + 344064;

    mgemm<64, 1, false, false, false, 1><<<dim3(200, 4), 256, 0, stream>>>(
        nullptr, 0, curh, curl, 128, 128, nullptr, 0, hpT_h, hpT_l,
        biasf + l * 512, nullptr, 0, hproj, 512, nullptr, nullptr, 128);
    bondcomp_mfma<<<2000, 512, 0, stream>>>(efph, hproj, WcT_h, W2T_h,
                                            pc_b2 + l * 128, se_W + l * 128, se_b + l,
                                            bond_src, comp_src, hcatp);
    // post-GEMM split-K=3: partials, then fused reduce (+bias+resid+planes)
    mgemm<32, 2, false, false, false, 3><<<dim3(400, 3), 256, 0, stream>>>(
        nullptr, 0, curh, curl, 128, 128, hcatp, 1024, WfT_h, WfT_l,
        nullptr, nullptr, 0, partials, 128, nullptr, nullptr, 1152);
    ksplit_reduce<<<1600, 256, 0, stream>>>(partials, post_b + l * 128, cur,
                                            nxt, nxth, nxtl);
    float* t = cur; cur = nxt; nxt = t;
    unsigned short* th = curh; curh = nxth; nxth = th;
    unsigned short* tl = curl; curl = nxtl; nxtl = tl;
  }
  mgemm<32, 0, true, false, false, 1><<<dim3(400, 1), 256, 0, stream>>>(
      cur, 128, nullptr, nullptr, 0, 128, nullptr, 0, wb + 2457600, wb + 2473984,
      outn_b1, nullptr, 0, tmp1, 128, nullptr, nullptr, 128);
  mgemm<32, 0, false, false, false, 1><<<dim3(400, 1), 256, 0, stream>>>(
      tmp1, 128, nullptr, nullptr, 0, 128, nullptr, 0, wb + 2490368, wb + 2506752,
      outn_b2, nullptr, 0, nodeout, 128, nullptr, nullptr, 128);
  readout_kernel<<<GRAPHS, 128, 0, stream>>>(nodeout, rbuf);
  gemm_rrr<true, false><<<4, 256, 0, stream>>>(rbuf, 384, ro_W1, ro_b1, nullptr, 0,
                                               roh, 128, 384);
  final_kernel<<<16, 256, 0, stream>>>(roh, ro_W2, ro_b2, (float*)d_out);
}

// Round 18
// 627.742 us; speedup vs baseline: 1.1999x; 1.0428x over previous
//
#include <hip/hip_runtime.h>
#include <math.h>

// PNA-EGNN forward, MI355X, round 18:
//  - hproj split output: cols 0-255 fp32 [12800][256] (bond epilogue), cols 256-511
//    bf16-hi hp16 [12800][256] (comp t-inputs). Comp gather bytes halve; hproj
//    write traffic 25->19.5MB. t rounding unchanged in structure (bf16 in, bf16 out).
//  - bondcomp r15/r17 single-tile form (proven 47.4us); outn BM=32 grid 400 (r17);
//    post-GEMM split-K=3 + fused reduce (r13); h bf16 planes (r9).
// hcat agg plane stored as bf16-hi ushort [12800][1024]: [aggB(512)|aggC(512)].

#define N_NODES 12800
#define GRAPHS 128

typedef __attribute__((ext_vector_type(8))) short short8;
typedef __attribute__((ext_vector_type(4))) float f32x4;
#define MFMA16(a, b, c) __builtin_amdgcn_mfma_f32_16x16x32_bf16(a, b, c, 0, 0, 0)

static __device__ __forceinline__ float relu_f(float v) { return v > 0.0f ? v : 0.0f; }

static __device__ __forceinline__ unsigned short bf16rn(float x) {
  union { float f; unsigned u; } a; a.f = x;
  return (unsigned short)((a.u + 0x7fffu + ((a.u >> 16) & 1u)) >> 16);
}
static __device__ __forceinline__ float bf16tof(unsigned short h) {
  union { unsigned u; float f; } a; a.u = ((unsigned)h) << 16;
  return a.f;
}
static __device__ __forceinline__ void cvt_hl(float x, unsigned short& h, unsigned short& l) {
  h = bf16rn(x);
  l = bf16rn(x - bf16tof(h));
}

// packed 2xbf16 conversion: v_cvt_pk_bf16_f32 (no builtin on gfx950 -> inline asm)
static __device__ __forceinline__ unsigned pk2(float a, float b) {
  unsigned r;
  asm("v_cvt_pk_bf16_f32 %0, %1, %2" : "=v"(r) : "v"(a), "v"(b));
  return r;
}
static __device__ __forceinline__ float pk_lo_f(unsigned p) {
  union { unsigned u; float f; } a; a.u = p << 16; return a.f;
}
static __device__ __forceinline__ float pk_hi_f(unsigned p) {
  union { unsigned u; float f; } a; a.u = p & 0xffff0000u; return a.f;
}
// float4 -> hi-plane uint2 (4 bf16) + lo-plane uint2 (residuals)
static __device__ __forceinline__ void cvt4(float4 v, uint2& h, uint2& l) {
  h.x = pk2(v.x, v.y);
  h.y = pk2(v.z, v.w);
  l.x = pk2(v.x - pk_lo_f(h.x), v.y - pk_hi_f(h.x));
  l.y = pk2(v.z - pk_lo_f(h.y), v.w - pk_hi_f(h.y));
}

union U16 {
  uint4 u4;
  uint2 u2[2];
  short8 s8;
};
static __device__ __forceinline__ short8 mk_s8(uint2 a, uint2 b) {
  U16 t; t.u2[0] = a; t.u2[1] = b; return t.s8;
}
static __device__ __forceinline__ short8 ld_s8(const uint4* p) {
  U16 t; t.u4 = *p; return t.s8;
}

// Stage 128x128 ushort hi-plane into fragment-major LDS (2048 uint4 slots = 32KB):
// slot = (ni*4+kb)*64 + quad*16 + l15
template <int NT>
static __device__ __forceinline__ void stage_Bh(
    const unsigned short* __restrict__ Wh, uint4* __restrict__ Bf, int tid) {
  uint4 tmp[2048 / NT];
#pragma unroll
  for (int i = 0; i < 2048 / NT; ++i) {
    int slot = tid + i * NT;
    int l15n = slot & 15;
    int quad_s = (slot >> 4) & 3;
    int kbni = slot >> 6;
    int kb_s = kbni & 3;
    int ni_s = kbni >> 2;
    int n = ni_s * 16 + l15n;
    int k8 = kb_s * 4 + quad_s;
    tmp[i] = *(const uint4*)&Wh[n * 128 + k8 * 8];
  }
#pragma unroll
  for (int i = 0; i < 2048 / NT; ++i) Bf[tid + i * NT] = tmp[i];
}

// ---------------- fp32 [12800][128] -> bf16 hi/lo planes ------------------------------
__global__ __launch_bounds__(256) void h2planes(
    const float* __restrict__ X, unsigned short* __restrict__ Yh,
    unsigned short* __restrict__ Yl) {
  int idx = blockIdx.x * 256 + threadIdx.x;  // 409600 float4s
  float4 v = *(const float4*)&X[(size_t)idx * 4];
  uint2 h, l;
  cvt4(v, h, l);
  *(uint2*)&Yh[(size_t)idx * 4] = h;
  *(uint2*)&Yl[(size_t)idx * 4] = l;
}

// ---------------- split-K reduce: Y = p0+p1+p2 + bias + resid; planes out -------------
__global__ __launch_bounds__(256) void ksplit_reduce(
    const float* __restrict__ p, const float* __restrict__ bias,
    const float* __restrict__ resid, float* __restrict__ Y,
    unsigned short* __restrict__ Yh, unsigned short* __restrict__ Yl) {
  int idx = blockIdx.x * 256 + threadIdx.x;  // 409600 float4s
  const float4* p4 = (const float4*)p;
  float4 a = p4[idx];
  float4 b = p4[idx + 409600];
  float4 c = p4[idx + 819200];
  float4 rr = *(const float4*)&resid[(size_t)idx * 4];
  float4 bb = *(const float4*)&bias[(idx & 31) * 4];
  float4 v;
  v.x = a.x + b.x + c.x + rr.x + bb.x;
  v.y = a.y + b.y + c.y + rr.y + bb.y;
  v.z = a.z + b.z + c.z + rr.z + bb.z;
  v.w = a.w + b.w + c.w + rr.w + bb.w;
  *(float4*)&Y[(size_t)idx * 4] = v;
  uint2 h, l;
  cvt4(v, h, l);
  ((uint2*)Yh)[idx] = h;
  ((uint2*)Yl)[idx] = l;
}

// ---------------- edge input projection, tiled: Yh = bf16hi(relu(X@W + b)) ------------
// X [51200][16], W [16][128]. 32 rows/block, 16 outputs/thread, K=16 unrolled.
__global__ __launch_bounds__(256) void edge_proj_kernel(
    const float* __restrict__ X, const float* __restrict__ W,
    const float* __restrict__ bias, unsigned short* __restrict__ Yh) {
  __shared__ float Xs[32][17];
  __shared__ float Ws[16][128];
  int tid = threadIdx.x;
  int row0 = blockIdx.x * 32;
  for (int i = tid; i < 512; i += 256) {
    int r = i >> 4, k = i & 15;
    Xs[r][k] = X[(size_t)(row0 + r) * 16 + k];
  }
  for (int i = tid; i < 2048; i += 256) Ws[i >> 7][i & 127] = W[i];
  __syncthreads();
  int rg = tid >> 5;         // 4 rows each
  int c0 = (tid & 31) * 4;   // 4 cols
  float bj0 = bias[c0], bj1 = bias[c0 + 1], bj2 = bias[c0 + 2], bj3 = bias[c0 + 3];
#pragma unroll
  for (int rr = 0; rr < 4; ++rr) {
    int r = rg * 4 + rr;
    float a0 = bj0, a1 = bj1, a2 = bj2, a3 = bj3;
#pragma unroll
    for (int k = 0; k < 16; ++k) {
      float x = Xs[r][k];
      float4 w = *(const float4*)&Ws[k][c0];
      a0 += x * w.x; a1 += x * w.y; a2 += x * w.z; a3 += x * w.w;
    }
    uint2 h;
    h.x = pk2(relu_f(a0), relu_f(a1));
    h.y = pk2(relu_f(a2), relu_f(a3));
    *(uint2*)&Yh[(size_t)(row0 + r) * 128 + c0] = h;
  }
}

// ---------------- per-layer hproj bias: [5][512] = [0 | pre_b | 0 | pc_b1] ------------
__global__ __launch_bounds__(256) void bias_kernel(
    const float* __restrict__ pre_b, const float* __restrict__ pc_b1,
    float* __restrict__ biasf) {
  int idx = blockIdx.x * 256 + threadIdx.x;  // 2560
  if (idx >= 2560) return;
  int l = idx >> 9, c = idx & 511;
  float v = 0.f;
  if (c >= 128 && c < 256) v = pre_b[l * 128 + (c - 128)];
  else if (c >= 384) v = pc_b1[l * 128 + (c - 384)];
  biasf[idx] = v;
}

// ---------------- weight prep: fold scalers + transpose + hi/lo split -----------
// ushort plane offsets (per layer stride 491520):
//  hprojT_hi 0 / lo 65536           [512][128]
//  WcT_hi 131072 / lo 147456        [128][128]
//  W2T_hi 163840 / lo 180224        [128][128]
//  WfoldT_hi 196608 / lo 344064     [128][1152]
//  outn1T_hi 2457600 / lo 2473984; outn2T_hi 2490368 / lo 2506752
__global__ __launch_bounds__(256) void fold_kernel(
    const float* __restrict__ pre_W, const float* __restrict__ pc_W1,
    const float* __restrict__ pc_W2, const float* __restrict__ post_W,
    const float* __restrict__ outn_W1, const float* __restrict__ outn_W2,
    unsigned short* __restrict__ wb) {
  int idx = blockIdx.x * 256 + threadIdx.x;  // 1,261,568 total
  const float C1 = 1.6094379124341003f;   // log 5
  const float C2 = 2.8332133440562162f;   // log 17
  float val;
  size_t ohi, olo;
  if (idx < 1228800) {
    int l = idx / 245760;
    int r = idx % 245760;
    size_t lb = (size_t)l * 491520;
    if (r < 65536) {  // hprojT [n=512][k=128]
      int n = r >> 7, k = r & 127;
      if (n < 128) val = pre_W[(size_t)l * 49152 + k * 128 + n];
      else if (n < 256) val = pre_W[(size_t)l * 49152 + (128 + k) * 128 + (n - 128)];
      else if (n < 384) val = pc_W1[(size_t)l * 32768 + k * 128 + (n - 256)];
      else val = pc_W1[(size_t)l * 32768 + (128 + k) * 128 + (n - 384)];
      ohi = lb + r; olo = ohi + 65536;
    } else if (r < 81920) {  // WcT
      int r2 = r - 65536; int n = r2 >> 7, k = r2 & 127;
      val = pre_W[(size_t)l * 49152 + (256 + k) * 128 + n];
      ohi = lb + 131072 + r2; olo = ohi + 16384;
    } else if (r < 98304) {  // W2T
      int r2 = r - 81920; int n = r2 >> 7, k = r2 & 127;
      val = pc_W2[(size_t)l * 16384 + k * 128 + n];
      ohi = lb + 163840 + r2; olo = ohi + 16384;
    } else {  // WfoldT [n=128][kk=1152]
      int r2 = r - 98304;
      int n = r2 / 1152, kk = r2 % 1152;
      const float* Wl = post_W + (size_t)l * 409600;
      if (kk < 128) val = Wl[kk * 128 + n];
      else if (kk < 640) {
        int j = kk - 128;
        val = Wl[(128 + j) * 128 + n] + C1 * Wl[(640 + j) * 128 + n] +
              (1.0f / C1) * Wl[(1152 + j) * 128 + n];
      } else {
        int j = kk - 640;
        val = Wl[(1664 + j) * 128 + n] + C2 * Wl[(2176 + j) * 128 + n] +
              (1.0f / C2) * Wl[(2688 + j) * 128 + n];
      }
      ohi = lb + 196608 + r2; olo = ohi + 147456;
    }
  } else {
    int r = idx - 1228800;
    if (r < 16384) {
      int n = r >> 7, k = r & 127;
      val = outn_W1[k * 128 + n];
      ohi = 2457600 + r; olo = ohi + 16384;
    } else {
      int r2 = r - 16384; int n = r2 >> 7, k = r2 & 127;
      val = outn_W2[k * 128 + n];
      ohi = 2490368 + r2; olo = ohi + 16384;
    }
  }
  unsigned short h, l2;
  cvt_hl(val, h, l2);
  wb[ohi] = h;
  wb[olo] = l2;
}

// ---------------- dense MFMA GEMM: Y[M,ntot] = X @ Wt^T (+bias)(+resid)(relu) ---------
// 256 threads / 4 waves; wave w owns cols [w*32, w*32+32).
// AMODE 0: A from fp32 X0 (cvt4).  AMODE 1: A from hi/lo planes.
// AMODE 2: k<K0 from hi/lo planes, k>=K0 from X1h (hi only).
// WPLANES: epilogue also emits Y as bf16 hi/lo planes (stride 128).
// KSPLIT>1: blockIdx.y = k-chunk; writes raw fp32 partials.
// PROJ=1: cols<256 -> fp32 Y (ystride 256); cols>=256 -> bf16-hi Yh[row*256+col-256].
template <int BM, int AMODE, bool RELU, bool RESID, bool WPLANES, int KSPLIT, int PROJ>
__global__ __launch_bounds__(256) void mgemm(
    const float* __restrict__ X0, int xs0,
    const unsigned short* __restrict__ Ah, const unsigned short* __restrict__ Al,
    int ahs, int K0,
    const unsigned short* __restrict__ X1h, int xs1,
    const unsigned short* __restrict__ Wth, const unsigned short* __restrict__ Wtl,
    const float* __restrict__ bias, const float* __restrict__ resid, int rstride,
    float* __restrict__ Y, int ystride,
    unsigned short* __restrict__ Yh, unsigned short* __restrict__ Yl, int K) {
  __shared__ unsigned short As_h[BM][40], As_l[BM][40];
  __shared__ unsigned short Bs_h[128][40], Bs_l[128][40];
  int tid = threadIdx.x;
  int wave = tid >> 6, lane = tid & 63, quad = lane >> 4, l15 = lane & 15;
  int row0 = blockIdx.x * BM;
  int n0, kbeg, kend;
  float* Yout = Y;
  if (KSPLIT > 1) {
    n0 = 0;
    int kc = K / KSPLIT;
    kbeg = blockIdx.y * kc;
    kend = kbeg + kc;
    Yout = Y + (size_t)blockIdx.y * N_NODES * 128;
  } else {
    n0 = blockIdx.y * 128;
    kbeg = 0;
    kend = K;
  }
  f32x4 acc[BM / 16][2];
#pragma unroll
  for (int mi = 0; mi < BM / 16; ++mi)
#pragma unroll
    for (int ni = 0; ni < 2; ++ni) acc[mi][ni] = (f32x4){0.f, 0.f, 0.f, 0.f};
  for (int kb = kbeg; kb < kend; kb += 32) {
    if (kb != kbeg) __syncthreads();
    bool haslo = (AMODE != 2) || (kb < K0);
    if (AMODE == 0) {
      for (int i = tid; i < BM * 8; i += 256) {
        int r = i >> 3, kq = i & 7;
        float4 v = *(const float4*)&X0[(size_t)(row0 + r) * xs0 + kb + kq * 4];
        uint2 th, tl;
        cvt4(v, th, tl);
        *(uint2*)&As_h[r][kq * 4] = th;
        *(uint2*)&As_l[r][kq * 4] = tl;
      }
    } else if (haslo) {
      for (int i = tid; i < BM * 4; i += 256) {
        int r = i >> 2, q = i & 3;
        size_t o = (size_t)(row0 + r) * ahs + kb + q * 8;
        *(uint4*)&As_h[r][q * 8] = *(const uint4*)&Ah[o];
        *(uint4*)&As_l[r][q * 8] = *(const uint4*)&Al[o];
      }
    } else {
      for (int i = tid; i < BM * 4; i += 256) {
        int r = i >> 2, q = i & 3;
        *(uint4*)&As_h[r][q * 8] =
            *(const uint4*)&X1h[(size_t)(row0 + r) * xs1 + (kb - K0) + q * 8];
      }
    }
    for (int i = tid; i < 512; i += 256) {
      int r = i >> 2, q = i & 3;
      size_t o = (size_t)(n0 + r) * K + kb + q * 8;
      *(uint4*)&Bs_h[r][q * 8] = *(const uint4*)&Wth[o];
      *(uint4*)&Bs_l[r][q * 8] = *(const uint4*)&Wtl[o];
    }
    __syncthreads();
    short8 bh[2], bl[2], ah[BM / 16], al[BM / 16];
#pragma unroll
    for (int ni = 0; ni < 2; ++ni) {
      bh[ni] = *(const short8*)&Bs_h[wave * 32 + ni * 16 + l15][quad * 8];
      bl[ni] = *(const short8*)&Bs_l[wave * 32 + ni * 16 + l15][quad * 8];
    }
#pragma unroll
    for (int mi = 0; mi < BM / 16; ++mi)
      ah[mi] = *(const short8*)&As_h[mi * 16 + l15][quad * 8];
    if (haslo) {
#pragma unroll
      for (int mi = 0; mi < BM / 16; ++mi)
        al[mi] = *(const short8*)&As_l[mi * 16 + l15][quad * 8];
    }
#pragma unroll
    for (int mi = 0; mi < BM / 16; ++mi)
#pragma unroll
      for (int ni = 0; ni < 2; ++ni) {
        acc[mi][ni] = MFMA16(ah[mi], bh[ni], acc[mi][ni]);
        acc[mi][ni] = MFMA16(ah[mi], bl[ni], acc[mi][ni]);
      }
    if (haslo) {
#pragma unroll
      for (int mi = 0; mi < BM / 16; ++mi)
#pragma unroll
        for (int ni = 0; ni < 2; ++ni)
          acc[mi][ni] = MFMA16(al[mi], bh[ni], acc[mi][ni]);
    }
  }
#pragma unroll
  for (int mi = 0; mi < BM / 16; ++mi)
#pragma unroll
    for (int ni = 0; ni < 2; ++ni) {
      int col = n0 + wave * 32 + ni * 16 + l15;
      if (KSPLIT > 1) {
#pragma unroll
        for (int r = 0; r < 4; ++r) {
          int row = row0 + mi * 16 + quad * 4 + r;
          Yout[(size_t)row * ystride + col] = acc[mi][ni][r];
        }
      } else if (PROJ == 1) {
        float bj = bias ? bias[col] : 0.f;
#pragma unroll
        for (int r = 0; r < 4; ++r) {
          int row = row0 + mi * 16 + quad * 4 + r;
          float v = acc[mi][ni][r] + bj;
          if (col < 256) Y[(size_t)row * 256 + col] = v;
          else Yh[(size_t)row * 256 + (col - 256)] = bf16rn(v);
        }
      } else {
        float bj = bias ? bias[col] : 0.f;
#pragma unroll
        for (int r = 0; r < 4; ++r) {
          int row = row0 + mi * 16 + quad * 4 + r;
          float v = acc[mi][ni][r] + bj;
          if (RESID) v += resid[(size_t)row * rstride + col];
          if (RELU) v = relu_f(v);
          Y[(size_t)row * ystride + col] = v;
          if (WPLANES) {
            unsigned short hh, ll;
            cvt_hl(v, hh, ll);
            Yh[(size_t)row * 128 + col] = hh;
            Yl[(size_t)row * 128 + col] = ll;
          }
        }
      }
    }
}

// ---------------- fused bond+comp: one dispatch, 2000 blocks --------------------------
// Blocks [0,400): bond path (128 bond edges each). Blocks [400,2000): comp path
// (128 comp edges each). Both: 512 thr / 8 waves x 16 edges, B-hi panel in 32KB
// fragment-major LDS, A bf16-hi in regs, 32 MFMA/wave, wave-local epilogues.
// hproj fp32 [12800][256] (cols 0-255); hp16 bf16 [12800][256] (cols 256-511).
#define BOND_BLOCKS 400
__global__ __launch_bounds__(512, 4) void bondcomp_mfma(
    const unsigned short* __restrict__ efph,
    const float* __restrict__ hproj, const unsigned short* __restrict__ hp16,
    const unsigned short* __restrict__ Wch, const unsigned short* __restrict__ W2h,
    const float* __restrict__ b2,
    const float* __restrict__ seW, const float* __restrict__ seb,
    const int* __restrict__ bond_src, const int* __restrict__ comp_src,
    unsigned short* __restrict__ aggp) {
  __shared__ uint4 Bf[2048];  // 32KB fragment-major B hi
  int tid = threadIdx.x;
  int wave = tid >> 6, lane = tid & 63, quad = lane >> 4, l15 = lane & 15;
  if (blockIdx.x < BOND_BLOCKS) {
    // ---------------- bond path ----------------
    int e0 = blockIdx.x * 128;
    int ew = e0 + wave * 16;
    short8 ah[4];
#pragma unroll
    for (int kb = 0; kb < 4; ++kb) {
      size_t o = (size_t)(ew + l15) * 128 + kb * 32 + quad * 8;
      ah[kb] = ld_s8((const uint4*)&efph[o]);
    }
    stage_Bh<512>(Wch, Bf, tid);
    __syncthreads();
    f32x4 acc[8];
#pragma unroll
    for (int ni = 0; ni < 8; ++ni) acc[ni] = (f32x4){0.f, 0.f, 0.f, 0.f};
#pragma unroll
    for (int kb = 0; kb < 4; ++kb) {
#pragma unroll
      for (int ni = 0; ni < 8; ++ni) {
        short8 bh = ld_s8(&Bf[(ni * 4 + kb) * 64 + lane]);
        acc[ni] = MFMA16(ah[kb], bh, acc[ni]);
      }
    }
    int node = (ew >> 2) + quad;
    int src_r[4];
#pragma unroll
    for (int r = 0; r < 4; ++r) src_r[r] = bond_src[ew + quad * 4 + r];
#pragma unroll
    for (int ni = 0; ni < 8; ++ni) {
      int c = ni * 16 + l15;
      float wbv = hproj[(size_t)node * 256 + 128 + c];  // includes pre_b
      float s = 0.f, sq = 0.f, mx = -1e30f, mn = 1e30f;
#pragma unroll
      for (int r = 0; r < 4; ++r) {
        float v = acc[ni][r] + wbv + hproj[(size_t)src_r[r] * 256 + c];
        s += v; sq += v * v; mx = fmaxf(mx, v); mn = fminf(mn, v);
      }
      float mean = s * 0.25f;
      float var = relu_f(sq * 0.25f - mean * mean);
      size_t base = (size_t)node * 1024 + c;
      aggp[base] = bf16rn(mean);
      aggp[base + 128] = bf16rn(mx);
      aggp[base + 256] = bf16rn(mn);
      aggp[base + 384] = bf16rn(sqrtf(var + 1e-5f));
    }
  } else {
    // ---------------- comp path ----------------
    int e0 = (blockIdx.x - BOND_BLOCKS) * 128;
    int e = e0 + wave * 16 + l15;
    int src = comp_src[e];
    int node = e >> 4;  // same node for whole wave
    const unsigned short* pa = hp16 + (size_t)src * 256;        // hA cols 0-127
    const unsigned short* pb = hp16 + (size_t)node * 256 + 128; // hB' cols 128-255
    short8 ah[4];
#pragma unroll
    for (int kb = 0; kb < 4; ++kb) {
      int k0 = kb * 32 + quad * 8;
      uint4 ua = *(const uint4*)&pa[k0];
      uint4 ub = *(const uint4*)&pb[k0];
      uint2 h0, h1;
      h0.x = pk2(relu_f(pk_lo_f(ua.x) + pk_lo_f(ub.x)),
                 relu_f(pk_hi_f(ua.x) + pk_hi_f(ub.x)));
      h0.y = pk2(relu_f(pk_lo_f(ua.y) + pk_lo_f(ub.y)),
                 relu_f(pk_hi_f(ua.y) + pk_hi_f(ub.y)));
      h1.x = pk2(relu_f(pk_lo_f(ua.z) + pk_lo_f(ub.z)),
                 relu_f(pk_hi_f(ua.z) + pk_hi_f(ub.z)));
      h1.y = pk2(relu_f(pk_lo_f(ua.w) + pk_lo_f(ub.w)),
                 relu_f(pk_hi_f(ua.w) + pk_hi_f(ub.w)));
      ah[kb] = mk_s8(h0, h1);
    }
    stage_Bh<512>(W2h, Bf, tid);
    __syncthreads();
    f32x4 acc[8];
#pragma unroll
    for (int ni = 0; ni < 8; ++ni) acc[ni] = (f32x4){0.f, 0.f, 0.f, 0.f};
#pragma unroll
    for (int kb = 0; kb < 4; ++kb) {
#pragma unroll
      for (int ni = 0; ni < 8; ++ni) {
        short8 bh = ld_s8(&Bf[(ni * 4 + kb) * 64 + lane]);
        acc[ni] = MFMA16(ah[kb], bh, acc[ni]);
      }
    }
    float b2v[8], swv[8];
#pragma unroll
    for (int ni = 0; ni < 8; ++ni) {
      int c = ni * 16 + l15;
      b2v[ni] = b2[c];
      swv[ni] = seW[c];
    }
    float seb0 = seb[0];
    float gate[4];
#pragma unroll
    for (int r = 0; r < 4; ++r) {
      float p = 0.f;
#pragma unroll
      for (int ni = 0; ni < 8; ++ni) p += (acc[ni][r] + b2v[ni]) * swv[ni];
      p += __shfl_xor(p, 1, 64);
      p += __shfl_xor(p, 2, 64);
      p += __shfl_xor(p, 4, 64);
      p += __shfl_xor(p, 8, 64);
      gate[r] = 1.f / (1.f + expf(-(p + seb0)));
    }
#pragma unroll
    for (int ni = 0; ni < 8; ++ni) {
      float s = 0.f, sq = 0.f, mx = -1e30f, mn = 1e30f;
#pragma unroll
      for (int r = 0; r < 4; ++r) {
        float v = (acc[ni][r] + b2v[ni]) * gate[r];
        s += v; sq += v * v; mx = fmaxf(mx, v); mn = fminf(mn, v);
      }
      s += __shfl_xor(s, 16, 64); sq += __shfl_xor(sq, 16, 64);
      mx = fmaxf(mx, __shfl_xor(mx, 16, 64)); mn = fminf(mn, __shfl_xor(mn, 16, 64));
      s += __shfl_xor(s, 32, 64); sq += __shfl_xor(sq, 32, 64);
      mx = fmaxf(mx, __shfl_xor(mx, 32, 64)); mn = fminf(mn, __shfl_xor(mn, 32, 64));
      if (quad == 0) {
        int c = ni * 16 + l15;
        float mean = s * 0.0625f;
        float var = relu_f(sq * 0.0625f - mean * mean);
        size_t base = (size_t)node * 1024 + 512 + c;
        aggp[base] = bf16rn(mean);
        aggp[base + 128] = bf16rn(mx);
        aggp[base + 256] = bf16rn(mn);
        aggp[base + 384] = bf16rn(sqrtf(var + 1e-5f));
      }
    }
  }
}

// ---------------- vector GEMM (readout MLP + node input projection) -------------------
template <bool RELU, bool RESID>
__global__ __launch_bounds__(256) void gemm_rrr(
    const float* __restrict__ X, int xstride, const float* __restrict__ W,
    const float* __restrict__ bias, const float* __restrict__ resid, int rstride,
    float* __restrict__ Y, int ystride, int Ktot) {
  __shared__ __align__(16) float Xs[32][68];
  __shared__ __align__(16) float Ws[64][128];
  int tid = threadIdx.x;
  int row0 = blockIdx.x * 32;
  int rg = tid >> 5;
  int c0 = (tid & 31) * 4;
  float acc[4][4] = {};
  for (int kb = 0; kb < Ktot; kb += 64) {
    __syncthreads();
    for (int i = tid; i < 32 * 64; i += 256) {
      int r = i >> 6, k = i & 63;
      Xs[r][k] = X[(size_t)(row0 + r) * xstride + kb + k];
    }
    for (int i = tid; i < 64 * 128; i += 256) {
      int k = i >> 7, c = i & 127;
      Ws[k][c] = W[(size_t)(kb + k) * 128 + c];
    }
    __syncthreads();
#pragma unroll
    for (int k4 = 0; k4 < 16; ++k4) {
      float4 w0 = *(const float4*)&Ws[k4 * 4 + 0][c0];
      float4 w1 = *(const float4*)&Ws[k4 * 4 + 1][c0];
      float4 w2 = *(const float4*)&Ws[k4 * 4 + 2][c0];
      float4 w3 = *(const float4*)&Ws[k4 * 4 + 3][c0];
#pragma unroll
      for (int r = 0; r < 4; ++r) {
        float4 x = *(const float4*)&Xs[rg * 4 + r][k4 * 4];
        acc[r][0] += x.x * w0.x + x.y * w1.x + x.z * w2.x + x.w * w3.x;
        acc[r][1] += x.x * w0.y + x.y * w1.y + x.z * w2.y + x.w * w3.y;
        acc[r][2] += x.x * w0.z + x.y * w1.z + x.z * w2.z + x.w * w3.z;
        acc[r][3] += x.x * w0.w + x.y * w1.w + x.z * w2.w + x.w * w3.w;
      }
    }
  }
  float bj[4] = {0.f, 0.f, 0.f, 0.f};
  if (bias) {
    bj[0] = bias[c0]; bj[1] = bias[c0 + 1]; bj[2] = bias[c0 + 2]; bj[3] = bias[c0 + 3];
  }
#pragma unroll
  for (int r = 0; r < 4; ++r) {
    int row = row0 + rg * 4 + r;
    float4 o;
    float* po = &o.x;
#pragma unroll
    for (int j = 0; j < 4; ++j) {
      float v = acc[r][j] + bj[j];
      if (RESID) v += resid[(size_t)row * rstride + c0 + j];
      if (RELU) v = relu_f(v);
      po[j] = v;
    }
    *(float4*)&Y[(size_t)row * ystride + c0] = o;
  }
}

// ---------------- readout + final ----------------------------------------------------
__global__ __launch_bounds__(128) void readout_kernel(const float* __restrict__ nodeout,
                                                      float* __restrict__ r) {
  int g = blockIdx.x, c = threadIdx.x;
  float s = 0.f, mx = -1e30f;
  for (int i = 0; i < 100; ++i) {
    float v = nodeout[(size_t)(g * 100 + i) * 128 + c];
    s += v; mx = fmaxf(mx, v);
  }
  r[g * 384 + c] = s;
  r[g * 384 + 128 + c] = s * 0.01f;
  r[g * 384 + 256 + c] = mx;
}

__global__ __launch_bounds__(256) void final_kernel(const float* __restrict__ roh,
                                                    const float* __restrict__ W2,
                                                    const float* __restrict__ b2,
                                                    float* __restrict__ out) {
  int idx = blockIdx.x * 256 + threadIdx.x;  // 4096
  int g = idx >> 5, c = idx & 31;
  float acc = b2[c];
  for (int k = 0; k < 128; ++k) acc += roh[g * 128 + k] * W2[k * 32 + c];
  out[idx] = acc;
}

extern "C" void kernel_launch(void* const* d_in, const int* in_sizes, int n_in,
                              void* d_out, int out_size, void* d_ws, size_t ws_size,
                              hipStream_t stream) {
  const float* node_feat = (const float*)d_in[0];
  const float* edge_feat = (const float*)d_in[1];
  const int* bond_src = (const int*)d_in[2];
  const int* comp_src = (const int*)d_in[4];
  const float* in_W = (const float*)d_in[7];
  const float* in_b = (const float*)d_in[8];
  const float* ein_W = (const float*)d_in[9];
  const float* ein_b = (const float*)d_in[10];
  const float* pre_W = (const float*)d_in[11];
  const float* pre_b = (const float*)d_in[12];
  const float* pc_W1 = (const float*)d_in[13];
  const float* pc_b1 = (const float*)d_in[14];
  const float* pc_W2 = (const float*)d_in[15];
  const float* pc_b2 = (const float*)d_in[16];
  const float* se_W = (const float*)d_in[17];
  const float* se_b = (const float*)d_in[18];
  const float* post_W = (const float*)d_in[19];
  const float* post_b = (const float*)d_in[20];
  const float* outn_W1 = (const float*)d_in[21];
  const float* outn_b1 = (const float*)d_in[22];
  const float* outn_W2 = (const float*)d_in[23];
  const float* outn_b2 = (const float*)d_in[24];
  const float* ro_W1 = (const float*)d_in[25];
  const float* ro_b1 = (const float*)d_in[26];
  const float* ro_W2 = (const float*)d_in[27];
  const float* ro_b2 = (const float*)d_in[28];

  float* ws = (float*)d_ws;
  float* hbuf = ws;                                    // 1,638,400
  float* hnew = ws + 1638400;                          // 1,638,400
  unsigned short* hcatp = (unsigned short*)(ws + 3276800);  // [12800][1024] ushort
  unsigned short* efph = (unsigned short*)(ws + 9830400);   // [51200][128] ushort
                                                       //   (ends at fl 13,107,200)
  unsigned short* hp16 = (unsigned short*)(ws + 13107200);  // [12800][256] ushort
  float* hproj = ws + 16384000;                        // [12800][256] fp32 (3,276,800)
                                                       //   + split-K partials alias
  unsigned short* wb = (unsigned short*)(ws + 22937600);    // 2,523,136 ushort
  float* tmp1 = ws + 24199168;                         // 1,638,400 (planesA in layers;
                                                       //   outn stage after)
  float* nodeout = ws + 25837568;                      // 1,638,400 (planesB in layers)
  float* rbuf = ws + 27475968;                         // 49,152 (biasf in layers)
  float* roh = ws + 27525120;                          // 16,384
  float* biasf = rbuf;                                 // [5][512] during layer loop only
  float* partials = hproj;                             // hproj/hp16 dead when post runs
  unsigned short* pAh = (unsigned short*)tmp1;         // [12800][128]
  unsigned short* pAl = pAh + 1638400;
  unsigned short* pBh = (unsigned short*)nodeout;
  unsigned short* pBl = pBh + 1638400;

  // node proj: tiled vector GEMM, then split to bf16 hi/lo planes
  gemm_rrr<true, false><<<400, 256, 0, stream>>>(node_feat, 64, in_W, in_b, nullptr, 0,
                                                 hbuf, 128, 64);
  h2planes<<<1600, 256, 0, stream>>>(hbuf, pAh, pAl);
  // edge proj: tiled, K=16 unrolled, bf16 hi plane only
  edge_proj_kernel<<<1600, 256, 0, stream>>>(edge_feat, ein_W, ein_b, efph);
  fold_kernel<<<4928, 256, 0, stream>>>(pre_W, pc_W1, pc_W2, post_W, outn_W1, outn_W2, wb);
  bias_kernel<<<10, 256, 0, stream>>>(pre_b, pc_b1, biasf);

  float* cur = hbuf;
  float* nxt = hnew;
  unsigned short *curh = pAh, *curl = pAl, *nxth = pBh, *nxtl = pBl;
  for (int l = 0; l < 5; ++l) {
    size_t lb = (size_t)l * 491520;
    const unsigned short* hpT_h = wb + lb;
    const unsigned short* hpT_l = wb + lb + 65536;
    const unsigned short* WcT_h = wb + lb + 131072;
    const unsigned short* W2T_h = wb + lb + 163840;
    const unsigned short* WfT_h = wb + lb + 196608;
    const unsigned short* WfT_l = wb + lb + 344064;

    mgemm<64, 1, false, false, false, 1, 1><<<dim3(200, 4), 256, 0, stream>>>(
        nullptr, 0, curh, curl, 128, 128, nullptr, 0, hpT_h, hpT_l,
        biasf + l * 512, nullptr, 0, hproj, 256, hp16, nullptr, 128);
    bondcomp_mfma<<<2000, 512, 0, stream>>>(efph, hproj, hp16, WcT_h, W2T_h,
                                            pc_b2 + l * 128, se_W + l * 128, se_b + l,
                                            bond_src, comp_src, hcatp);
    // post-GEMM split-K=3: partials, then fused reduce (+bias+resid+planes)
    mgemm<32, 2, false, false, false, 3, 0><<<dim3(400, 3), 256, 0, stream>>>(
        nullptr, 0, curh, curl, 128, 128, hcatp, 1024, WfT_h, WfT_l,
        nullptr, nullptr, 0, partials, 128, nullptr, nullptr, 1152);
    ksplit_reduce<<<1600, 256, 0, stream>>>(partials, post_b + l * 128, cur,
                                            nxt, nxth, nxtl);
    float* t = cur; cur = nxt; nxt = t;
    unsigned short* th = curh; curh = nxth; nxth = th;
    unsigned short* tl = curl; curl = nxtl; nxtl = tl;
  }
  mgemm<32, 0, true, false, false, 1, 0><<<dim3(400, 1), 256, 0, stream>>>(
      cur, 128, nullptr, nullptr, 0, 128, nullptr, 0, wb + 2457600, wb + 2473984,
      outn_b1, nullptr, 0, tmp1, 128, nullptr, nullptr, 128);
  mgemm<32, 0, false, false, false, 1, 0><<<dim3(400, 1), 256, 0, stream>>>(
      tmp1, 128, nullptr, nullptr, 0, 128, nullptr, 0, wb + 2490368, wb + 2506752,
      outn_b2, nullptr, 0, nodeout, 128, nullptr, nullptr, 128);
  readout_kernel<<<GRAPHS, 128, 0, stream>>>(nodeout, rbuf);
  gemm_rrr<true, false><<<4, 256, 0, stream>>>(rbuf, 384, ro_W1, ro_b1, nullptr, 0,
                                               roh, 128, 384);
  final_kernel<<<16, 256, 0, stream>>>(roh, ro_W2, ro_b2, (float*)d_out);
}

// Round 19
// 622.485 us; speedup vs baseline: 1.2100x; 1.0084x over previous
//
#include <hip/hip_runtime.h>
#include <math.h>

// PNA-EGNN forward, MI355X, round 19:
//  - hproj fully bf16: PROJ epilogue writes all 512 cols as bf16-hi into hp16
//    [12800][512]; fp32 hproj buffer gone. Bond epilogue gathers bf16 (bytes halve);
//    hproj write traffic 19.5->6.5MB.
//  - s_setprio(1) around bondcomp MFMA clusters (T5: phase-diverse waves here).
//  - bondcomp r17 single-tile form; outn BM=32 grid 400; post split-K=3 (r13);
//    h bf16 planes (r9).
// hcat agg plane stored as bf16-hi ushort [12800][1024]: [aggB(512)|aggC(512)].

#define N_NODES 12800
#define GRAPHS 128

typedef __attribute__((ext_vector_type(8))) short short8;
typedef __attribute__((ext_vector_type(4))) float f32x4;
#define MFMA16(a, b, c) __builtin_amdgcn_mfma_f32_16x16x32_bf16(a, b, c, 0, 0, 0)

static __device__ __forceinline__ float relu_f(float v) { return v > 0.0f ? v : 0.0f; }

static __device__ __forceinline__ unsigned short bf16rn(float x) {
  union { float f; unsigned u; } a; a.f = x;
  return (unsigned short)((a.u + 0x7fffu + ((a.u >> 16) & 1u)) >> 16);
}
static __device__ __forceinline__ float bf16tof(unsigned short h) {
  union { unsigned u; float f; } a; a.u = ((unsigned)h) << 16;
  return a.f;
}
static __device__ __forceinline__ void cvt_hl(float x, unsigned short& h, unsigned short& l) {
  h = bf16rn(x);
  l = bf16rn(x - bf16tof(h));
}

// packed 2xbf16 conversion: v_cvt_pk_bf16_f32 (no builtin on gfx950 -> inline asm)
static __device__ __forceinline__ unsigned pk2(float a, float b) {
  unsigned r;
  asm("v_cvt_pk_bf16_f32 %0, %1, %2" : "=v"(r) : "v"(a), "v"(b));
  return r;
}
static __device__ __forceinline__ float pk_lo_f(unsigned p) {
  union { unsigned u; float f; } a; a.u = p << 16; return a.f;
}
static __device__ __forceinline__ float pk_hi_f(unsigned p) {
  union { unsigned u; float f; } a; a.u = p & 0xffff0000u; return a.f;
}
// float4 -> hi-plane uint2 (4 bf16) + lo-plane uint2 (residuals)
static __device__ __forceinline__ void cvt4(float4 v, uint2& h, uint2& l) {
  h.x = pk2(v.x, v.y);
  h.y = pk2(v.z, v.w);
  l.x = pk2(v.x - pk_lo_f(h.x), v.y - pk_hi_f(h.x));
  l.y = pk2(v.z - pk_lo_f(h.y), v.w - pk_hi_f(h.y));
}

union U16 {
  uint4 u4;
  uint2 u2[2];
  short8 s8;
};
static __device__ __forceinline__ short8 mk_s8(uint2 a, uint2 b) {
  U16 t; t.u2[0] = a; t.u2[1] = b; return t.s8;
}
static __device__ __forceinline__ short8 ld_s8(const uint4* p) {
  U16 t; t.u4 = *p; return t.s8;
}

// Stage 128x128 ushort hi-plane into fragment-major LDS (2048 uint4 slots = 32KB):
// slot = (ni*4+kb)*64 + quad*16 + l15
template <int NT>
static __device__ __forceinline__ void stage_Bh(
    const unsigned short* __restrict__ Wh, uint4* __restrict__ Bf, int tid) {
  uint4 tmp[2048 / NT];
#pragma unroll
  for (int i = 0; i < 2048 / NT; ++i) {
    int slot = tid + i * NT;
    int l15n = slot & 15;
    int quad_s = (slot >> 4) & 3;
    int kbni = slot >> 6;
    int kb_s = kbni & 3;
    int ni_s = kbni >> 2;
    int n = ni_s * 16 + l15n;
    int k8 = kb_s * 4 + quad_s;
    tmp[i] = *(const uint4*)&Wh[n * 128 + k8 * 8];
  }
#pragma unroll
  for (int i = 0; i < 2048 / NT; ++i) Bf[tid + i * NT] = tmp[i];
}

// ---------------- fp32 [12800][128] -> bf16 hi/lo planes ------------------------------
__global__ __launch_bounds__(256) void h2planes(
    const float* __restrict__ X, unsigned short* __restrict__ Yh,
    unsigned short* __restrict__ Yl) {
  int idx = blockIdx.x * 256 + threadIdx.x;  // 409600 float4s
  float4 v = *(const float4*)&X[(size_t)idx * 4];
  uint2 h, l;
  cvt4(v, h, l);
  *(uint2*)&Yh[(size_t)idx * 4] = h;
  *(uint2*)&Yl[(size_t)idx * 4] = l;
}

// ---------------- split-K reduce: Y = p0+p1+p2 + bias + resid; planes out -------------
__global__ __launch_bounds__(256) void ksplit_reduce(
    const float* __restrict__ p, const float* __restrict__ bias,
    const float* __restrict__ resid, float* __restrict__ Y,
    unsigned short* __restrict__ Yh, unsigned short* __restrict__ Yl) {
  int idx = blockIdx.x * 256 + threadIdx.x;  // 409600 float4s
  const float4* p4 = (const float4*)p;
  float4 a = p4[idx];
  float4 b = p4[idx + 409600];
  float4 c = p4[idx + 819200];
  float4 rr = *(const float4*)&resid[(size_t)idx * 4];
  float4 bb = *(const float4*)&bias[(idx & 31) * 4];
  float4 v;
  v.x = a.x + b.x + c.x + rr.x + bb.x;
  v.y = a.y + b.y + c.y + rr.y + bb.y;
  v.z = a.z + b.z + c.z + rr.z + bb.z;
  v.w = a.w + b.w + c.w + rr.w + bb.w;
  *(float4*)&Y[(size_t)idx * 4] = v;
  uint2 h, l;
  cvt4(v, h, l);
  ((uint2*)Yh)[idx] = h;
  ((uint2*)Yl)[idx] = l;
}

// ---------------- edge input projection, tiled: Yh = bf16hi(relu(X@W + b)) ------------
// X [51200][16], W [16][128]. 32 rows/block, 16 outputs/thread, K=16 unrolled.
__global__ __launch_bounds__(256) void edge_proj_kernel(
    const float* __restrict__ X, const float* __restrict__ W,
    const float* __restrict__ bias, unsigned short* __restrict__ Yh) {
  __shared__ float Xs[32][17];
  __shared__ float Ws[16][128];
  int tid = threadIdx.x;
  int row0 = blockIdx.x * 32;
  for (int i = tid; i < 512; i += 256) {
    int r = i >> 4, k = i & 15;
    Xs[r][k] = X[(size_t)(row0 + r) * 16 + k];
  }
  for (int i = tid; i < 2048; i += 256) Ws[i >> 7][i & 127] = W[i];
  __syncthreads();
  int rg = tid >> 5;         // 4 rows each
  int c0 = (tid & 31) * 4;   // 4 cols
  float bj0 = bias[c0], bj1 = bias[c0 + 1], bj2 = bias[c0 + 2], bj3 = bias[c0 + 3];
#pragma unroll
  for (int rr = 0; rr < 4; ++rr) {
    int r = rg * 4 + rr;
    float a0 = bj0, a1 = bj1, a2 = bj2, a3 = bj3;
#pragma unroll
    for (int k = 0; k < 16; ++k) {
      float x = Xs[r][k];
      float4 w = *(const float4*)&Ws[k][c0];
      a0 += x * w.x; a1 += x * w.y; a2 += x * w.z; a3 += x * w.w;
    }
    uint2 h;
    h.x = pk2(relu_f(a0), relu_f(a1));
    h.y = pk2(relu_f(a2), relu_f(a3));
    *(uint2*)&Yh[(size_t)(row0 + r) * 128 + c0] = h;
  }
}

// ---------------- per-layer hproj bias: [5][512] = [0 | pre_b | 0 | pc_b1] ------------
__global__ __launch_bounds__(256) void bias_kernel(
    const float* __restrict__ pre_b, const float* __restrict__ pc_b1,
    float* __restrict__ biasf) {
  int idx = blockIdx.x * 256 + threadIdx.x;  // 2560
  if (idx >= 2560) return;
  int l = idx >> 9, c = idx & 511;
  float v = 0.f;
  if (c >= 128 && c < 256) v = pre_b[l * 128 + (c - 128)];
  else if (c >= 384) v = pc_b1[l * 128 + (c - 384)];
  biasf[idx] = v;
}

// ---------------- weight prep: fold scalers + transpose + hi/lo split -----------
// ushort plane offsets (per layer stride 491520):
//  hprojT_hi 0 / lo 65536           [512][128]
//  WcT_hi 131072 / lo 147456        [128][128]
//  W2T_hi 163840 / lo 180224        [128][128]
//  WfoldT_hi 196608 / lo 344064     [128][1152]
//  outn1T_hi 2457600 / lo 2473984; outn2T_hi 2490368 / lo 2506752
__global__ __launch_bounds__(256) void fold_kernel(
    const float* __restrict__ pre_W, const float* __restrict__ pc_W1,
    const float* __restrict__ pc_W2, const float* __restrict__ post_W,
    const float* __restrict__ outn_W1, const float* __restrict__ outn_W2,
    unsigned short* __restrict__ wb) {
  int idx = blockIdx.x * 256 + threadIdx.x;  // 1,261,568 total
  const float C1 = 1.6094379124341003f;   // log 5
  const float C2 = 2.8332133440562162f;   // log 17
  float val;
  size_t ohi, olo;
  if (idx < 1228800) {
    int l = idx / 245760;
    int r = idx % 245760;
    size_t lb = (size_t)l * 491520;
    if (r < 65536) {  // hprojT [n=512][k=128]
      int n = r >> 7, k = r & 127;
      if (n < 128) val = pre_W[(size_t)l * 49152 + k * 128 + n];
      else if (n < 256) val = pre_W[(size_t)l * 49152 + (128 + k) * 128 + (n - 128)];
      else if (n < 384) val = pc_W1[(size_t)l * 32768 + k * 128 + (n - 256)];
      else val = pc_W1[(size_t)l * 32768 + (128 + k) * 128 + (n - 384)];
      ohi = lb + r; olo = ohi + 65536;
    } else if (r < 81920) {  // WcT
      int r2 = r - 65536; int n = r2 >> 7, k = r2 & 127;
      val = pre_W[(size_t)l * 49152 + (256 + k) * 128 + n];
      ohi = lb + 131072 + r2; olo = ohi + 16384;
    } else if (r < 98304) {  // W2T
      int r2 = r - 81920; int n = r2 >> 7, k = r2 & 127;
      val = pc_W2[(size_t)l * 16384 + k * 128 + n];
      ohi = lb + 163840 + r2; olo = ohi + 16384;
    } else {  // WfoldT [n=128][kk=1152]
      int r2 = r - 98304;
      int n = r2 / 1152, kk = r2 % 1152;
      const float* Wl = post_W + (size_t)l * 409600;
      if (kk < 128) val = Wl[kk * 128 + n];
      else if (kk < 640) {
        int j = kk - 128;
        val = Wl[(128 + j) * 128 + n] + C1 * Wl[(640 + j) * 128 + n] +
              (1.0f / C1) * Wl[(1152 + j) * 128 + n];
      } else {
        int j = kk - 640;
        val = Wl[(1664 + j) * 128 + n] + C2 * Wl[(2176 + j) * 128 + n] +
              (1.0f / C2) * Wl[(2688 + j) * 128 + n];
      }
      ohi = lb + 196608 + r2; olo = ohi + 147456;
    }
  } else {
    int r = idx - 1228800;
    if (r < 16384) {
      int n = r >> 7, k = r & 127;
      val = outn_W1[k * 128 + n];
      ohi = 2457600 + r; olo = ohi + 16384;
    } else {
      int r2 = r - 16384; int n = r2 >> 7, k = r2 & 127;
      val = outn_W2[k * 128 + n];
      ohi = 2490368 + r2; olo = ohi + 16384;
    }
  }
  unsigned short h, l2;
  cvt_hl(val, h, l2);
  wb[ohi] = h;
  wb[olo] = l2;
}

// ---------------- dense MFMA GEMM: Y[M,ntot] = X @ Wt^T (+bias)(+resid)(relu) ---------
// 256 threads / 4 waves; wave w owns cols [w*32, w*32+32).
// AMODE 0: A from fp32 X0 (cvt4).  AMODE 1: A from hi/lo planes.
// AMODE 2: k<K0 from hi/lo planes, k>=K0 from X1h (hi only).
// WPLANES: epilogue also emits Y as bf16 hi/lo planes (stride 128).
// KSPLIT>1: blockIdx.y = k-chunk; writes raw fp32 partials.
// PROJ=1: ALL cols -> bf16-hi Yh[row*512+col].
template <int BM, int AMODE, bool RELU, bool RESID, bool WPLANES, int KSPLIT, int PROJ>
__global__ __launch_bounds__(256) void mgemm(
    const float* __restrict__ X0, int xs0,
    const unsigned short* __restrict__ Ah, const unsigned short* __restrict__ Al,
    int ahs, int K0,
    const unsigned short* __restrict__ X1h, int xs1,
    const unsigned short* __restrict__ Wth, const unsigned short* __restrict__ Wtl,
    const float* __restrict__ bias, const float* __restrict__ resid, int rstride,
    float* __restrict__ Y, int ystride,
    unsigned short* __restrict__ Yh, unsigned short* __restrict__ Yl, int K) {
  __shared__ unsigned short As_h[BM][40], As_l[BM][40];
  __shared__ unsigned short Bs_h[128][40], Bs_l[128][40];
  int tid = threadIdx.x;
  int wave = tid >> 6, lane = tid & 63, quad = lane >> 4, l15 = lane & 15;
  int row0 = blockIdx.x * BM;
  int n0, kbeg, kend;
  float* Yout = Y;
  if (KSPLIT > 1) {
    n0 = 0;
    int kc = K / KSPLIT;
    kbeg = blockIdx.y * kc;
    kend = kbeg + kc;
    Yout = Y + (size_t)blockIdx.y * N_NODES * 128;
  } else {
    n0 = blockIdx.y * 128;
    kbeg = 0;
    kend = K;
  }
  f32x4 acc[BM / 16][2];
#pragma unroll
  for (int mi = 0; mi < BM / 16; ++mi)
#pragma unroll
    for (int ni = 0; ni < 2; ++ni) acc[mi][ni] = (f32x4){0.f, 0.f, 0.f, 0.f};
  for (int kb = kbeg; kb < kend; kb += 32) {
    if (kb != kbeg) __syncthreads();
    bool haslo = (AMODE != 2) || (kb < K0);
    if (AMODE == 0) {
      for (int i = tid; i < BM * 8; i += 256) {
        int r = i >> 3, kq = i & 7;
        float4 v = *(const float4*)&X0[(size_t)(row0 + r) * xs0 + kb + kq * 4];
        uint2 th, tl;
        cvt4(v, th, tl);
        *(uint2*)&As_h[r][kq * 4] = th;
        *(uint2*)&As_l[r][kq * 4] = tl;
      }
    } else if (haslo) {
      for (int i = tid; i < BM * 4; i += 256) {
        int r = i >> 2, q = i & 3;
        size_t o = (size_t)(row0 + r) * ahs + kb + q * 8;
        *(uint4*)&As_h[r][q * 8] = *(const uint4*)&Ah[o];
        *(uint4*)&As_l[r][q * 8] = *(const uint4*)&Al[o];
      }
    } else {
      for (int i = tid; i < BM * 4; i += 256) {
        int r = i >> 2, q = i & 3;
        *(uint4*)&As_h[r][q * 8] =
            *(const uint4*)&X1h[(size_t)(row0 + r) * xs1 + (kb - K0) + q * 8];
      }
    }
    for (int i = tid; i < 512; i += 256) {
      int r = i >> 2, q = i & 3;
      size_t o = (size_t)(n0 + r) * K + kb + q * 8;
      *(uint4*)&Bs_h[r][q * 8] = *(const uint4*)&Wth[o];
      *(uint4*)&Bs_l[r][q * 8] = *(const uint4*)&Wtl[o];
    }
    __syncthreads();
    short8 bh[2], bl[2], ah[BM / 16], al[BM / 16];
#pragma unroll
    for (int ni = 0; ni < 2; ++ni) {
      bh[ni] = *(const short8*)&Bs_h[wave * 32 + ni * 16 + l15][quad * 8];
      bl[ni] = *(const short8*)&Bs_l[wave * 32 + ni * 16 + l15][quad * 8];
    }
#pragma unroll
    for (int mi = 0; mi < BM / 16; ++mi)
      ah[mi] = *(const short8*)&As_h[mi * 16 + l15][quad * 8];
    if (haslo) {
#pragma unroll
      for (int mi = 0; mi < BM / 16; ++mi)
        al[mi] = *(const short8*)&As_l[mi * 16 + l15][quad * 8];
    }
#pragma unroll
    for (int mi = 0; mi < BM / 16; ++mi)
#pragma unroll
      for (int ni = 0; ni < 2; ++ni) {
        acc[mi][ni] = MFMA16(ah[mi], bh[ni], acc[mi][ni]);
        acc[mi][ni] = MFMA16(ah[mi], bl[ni], acc[mi][ni]);
      }
    if (haslo) {
#pragma unroll
      for (int mi = 0; mi < BM / 16; ++mi)
#pragma unroll
        for (int ni = 0; ni < 2; ++ni)
          acc[mi][ni] = MFMA16(al[mi], bh[ni], acc[mi][ni]);
    }
  }
#pragma unroll
  for (int mi = 0; mi < BM / 16; ++mi)
#pragma unroll
    for (int ni = 0; ni < 2; ++ni) {
      int col = n0 + wave * 32 + ni * 16 + l15;
      if (KSPLIT > 1) {
#pragma unroll
        for (int r = 0; r < 4; ++r) {
          int row = row0 + mi * 16 + quad * 4 + r;
          Yout[(size_t)row * ystride + col] = acc[mi][ni][r];
        }
      } else if (PROJ == 1) {
        float bj = bias ? bias[col] : 0.f;
#pragma unroll
        for (int r = 0; r < 4; ++r) {
          int row = row0 + mi * 16 + quad * 4 + r;
          float v = acc[mi][ni][r] + bj;
          Yh[(size_t)row * 512 + col] = bf16rn(v);
        }
      } else {
        float bj = bias ? bias[col] : 0.f;
#pragma unroll
        for (int r = 0; r < 4; ++r) {
          int row = row0 + mi * 16 + quad * 4 + r;
          float v = acc[mi][ni][r] + bj;
          if (RESID) v += resid[(size_t)row * rstride + col];
          if (RELU) v = relu_f(v);
          Y[(size_t)row * ystride + col] = v;
          if (WPLANES) {
            unsigned short hh, ll;
            cvt_hl(v, hh, ll);
            Yh[(size_t)row * 128 + col] = hh;
            Yl[(size_t)row * 128 + col] = ll;
          }
        }
      }
    }
}

// ---------------- fused bond+comp: one dispatch, 2000 blocks --------------------------
// Blocks [0,400): bond path (128 bond edges each). Blocks [400,2000): comp path
// (128 comp edges each). Both: 512 thr / 8 waves x 16 edges, B-hi panel in 32KB
// fragment-major LDS, A bf16-hi in regs, 32 MFMA/wave (setprio-wrapped),
// wave-local epilogues. hp16 bf16-hi [12800][512] holds all hproj columns.
#define BOND_BLOCKS 400
__global__ __launch_bounds__(512, 4) void bondcomp_mfma(
    const unsigned short* __restrict__ efph,
    const unsigned short* __restrict__ hp16,
    const unsigned short* __restrict__ Wch, const unsigned short* __restrict__ W2h,
    const float* __restrict__ b2,
    const float* __restrict__ seW, const float* __restrict__ seb,
    const int* __restrict__ bond_src, const int* __restrict__ comp_src,
    unsigned short* __restrict__ aggp) {
  __shared__ uint4 Bf[2048];  // 32KB fragment-major B hi
  int tid = threadIdx.x;
  int wave = tid >> 6, lane = tid & 63, quad = lane >> 4, l15 = lane & 15;
  if (blockIdx.x < BOND_BLOCKS) {
    // ---------------- bond path ----------------
    int e0 = blockIdx.x * 128;
    int ew = e0 + wave * 16;
    short8 ah[4];
#pragma unroll
    for (int kb = 0; kb < 4; ++kb) {
      size_t o = (size_t)(ew + l15) * 128 + kb * 32 + quad * 8;
      ah[kb] = ld_s8((const uint4*)&efph[o]);
    }
    stage_Bh<512>(Wch, Bf, tid);
    __syncthreads();
    f32x4 acc[8];
#pragma unroll
    for (int ni = 0; ni < 8; ++ni) acc[ni] = (f32x4){0.f, 0.f, 0.f, 0.f};
    __builtin_amdgcn_s_setprio(1);
#pragma unroll
    for (int kb = 0; kb < 4; ++kb) {
#pragma unroll
      for (int ni = 0; ni < 8; ++ni) {
        short8 bh = ld_s8(&Bf[(ni * 4 + kb) * 64 + lane]);
        acc[ni] = MFMA16(ah[kb], bh, acc[ni]);
      }
    }
    __builtin_amdgcn_s_setprio(0);
    int node = (ew >> 2) + quad;
    int src_r[4];
#pragma unroll
    for (int r = 0; r < 4; ++r) src_r[r] = bond_src[ew + quad * 4 + r];
#pragma unroll
    for (int ni = 0; ni < 8; ++ni) {
      int c = ni * 16 + l15;
      float wbv = bf16tof(hp16[(size_t)node * 512 + 128 + c]);  // includes pre_b
      float s = 0.f, sq = 0.f, mx = -1e30f, mn = 1e30f;
#pragma unroll
      for (int r = 0; r < 4; ++r) {
        float v = acc[ni][r] + wbv + bf16tof(hp16[(size_t)src_r[r] * 512 + c]);
        s += v; sq += v * v; mx = fmaxf(mx, v); mn = fminf(mn, v);
      }
      float mean = s * 0.25f;
      float var = relu_f(sq * 0.25f - mean * mean);
      size_t base = (size_t)node * 1024 + c;
      aggp[base] = bf16rn(mean);
      aggp[base + 128] = bf16rn(mx);
      aggp[base + 256] = bf16rn(mn);
      aggp[base + 384] = bf16rn(sqrtf(var + 1e-5f));
    }
  } else {
    // ---------------- comp path ----------------
    int e0 = (blockIdx.x - BOND_BLOCKS) * 128;
    int e = e0 + wave * 16 + l15;
    int src = comp_src[e];
    int node = e >> 4;  // same node for whole wave
    const unsigned short* pa = hp16 + (size_t)src * 512 + 256;   // hA cols 256-383
    const unsigned short* pb = hp16 + (size_t)node * 512 + 384;  // hB' cols 384-511
    short8 ah[4];
#pragma unroll
    for (int kb = 0; kb < 4; ++kb) {
      int k0 = kb * 32 + quad * 8;
      uint4 ua = *(const uint4*)&pa[k0];
      uint4 ub = *(const uint4*)&pb[k0];
      uint2 h0, h1;
      h0.x = pk2(relu_f(pk_lo_f(ua.x) + pk_lo_f(ub.x)),
                 relu_f(pk_hi_f(ua.x) + pk_hi_f(ub.x)));
      h0.y = pk2(relu_f(pk_lo_f(ua.y) + pk_lo_f(ub.y)),
                 relu_f(pk_hi_f(ua.y) + pk_hi_f(ub.y)));
      h1.x = pk2(relu_f(pk_lo_f(ua.z) + pk_lo_f(ub.z)),
                 relu_f(pk_hi_f(ua.z) + pk_hi_f(ub.z)));
      h1.y = pk2(relu_f(pk_lo_f(ua.w) + pk_lo_f(ub.w)),
                 relu_f(pk_hi_f(ua.w) + pk_hi_f(ub.w)));
      ah[kb] = mk_s8(h0, h1);
    }
    stage_Bh<512>(W2h, Bf, tid);
    __syncthreads();
    f32x4 acc[8];
#pragma unroll
    for (int ni = 0; ni < 8; ++ni) acc[ni] = (f32x4){0.f, 0.f, 0.f, 0.f};
    __builtin_amdgcn_s_setprio(1);
#pragma unroll
    for (int kb = 0; kb < 4; ++kb) {
#pragma unroll
      for (int ni = 0; ni < 8; ++ni) {
        short8 bh = ld_s8(&Bf[(ni * 4 + kb) * 64 + lane]);
        acc[ni] = MFMA16(ah[kb], bh, acc[ni]);
      }
    }
    __builtin_amdgcn_s_setprio(0);
    float b2v[8], swv[8];
#pragma unroll
    for (int ni = 0; ni < 8; ++ni) {
      int c = ni * 16 + l15;
      b2v[ni] = b2[c];
      swv[ni] = seW[c];
    }
    float seb0 = seb[0];
    float gate[4];
#pragma unroll
    for (int r = 0; r < 4; ++r) {
      float p = 0.f;
#pragma unroll
      for (int ni = 0; ni < 8; ++ni) p += (acc[ni][r] + b2v[ni]) * swv[ni];
      p += __shfl_xor(p, 1, 64);
      p += __shfl_xor(p, 2, 64);
      p += __shfl_xor(p, 4, 64);
      p += __shfl_xor(p, 8, 64);
      gate[r] = 1.f / (1.f + expf(-(p + seb0)));
    }
#pragma unroll
    for (int ni = 0; ni < 8; ++ni) {
      float s = 0.f, sq = 0.f, mx = -1e30f, mn = 1e30f;
#pragma unroll
      for (int r = 0; r < 4; ++r) {
        float v = (acc[ni][r] + b2v[ni]) * gate[r];
        s += v; sq += v * v; mx = fmaxf(mx, v); mn = fminf(mn, v);
      }
      s += __shfl_xor(s, 16, 64); sq += __shfl_xor(sq, 16, 64);
      mx = fmaxf(mx, __shfl_xor(mx, 16, 64)); mn = fminf(mn, __shfl_xor(mn, 16, 64));
      s += __shfl_xor(s, 32, 64); sq += __shfl_xor(sq, 32, 64);
      mx = fmaxf(mx, __shfl_xor(mx, 32, 64)); mn = fminf(mn, __shfl_xor(mn, 32, 64));
      if (quad == 0) {
        int c = ni * 16 + l15;
        float mean = s * 0.0625f;
        float var = relu_f(sq * 0.0625f - mean * mean);
        size_t base = (size_t)node * 1024 + 512 + c;
        aggp[base] = bf16rn(mean);
        aggp[base + 128] = bf16rn(mx);
        aggp[base + 256] = bf16rn(mn);
        aggp[base + 384] = bf16rn(sqrtf(var + 1e-5f));
      }
    }
  }
}

// ---------------- vector GEMM (readout MLP + node input projection) -------------------
template <bool RELU, bool RESID>
__global__ __launch_bounds__(256) void gemm_rrr(
    const float* __restrict__ X, int xstride, const float* __restrict__ W,
    const float* __restrict__ bias, const float* __restrict__ resid, int rstride,
    float* __restrict__ Y, int ystride, int Ktot) {
  __shared__ __align__(16) float Xs[32][68];
  __shared__ __align__(16) float Ws[64][128];
  int tid = threadIdx.x;
  int row0 = blockIdx.x * 32;
  int rg = tid >> 5;
  int c0 = (tid & 31) * 4;
  float acc[4][4] = {};
  for (int kb = 0; kb < Ktot; kb += 64) {
    __syncthreads();
    for (int i = tid; i < 32 * 64; i += 256) {
      int r = i >> 6, k = i & 63;
      Xs[r][k] = X[(size_t)(row0 + r) * xstride + kb + k];
    }
    for (int i = tid; i < 64 * 128; i += 256) {
      int k = i >> 7, c = i & 127;
      Ws[k][c] = W[(size_t)(kb + k) * 128 + c];
    }
    __syncthreads();
#pragma unroll
    for (int k4 = 0; k4 < 16; ++k4) {
      float4 w0 = *(const float4*)&Ws[k4 * 4 + 0][c0];
      float4 w1 = *(const float4*)&Ws[k4 * 4 + 1][c0];
      float4 w2 = *(const float4*)&Ws[k4 * 4 + 2][c0];
      float4 w3 = *(const float4*)&Ws[k4 * 4 + 3][c0];
#pragma unroll
      for (int r = 0; r < 4; ++r) {
        float4 x = *(const float4*)&Xs[rg * 4 + r][k4 * 4];
        acc[r][0] += x.x * w0.x + x.y * w1.x + x.z * w2.x + x.w * w3.x;
        acc[r][1] += x.x * w0.y + x.y * w1.y + x.z * w2.y + x.w * w3.y;
        acc[r][2] += x.x * w0.z + x.y * w1.z + x.z * w2.z + x.w * w3.z;
        acc[r][3] += x.x * w0.w + x.y * w1.w + x.z * w2.w + x.w * w3.w;
      }
    }
  }
  float bj[4] = {0.f, 0.f, 0.f, 0.f};
  if (bias) {
    bj[0] = bias[c0]; bj[1] = bias[c0 + 1]; bj[2] = bias[c0 + 2]; bj[3] = bias[c0 + 3];
  }
#pragma unroll
  for (int r = 0; r < 4; ++r) {
    int row = row0 + rg * 4 + r;
    float4 o;
    float* po = &o.x;
#pragma unroll
    for (int j = 0; j < 4; ++j) {
      float v = acc[r][j] + bj[j];
      if (RESID) v += resid[(size_t)row * rstride + c0 + j];
      if (RELU) v = relu_f(v);
      po[j] = v;
    }
    *(float4*)&Y[(size_t)row * ystride + c0] = o;
  }
}

// ---------------- readout + final ----------------------------------------------------
__global__ __launch_bounds__(128) void readout_kernel(const float* __restrict__ nodeout,
                                                      float* __restrict__ r) {
  int g = blockIdx.x, c = threadIdx.x;
  float s = 0.f, mx = -1e30f;
  for (int i = 0; i < 100; ++i) {
    float v = nodeout[(size_t)(g * 100 + i) * 128 + c];
    s += v; mx = fmaxf(mx, v);
  }
  r[g * 384 + c] = s;
  r[g * 384 + 128 + c] = s * 0.01f;
  r[g * 384 + 256 + c] = mx;
}

__global__ __launch_bounds__(256) void final_kernel(const float* __restrict__ roh,
                                                    const float* __restrict__ W2,
                                                    const float* __restrict__ b2,
                                                    float* __restrict__ out) {
  int idx = blockIdx.x * 256 + threadIdx.x;  // 4096
  int g = idx >> 5, c = idx & 31;
  float acc = b2[c];
  for (int k = 0; k < 128; ++k) acc += roh[g * 128 + k] * W2[k * 32 + c];
  out[idx] = acc;
}

extern "C" void kernel_launch(void* const* d_in, const int* in_sizes, int n_in,
                              void* d_out, int out_size, void* d_ws, size_t ws_size,
                              hipStream_t stream) {
  const float* node_feat = (const float*)d_in[0];
  const float* edge_feat = (const float*)d_in[1];
  const int* bond_src = (const int*)d_in[2];
  const int* comp_src = (const int*)d_in[4];
  const float* in_W = (const float*)d_in[7];
  const float* in_b = (const float*)d_in[8];
  const float* ein_W = (const float*)d_in[9];
  const float* ein_b = (const float*)d_in[10];
  const float* pre_W = (const float*)d_in[11];
  const float* pre_b = (const float*)d_in[12];
  const float* pc_W1 = (const float*)d_in[13];
  const float* pc_b1 = (const float*)d_in[14];
  const float* pc_W2 = (const float*)d_in[15];
  const float* pc_b2 = (const float*)d_in[16];
  const float* se_W = (const float*)d_in[17];
  const float* se_b = (const float*)d_in[18];
  const float* post_W = (const float*)d_in[19];
  const float* post_b = (const float*)d_in[20];
  const float* outn_W1 = (const float*)d_in[21];
  const float* outn_b1 = (const float*)d_in[22];
  const float* outn_W2 = (const float*)d_in[23];
  const float* outn_b2 = (const float*)d_in[24];
  const float* ro_W1 = (const float*)d_in[25];
  const float* ro_b1 = (const float*)d_in[26];
  const float* ro_W2 = (const float*)d_in[27];
  const float* ro_b2 = (const float*)d_in[28];

  float* ws = (float*)d_ws;
  float* hbuf = ws;                                    // 1,638,400
  float* hnew = ws + 1638400;                          // 1,638,400
  unsigned short* hcatp = (unsigned short*)(ws + 3276800);  // [12800][1024] ushort
  unsigned short* efph = (unsigned short*)(ws + 9830400);   // [51200][128] ushort
                                                       //   (ends at fl 13,107,200)
  unsigned short* hp16 = (unsigned short*)(ws + 13107200);  // [12800][512] ushort
                                                       //   (3,276,800 fl, ends 16,384,000)
  float* partials = ws + 16384000;                     // 3 x 1,638,400 fp32 split-K
  unsigned short* wb = (unsigned short*)(ws + 22937600);    // 2,523,136 ushort
  float* tmp1 = ws + 24199168;                         // 1,638,400 (planesA in layers;
                                                       //   outn stage after)
  float* nodeout = ws + 25837568;                      // 1,638,400 (planesB in layers)
  float* rbuf = ws + 27475968;                         // 49,152 (biasf in layers)
  float* roh = ws + 27525120;                          // 16,384
  float* biasf = rbuf;                                 // [5][512] during layer loop only
  unsigned short* pAh = (unsigned short*)tmp1;         // [12800][128]
  unsigned short* pAl = pAh + 1638400;
  unsigned short* pBh = (unsigned short*)nodeout;
  unsigned short* pBl = pBh + 1638400;

  // node proj: tiled vector GEMM, then split to bf16 hi/lo planes
  gemm_rrr<true, false><<<400, 256, 0, stream>>>(node_feat, 64, in_W, in_b, nullptr, 0,
                                                 hbuf, 128, 64);
  h2planes<<<1600, 256, 0, stream>>>(hbuf, pAh, pAl);
  // edge proj: tiled, K=16 unrolled, bf16 hi plane only
  edge_proj_kernel<<<1600, 256, 0, stream>>>(edge_feat, ein_W, ein_b, efph);
  fold_kernel<<<4928, 256, 0, stream>>>(pre_W, pc_W1, pc_W2, post_W, outn_W1, outn_W2, wb);
  bias_kernel<<<10, 256, 0, stream>>>(pre_b, pc_b1, biasf);

  float* cur = hbuf;
  float* nxt = hnew;
  unsigned short *curh = pAh, *curl = pAl, *nxth = pBh, *nxtl = pBl;
  for (int l = 0; l < 5; ++l) {
    size_t lb = (size_t)l * 491520;
    const unsigned short* hpT_h = wb + lb;
    const unsigned short* hpT_l = wb + lb + 65536;
    const unsigned short* WcT_h = wb + lb + 131072;
    const unsigned short* W2T_h = wb + lb + 163840;
    const unsigned short* WfT_h = wb + lb + 196608;
    const unsigned short* WfT_l = wb + lb + 344064;

    mgemm<64, 1, false, false, false, 1, 1><<<dim3(200, 4), 256, 0, stream>>>(
        nullptr, 0, curh, curl, 128, 128, nullptr, 0, hpT_h, hpT_l,
        biasf + l * 512, nullptr, 0, nullptr, 512, hp16, nullptr, 128);
    bondcomp_mfma<<<2000, 512, 0, stream>>>(efph, hp16, WcT_h, W2T_h,
                                            pc_b2 + l * 128, se_W + l * 128, se_b + l,
                                            bond_src, comp_src, hcatp);
    // post-GEMM split-K=3: partials, then fused reduce (+bias+resid+planes)
    mgemm<32, 2, false, false, false, 3, 0><<<dim3(400, 3), 256, 0, stream>>>(
        nullptr, 0, curh, curl, 128, 128, hcatp, 1024, WfT_h, WfT_l,
        nullptr, nullptr, 0, partials, 128, nullptr, nullptr, 1152);
    ksplit_reduce<<<1600, 256, 0, stream>>>(partials, post_b + l * 128, cur,
                                            nxt, nxth, nxtl);
    float* t = cur; cur = nxt; nxt = t;
    unsigned short* th = curh; curh = nxth; nxth = th;
    unsigned short* tl = curl; curl = nxtl; nxtl = tl;
  }
  mgemm<32, 0, true, false, false, 1, 0><<<dim3(400, 1), 256, 0, stream>>>(
      cur, 128, nullptr, nullptr, 0, 128, nullptr, 0, wb + 2457600, wb + 2473984,
      outn_b1, nullptr, 0, tmp1, 128, nullptr, nullptr, 128);
  mgemm<32, 0, false, false, false, 1, 0><<<dim3(400, 1), 256, 0, stream>>>(
      tmp1, 128, nullptr, nullptr, 0, 128, nullptr, 0, wb + 2490368, wb + 2506752,
      outn_b2, nullptr, 0, nodeout, 128, nullptr, nullptr, 128);
  readout_kernel<<<GRAPHS, 128, 0, stream>>>(nodeout, rbuf);
  gemm_rrr<true, false><<<4, 256, 0, stream>>>(rbuf, 384, ro_W1, ro_b1, nullptr, 0,
                                               roh, 128, 384);
  final_kernel<<<16, 256, 0, stream>>>(roh, ro_W2, ro_b2, (float*)d_out);
}

// Round 20
// 615.621 us; speedup vs baseline: 1.2235x; 1.0112x over previous
//
#include <hip/hip_runtime.h>
#include <math.h>

// PNA-EGNN forward, MI355X, round 20:
//  - r19's s_setprio REMOVED (T5 is negative in barrier-lockstep kernels, per m190;
//    bondcomp waves hit MFMA in lockstep after the stage barrier). Single-change A/B.
//  - hproj fully bf16 hp16[12800][512] (r19, kept); bondcomp r17 single-tile form;
//    outn BM=32 grid 400; post split-K=3 (r13); h bf16 planes (r9).
// hcat agg plane stored as bf16-hi ushort [12800][1024]: [aggB(512)|aggC(512)].

#define N_NODES 12800
#define GRAPHS 128

typedef __attribute__((ext_vector_type(8))) short short8;
typedef __attribute__((ext_vector_type(4))) float f32x4;
#define MFMA16(a, b, c) __builtin_amdgcn_mfma_f32_16x16x32_bf16(a, b, c, 0, 0, 0)

static __device__ __forceinline__ float relu_f(float v) { return v > 0.0f ? v : 0.0f; }

static __device__ __forceinline__ unsigned short bf16rn(float x) {
  union { float f; unsigned u; } a; a.f = x;
  return (unsigned short)((a.u + 0x7fffu + ((a.u >> 16) & 1u)) >> 16);
}
static __device__ __forceinline__ float bf16tof(unsigned short h) {
  union { unsigned u; float f; } a; a.u = ((unsigned)h) << 16;
  return a.f;
}
static __device__ __forceinline__ void cvt_hl(float x, unsigned short& h, unsigned short& l) {
  h = bf16rn(x);
  l = bf16rn(x - bf16tof(h));
}

// packed 2xbf16 conversion: v_cvt_pk_bf16_f32 (no builtin on gfx950 -> inline asm)
static __device__ __forceinline__ unsigned pk2(float a, float b) {
  unsigned r;
  asm("v_cvt_pk_bf16_f32 %0, %1, %2" : "=v"(r) : "v"(a), "v"(b));
  return r;
}
static __device__ __forceinline__ float pk_lo_f(unsigned p) {
  union { unsigned u; float f; } a; a.u = p << 16; return a.f;
}
static __device__ __forceinline__ float pk_hi_f(unsigned p) {
  union { unsigned u; float f; } a; a.u = p & 0xffff0000u; return a.f;
}
// float4 -> hi-plane uint2 (4 bf16) + lo-plane uint2 (residuals)
static __device__ __forceinline__ void cvt4(float4 v, uint2& h, uint2& l) {
  h.x = pk2(v.x, v.y);
  h.y = pk2(v.z, v.w);
  l.x = pk2(v.x - pk_lo_f(h.x), v.y - pk_hi_f(h.x));
  l.y = pk2(v.z - pk_lo_f(h.y), v.w - pk_hi_f(h.y));
}

union U16 {
  uint4 u4;
  uint2 u2[2];
  short8 s8;
};
static __device__ __forceinline__ short8 mk_s8(uint2 a, uint2 b) {
  U16 t; t.u2[0] = a; t.u2[1] = b; return t.s8;
}
static __device__ __forceinline__ short8 ld_s8(const uint4* p) {
  U16 t; t.u4 = *p; return t.s8;
}

// Stage 128x128 ushort hi-plane into fragment-major LDS (2048 uint4 slots = 32KB):
// slot = (ni*4+kb)*64 + quad*16 + l15
template <int NT>
static __device__ __forceinline__ void stage_Bh(
    const unsigned short* __restrict__ Wh, uint4* __restrict__ Bf, int tid) {
  uint4 tmp[2048 / NT];
#pragma unroll
  for (int i = 0; i < 2048 / NT; ++i) {
    int slot = tid + i * NT;
    int l15n = slot & 15;
    int quad_s = (slot >> 4) & 3;
    int kbni = slot >> 6;
    int kb_s = kbni & 3;
    int ni_s = kbni >> 2;
    int n = ni_s * 16 + l15n;
    int k8 = kb_s * 4 + quad_s;
    tmp[i] = *(const uint4*)&Wh[n * 128 + k8 * 8];
  }
#pragma unroll
  for (int i = 0; i < 2048 / NT; ++i) Bf[tid + i * NT] = tmp[i];
}

// ---------------- fp32 [12800][128] -> bf16 hi/lo planes ------------------------------
__global__ __launch_bounds__(256) void h2planes(
    const float* __restrict__ X, unsigned short* __restrict__ Yh,
    unsigned short* __restrict__ Yl) {
  int idx = blockIdx.x * 256 + threadIdx.x;  // 409600 float4s
  float4 v = *(const float4*)&X[(size_t)idx * 4];
  uint2 h, l;
  cvt4(v, h, l);
  *(uint2*)&Yh[(size_t)idx * 4] = h;
  *(uint2*)&Yl[(size_t)idx * 4] = l;
}

// ---------------- split-K reduce: Y = p0+p1+p2 + bias + resid; planes out -------------
__global__ __launch_bounds__(256) void ksplit_reduce(
    const float* __restrict__ p, const float* __restrict__ bias,
    const float* __restrict__ resid, float* __restrict__ Y,
    unsigned short* __restrict__ Yh, unsigned short* __restrict__ Yl) {
  int idx = blockIdx.x * 256 + threadIdx.x;  // 409600 float4s
  const float4* p4 = (const float4*)p;
  float4 a = p4[idx];
  float4 b = p4[idx + 409600];
  float4 c = p4[idx + 819200];
  float4 rr = *(const float4*)&resid[(size_t)idx * 4];
  float4 bb = *(const float4*)&bias[(idx & 31) * 4];
  float4 v;
  v.x = a.x + b.x + c.x + rr.x + bb.x;
  v.y = a.y + b.y + c.y + rr.y + bb.y;
  v.z = a.z + b.z + c.z + rr.z + bb.z;
  v.w = a.w + b.w + c.w + rr.w + bb.w;
  *(float4*)&Y[(size_t)idx * 4] = v;
  uint2 h, l;
  cvt4(v, h, l);
  ((uint2*)Yh)[idx] = h;
  ((uint2*)Yl)[idx] = l;
}

// ---------------- edge input projection, tiled: Yh = bf16hi(relu(X@W + b)) ------------
// X [51200][16], W [16][128]. 32 rows/block, 16 outputs/thread, K=16 unrolled.
__global__ __launch_bounds__(256) void edge_proj_kernel(
    const float* __restrict__ X, const float* __restrict__ W,
    const float* __restrict__ bias, unsigned short* __restrict__ Yh) {
  __shared__ float Xs[32][17];
  __shared__ float Ws[16][128];
  int tid = threadIdx.x;
  int row0 = blockIdx.x * 32;
  for (int i = tid; i < 512; i += 256) {
    int r = i >> 4, k = i & 15;
    Xs[r][k] = X[(size_t)(row0 + r) * 16 + k];
  }
  for (int i = tid; i < 2048; i += 256) Ws[i >> 7][i & 127] = W[i];
  __syncthreads();
  int rg = tid >> 5;         // 4 rows each
  int c0 = (tid & 31) * 4;   // 4 cols
  float bj0 = bias[c0], bj1 = bias[c0 + 1], bj2 = bias[c0 + 2], bj3 = bias[c0 + 3];
#pragma unroll
  for (int rr = 0; rr < 4; ++rr) {
    int r = rg * 4 + rr;
    float a0 = bj0, a1 = bj1, a2 = bj2, a3 = bj3;
#pragma unroll
    for (int k = 0; k < 16; ++k) {
      float x = Xs[r][k];
      float4 w = *(const float4*)&Ws[k][c0];
      a0 += x * w.x; a1 += x * w.y; a2 += x * w.z; a3 += x * w.w;
    }
    uint2 h;
    h.x = pk2(relu_f(a0), relu_f(a1));
    h.y = pk2(relu_f(a2), relu_f(a3));
    *(uint2*)&Yh[(size_t)(row0 + r) * 128 + c0] = h;
  }
}

// ---------------- per-layer hproj bias: [5][512] = [0 | pre_b | 0 | pc_b1] ------------
__global__ __launch_bounds__(256) void bias_kernel(
    const float* __restrict__ pre_b, const float* __restrict__ pc_b1,
    float* __restrict__ biasf) {
  int idx = blockIdx.x * 256 + threadIdx.x;  // 2560
  if (idx >= 2560) return;
  int l = idx >> 9, c = idx & 511;
  float v = 0.f;
  if (c >= 128 && c < 256) v = pre_b[l * 128 + (c - 128)];
  else if (c >= 384) v = pc_b1[l * 128 + (c - 384)];
  biasf[idx] = v;
}

// ---------------- weight prep: fold scalers + transpose + hi/lo split -----------
// ushort plane offsets (per layer stride 491520):
//  hprojT_hi 0 / lo 65536           [512][128]
//  WcT_hi 131072 / lo 147456        [128][128]
//  W2T_hi 163840 / lo 180224        [128][128]
//  WfoldT_hi 196608 / lo 344064     [128][1152]
//  outn1T_hi 2457600 / lo 2473984; outn2T_hi 2490368 / lo 2506752
__global__ __launch_bounds__(256) void fold_kernel(
    const float* __restrict__ pre_W, const float* __restrict__ pc_W1,
    const float* __restrict__ pc_W2, const float* __restrict__ post_W,
    const float* __restrict__ outn_W1, const float* __restrict__ outn_W2,
    unsigned short* __restrict__ wb) {
  int idx = blockIdx.x * 256 + threadIdx.x;  // 1,261,568 total
  const float C1 = 1.6094379124341003f;   // log 5
  const float C2 = 2.8332133440562162f;   // log 17
  float val;
  size_t ohi, olo;
  if (idx < 1228800) {
    int l = idx / 245760;
    int r = idx % 245760;
    size_t lb = (size_t)l * 491520;
    if (r < 65536) {  // hprojT [n=512][k=128]
      int n = r >> 7, k = r & 127;
      if (n < 128) val = pre_W[(size_t)l * 49152 + k * 128 + n];
      else if (n < 256) val = pre_W[(size_t)l * 49152 + (128 + k) * 128 + (n - 128)];
      else if (n < 384) val = pc_W1[(size_t)l * 32768 + k * 128 + (n - 256)];
      else val = pc_W1[(size_t)l * 32768 + (128 + k) * 128 + (n - 384)];
      ohi = lb + r; olo = ohi + 65536;
    } else if (r < 81920) {  // WcT
      int r2 = r - 65536; int n = r2 >> 7, k = r2 & 127;
      val = pre_W[(size_t)l * 49152 + (256 + k) * 128 + n];
      ohi = lb + 131072 + r2; olo = ohi + 16384;
    } else if (r < 98304) {  // W2T
      int r2 = r - 81920; int n = r2 >> 7, k = r2 & 127;
      val = pc_W2[(size_t)l * 16384 + k * 128 + n];
      ohi = lb + 163840 + r2; olo = ohi + 16384;
    } else {  // WfoldT [n=128][kk=1152]
      int r2 = r - 98304;
      int n = r2 / 1152, kk = r2 % 1152;
      const float* Wl = post_W + (size_t)l * 409600;
      if (kk < 128) val = Wl[kk * 128 + n];
      else if (kk < 640) {
        int j = kk - 128;
        val = Wl[(128 + j) * 128 + n] + C1 * Wl[(640 + j) * 128 + n] +
              (1.0f / C1) * Wl[(1152 + j) * 128 + n];
      } else {
        int j = kk - 640;
        val = Wl[(1664 + j) * 128 + n] + C2 * Wl[(2176 + j) * 128 + n] +
              (1.0f / C2) * Wl[(2688 + j) * 128 + n];
      }
      ohi = lb + 196608 + r2; olo = ohi + 147456;
    }
  } else {
    int r = idx - 1228800;
    if (r < 16384) {
      int n = r >> 7, k = r & 127;
      val = outn_W1[k * 128 + n];
      ohi = 2457600 + r; olo = ohi + 16384;
    } else {
      int r2 = r - 16384; int n = r2 >> 7, k = r2 & 127;
      val = outn_W2[k * 128 + n];
      ohi = 2490368 + r2; olo = ohi + 16384;
    }
  }
  unsigned short h, l2;
  cvt_hl(val, h, l2);
  wb[ohi] = h;
  wb[olo] = l2;
}

// ---------------- dense MFMA GEMM: Y[M,ntot] = X @ Wt^T (+bias)(+resid)(relu) ---------
// 256 threads / 4 waves; wave w owns cols [w*32, w*32+32).
// AMODE 0: A from fp32 X0 (cvt4).  AMODE 1: A from hi/lo planes.
// AMODE 2: k<K0 from hi/lo planes, k>=K0 from X1h (hi only).
// WPLANES: epilogue also emits Y as bf16 hi/lo planes (stride 128).
// KSPLIT>1: blockIdx.y = k-chunk; writes raw fp32 partials.
// PROJ=1: ALL cols -> bf16-hi Yh[row*512+col].
template <int BM, int AMODE, bool RELU, bool RESID, bool WPLANES, int KSPLIT, int PROJ>
__global__ __launch_bounds__(256) void mgemm(
    const float* __restrict__ X0, int xs0,
    const unsigned short* __restrict__ Ah, const unsigned short* __restrict__ Al,
    int ahs, int K0,
    const unsigned short* __restrict__ X1h, int xs1,
    const unsigned short* __restrict__ Wth, const unsigned short* __restrict__ Wtl,
    const float* __restrict__ bias, const float* __restrict__ resid, int rstride,
    float* __restrict__ Y, int ystride,
    unsigned short* __restrict__ Yh, unsigned short* __restrict__ Yl, int K) {
  __shared__ unsigned short As_h[BM][40], As_l[BM][40];
  __shared__ unsigned short Bs_h[128][40], Bs_l[128][40];
  int tid = threadIdx.x;
  int wave = tid >> 6, lane = tid & 63, quad = lane >> 4, l15 = lane & 15;
  int row0 = blockIdx.x * BM;
  int n0, kbeg, kend;
  float* Yout = Y;
  if (KSPLIT > 1) {
    n0 = 0;
    int kc = K / KSPLIT;
    kbeg = blockIdx.y * kc;
    kend = kbeg + kc;
    Yout = Y + (size_t)blockIdx.y * N_NODES * 128;
  } else {
    n0 = blockIdx.y * 128;
    kbeg = 0;
    kend = K;
  }
  f32x4 acc[BM / 16][2];
#pragma unroll
  for (int mi = 0; mi < BM / 16; ++mi)
#pragma unroll
    for (int ni = 0; ni < 2; ++ni) acc[mi][ni] = (f32x4){0.f, 0.f, 0.f, 0.f};
  for (int kb = kbeg; kb < kend; kb += 32) {
    if (kb != kbeg) __syncthreads();
    bool haslo = (AMODE != 2) || (kb < K0);
    if (AMODE == 0) {
      for (int i = tid; i < BM * 8; i += 256) {
        int r = i >> 3, kq = i & 7;
        float4 v = *(const float4*)&X0[(size_t)(row0 + r) * xs0 + kb + kq * 4];
        uint2 th, tl;
        cvt4(v, th, tl);
        *(uint2*)&As_h[r][kq * 4] = th;
        *(uint2*)&As_l[r][kq * 4] = tl;
      }
    } else if (haslo) {
      for (int i = tid; i < BM * 4; i += 256) {
        int r = i >> 2, q = i & 3;
        size_t o = (size_t)(row0 + r) * ahs + kb + q * 8;
        *(uint4*)&As_h[r][q * 8] = *(const uint4*)&Ah[o];
        *(uint4*)&As_l[r][q * 8] = *(const uint4*)&Al[o];
      }
    } else {
      for (int i = tid; i < BM * 4; i += 256) {
        int r = i >> 2, q = i & 3;
        *(uint4*)&As_h[r][q * 8] =
            *(const uint4*)&X1h[(size_t)(row0 + r) * xs1 + (kb - K0) + q * 8];
      }
    }
    for (int i = tid; i < 512; i += 256) {
      int r = i >> 2, q = i & 3;
      size_t o = (size_t)(n0 + r) * K + kb + q * 8;
      *(uint4*)&Bs_h[r][q * 8] = *(const uint4*)&Wth[o];
      *(uint4*)&Bs_l[r][q * 8] = *(const uint4*)&Wtl[o];
    }
    __syncthreads();
    short8 bh[2], bl[2], ah[BM / 16], al[BM / 16];
#pragma unroll
    for (int ni = 0; ni < 2; ++ni) {
      bh[ni] = *(const short8*)&Bs_h[wave * 32 + ni * 16 + l15][quad * 8];
      bl[ni] = *(const short8*)&Bs_l[wave * 32 + ni * 16 + l15][quad * 8];
    }
#pragma unroll
    for (int mi = 0; mi < BM / 16; ++mi)
      ah[mi] = *(const short8*)&As_h[mi * 16 + l15][quad * 8];
    if (haslo) {
#pragma unroll
      for (int mi = 0; mi < BM / 16; ++mi)
        al[mi] = *(const short8*)&As_l[mi * 16 + l15][quad * 8];
    }
#pragma unroll
    for (int mi = 0; mi < BM / 16; ++mi)
#pragma unroll
      for (int ni = 0; ni < 2; ++ni) {
        acc[mi][ni] = MFMA16(ah[mi], bh[ni], acc[mi][ni]);
        acc[mi][ni] = MFMA16(ah[mi], bl[ni], acc[mi][ni]);
      }
    if (haslo) {
#pragma unroll
      for (int mi = 0; mi < BM / 16; ++mi)
#pragma unroll
        for (int ni = 0; ni < 2; ++ni)
          acc[mi][ni] = MFMA16(al[mi], bh[ni], acc[mi][ni]);
    }
  }
#pragma unroll
  for (int mi = 0; mi < BM / 16; ++mi)
#pragma unroll
    for (int ni = 0; ni < 2; ++ni) {
      int col = n0 + wave * 32 + ni * 16 + l15;
      if (KSPLIT > 1) {
#pragma unroll
        for (int r = 0; r < 4; ++r) {
          int row = row0 + mi * 16 + quad * 4 + r;
          Yout[(size_t)row * ystride + col] = acc[mi][ni][r];
        }
      } else if (PROJ == 1) {
        float bj = bias ? bias[col] : 0.f;
#pragma unroll
        for (int r = 0; r < 4; ++r) {
          int row = row0 + mi * 16 + quad * 4 + r;
          float v = acc[mi][ni][r] + bj;
          Yh[(size_t)row * 512 + col] = bf16rn(v);
        }
      } else {
        float bj = bias ? bias[col] : 0.f;
#pragma unroll
        for (int r = 0; r < 4; ++r) {
          int row = row0 + mi * 16 + quad * 4 + r;
          float v = acc[mi][ni][r] + bj;
          if (RESID) v += resid[(size_t)row * rstride + col];
          if (RELU) v = relu_f(v);
          Y[(size_t)row * ystride + col] = v;
          if (WPLANES) {
            unsigned short hh, ll;
            cvt_hl(v, hh, ll);
            Yh[(size_t)row * 128 + col] = hh;
            Yl[(size_t)row * 128 + col] = ll;
          }
        }
      }
    }
}

// ---------------- fused bond+comp: one dispatch, 2000 blocks --------------------------
// Blocks [0,400): bond path (128 bond edges each). Blocks [400,2000): comp path
// (128 comp edges each). Both: 512 thr / 8 waves x 16 edges, B-hi panel in 32KB
// fragment-major LDS, A bf16-hi in regs, 32 MFMA/wave, wave-local epilogues.
// hp16 bf16-hi [12800][512] holds all hproj columns.
#define BOND_BLOCKS 400
__global__ __launch_bounds__(512, 4) void bondcomp_mfma(
    const unsigned short* __restrict__ efph,
    const unsigned short* __restrict__ hp16,
    const unsigned short* __restrict__ Wch, const unsigned short* __restrict__ W2h,
    const float* __restrict__ b2,
    const float* __restrict__ seW, const float* __restrict__ seb,
    const int* __restrict__ bond_src, const int* __restrict__ comp_src,
    unsigned short* __restrict__ aggp) {
  __shared__ uint4 Bf[2048];  // 32KB fragment-major B hi
  int tid = threadIdx.x;
  int wave = tid >> 6, lane = tid & 63, quad = lane >> 4, l15 = lane & 15;
  if (blockIdx.x < BOND_BLOCKS) {
    // ---------------- bond path ----------------
    int e0 = blockIdx.x * 128;
    int ew = e0 + wave * 16;
    short8 ah[4];
#pragma unroll
    for (int kb = 0; kb < 4; ++kb) {
      size_t o = (size_t)(ew + l15) * 128 + kb * 32 + quad * 8;
      ah[kb] = ld_s8((const uint4*)&efph[o]);
    }
    stage_Bh<512>(Wch, Bf, tid);
    __syncthreads();
    f32x4 acc[8];
#pragma unroll
    for (int ni = 0; ni < 8; ++ni) acc[ni] = (f32x4){0.f, 0.f, 0.f, 0.f};
#pragma unroll
    for (int kb = 0; kb < 4; ++kb) {
#pragma unroll
      for (int ni = 0; ni < 8; ++ni) {
        short8 bh = ld_s8(&Bf[(ni * 4 + kb) * 64 + lane]);
        acc[ni] = MFMA16(ah[kb], bh, acc[ni]);
      }
    }
    int node = (ew >> 2) + quad;
    int src_r[4];
#pragma unroll
    for (int r = 0; r < 4; ++r) src_r[r] = bond_src[ew + quad * 4 + r];
#pragma unroll
    for (int ni = 0; ni < 8; ++ni) {
      int c = ni * 16 + l15;
      float wbv = bf16tof(hp16[(size_t)node * 512 + 128 + c]);  // includes pre_b
      float s = 0.f, sq = 0.f, mx = -1e30f, mn = 1e30f;
#pragma unroll
      for (int r = 0; r < 4; ++r) {
        float v = acc[ni][r] + wbv + bf16tof(hp16[(size_t)src_r[r] * 512 + c]);
        s += v; sq += v * v; mx = fmaxf(mx, v); mn = fminf(mn, v);
      }
      float mean = s * 0.25f;
      float var = relu_f(sq * 0.25f - mean * mean);
      size_t base = (size_t)node * 1024 + c;
      aggp[base] = bf16rn(mean);
      aggp[base + 128] = bf16rn(mx);
      aggp[base + 256] = bf16rn(mn);
      aggp[base + 384] = bf16rn(sqrtf(var + 1e-5f));
    }
  } else {
    // ---------------- comp path ----------------
    int e0 = (blockIdx.x - BOND_BLOCKS) * 128;
    int e = e0 + wave * 16 + l15;
    int src = comp_src[e];
    int node = e >> 4;  // same node for whole wave
    const unsigned short* pa = hp16 + (size_t)src * 512 + 256;   // hA cols 256-383
    const unsigned short* pb = hp16 + (size_t)node * 512 + 384;  // hB' cols 384-511
    short8 ah[4];
#pragma unroll
    for (int kb = 0; kb < 4; ++kb) {
      int k0 = kb * 32 + quad * 8;
      uint4 ua = *(const uint4*)&pa[k0];
      uint4 ub = *(const uint4*)&pb[k0];
      uint2 h0, h1;
      h0.x = pk2(relu_f(pk_lo_f(ua.x) + pk_lo_f(ub.x)),
                 relu_f(pk_hi_f(ua.x) + pk_hi_f(ub.x)));
      h0.y = pk2(relu_f(pk_lo_f(ua.y) + pk_lo_f(ub.y)),
                 relu_f(pk_hi_f(ua.y) + pk_hi_f(ub.y)));
      h1.x = pk2(relu_f(pk_lo_f(ua.z) + pk_lo_f(ub.z)),
                 relu_f(pk_hi_f(ua.z) + pk_hi_f(ub.z)));
      h1.y = pk2(relu_f(pk_lo_f(ua.w) + pk_lo_f(ub.w)),
                 relu_f(pk_hi_f(ua.w) + pk_hi_f(ub.w)));
      ah[kb] = mk_s8(h0, h1);
    }
    stage_Bh<512>(W2h, Bf, tid);
    __syncthreads();
    f32x4 acc[8];
#pragma unroll
    for (int ni = 0; ni < 8; ++ni) acc[ni] = (f32x4){0.f, 0.f, 0.f, 0.f};
#pragma unroll
    for (int kb = 0; kb < 4; ++kb) {
#pragma unroll
      for (int ni = 0; ni < 8; ++ni) {
        short8 bh = ld_s8(&Bf[(ni * 4 + kb) * 64 + lane]);
        acc[ni] = MFMA16(ah[kb], bh, acc[ni]);
      }
    }
    float b2v[8], swv[8];
#pragma unroll
    for (int ni = 0; ni < 8; ++ni) {
      int c = ni * 16 + l15;
      b2v[ni] = b2[c];
      swv[ni] = seW[c];
    }
    float seb0 = seb[0];
    float gate[4];
#pragma unroll
    for (int r = 0; r < 4; ++r) {
      float p = 0.f;
#pragma unroll
      for (int ni = 0; ni < 8; ++ni) p += (acc[ni][r] + b2v[ni]) * swv[ni];
      p += __shfl_xor(p, 1, 64);
      p += __shfl_xor(p, 2, 64);
      p += __shfl_xor(p, 4, 64);
      p += __shfl_xor(p, 8, 64);
      gate[r] = 1.f / (1.f + expf(-(p + seb0)));
    }
#pragma unroll
    for (int ni = 0; ni < 8; ++ni) {
      float s = 0.f, sq = 0.f, mx = -1e30f, mn = 1e30f;
#pragma unroll
      for (int r = 0; r < 4; ++r) {
        float v = (acc[ni][r] + b2v[ni]) * gate[r];
        s += v; sq += v * v; mx = fmaxf(mx, v); mn = fminf(mn, v);
      }
      s += __shfl_xor(s, 16, 64); sq += __shfl_xor(sq, 16, 64);
      mx = fmaxf(mx, __shfl_xor(mx, 16, 64)); mn = fminf(mn, __shfl_xor(mn, 16, 64));
      s += __shfl_xor(s, 32, 64); sq += __shfl_xor(sq, 32, 64);
      mx = fmaxf(mx, __shfl_xor(mx, 32, 64)); mn = fminf(mn, __shfl_xor(mn, 32, 64));
      if (quad == 0) {
        int c = ni * 16 + l15;
        float mean = s * 0.0625f;
        float var = relu_f(sq * 0.0625f - mean * mean);
        size_t base = (size_t)node * 1024 + 512 + c;
        aggp[base] = bf16rn(mean);
        aggp[base + 128] = bf16rn(mx);
        aggp[base + 256] = bf16rn(mn);
        aggp[base + 384] = bf16rn(sqrtf(var + 1e-5f));
      }
    }
  }
}

// ---------------- vector GEMM (readout MLP + node input projection) -------------------
template <bool RELU, bool RESID>
__global__ __launch_bounds__(256) void gemm_rrr(
    const float* __restrict__ X, int xstride, const float* __restrict__ W,
    const float* __restrict__ bias, const float* __restrict__ resid, int rstride,
    float* __restrict__ Y, int ystride, int Ktot) {
  __shared__ __align__(16) float Xs[32][68];
  __shared__ __align__(16) float Ws[64][128];
  int tid = threadIdx.x;
  int row0 = blockIdx.x * 32;
  int rg = tid >> 5;
  int c0 = (tid & 31) * 4;
  float acc[4][4] = {};
  for (int kb = 0; kb < Ktot; kb += 64) {
    __syncthreads();
    for (int i = tid; i < 32 * 64; i += 256) {
      int r = i >> 6, k = i & 63;
      Xs[r][k] = X[(size_t)(row0 + r) * xstride + kb + k];
    }
    for (int i = tid; i < 64 * 128; i += 256) {
      int k = i >> 7, c = i & 127;
      Ws[k][c] = W[(size_t)(kb + k) * 128 + c];
    }
    __syncthreads();
#pragma unroll
    for (int k4 = 0; k4 < 16; ++k4) {
      float4 w0 = *(const float4*)&Ws[k4 * 4 + 0][c0];
      float4 w1 = *(const float4*)&Ws[k4 * 4 + 1][c0];
      float4 w2 = *(const float4*)&Ws[k4 * 4 + 2][c0];
      float4 w3 = *(const float4*)&Ws[k4 * 4 + 3][c0];
#pragma unroll
      for (int r = 0; r < 4; ++r) {
        float4 x = *(const float4*)&Xs[rg * 4 + r][k4 * 4];
        acc[r][0] += x.x * w0.x + x.y * w1.x + x.z * w2.x + x.w * w3.x;
        acc[r][1] += x.x * w0.y + x.y * w1.y + x.z * w2.y + x.w * w3.y;
        acc[r][2] += x.x * w0.z + x.y * w1.z + x.z * w2.z + x.w * w3.z;
        acc[r][3] += x.x * w0.w + x.y * w1.w + x.z * w2.w + x.w * w3.w;
      }
    }
  }
  float bj[4] = {0.f, 0.f, 0.f, 0.f};
  if (bias) {
    bj[0] = bias[c0]; bj[1] = bias[c0 + 1]; bj[2] = bias[c0 + 2]; bj[3] = bias[c0 + 3];
  }
#pragma unroll
  for (int r = 0; r < 4; ++r) {
    int row = row0 + rg * 4 + r;
    float4 o;
    float* po = &o.x;
#pragma unroll
    for (int j = 0; j < 4; ++j) {
      float v = acc[r][j] + bj[j];
      if (RESID) v += resid[(size_t)row * rstride + c0 + j];
      if (RELU) v = relu_f(v);
      po[j] = v;
    }
    *(float4*)&Y[(size_t)row * ystride + c0] = o;
  }
}

// ---------------- readout + final ----------------------------------------------------
__global__ __launch_bounds__(128) void readout_kernel(const float* __restrict__ nodeout,
                                                      float* __restrict__ r) {
  int g = blockIdx.x, c = threadIdx.x;
  float s = 0.f, mx = -1e30f;
  for (int i = 0; i < 100; ++i) {
    float v = nodeout[(size_t)(g * 100 + i) * 128 + c];
    s += v; mx = fmaxf(mx, v);
  }
  r[g * 384 + c] = s;
  r[g * 384 + 128 + c] = s * 0.01f;
  r[g * 384 + 256 + c] = mx;
}

__global__ __launch_bounds__(256) void final_kernel(const float* __restrict__ roh,
                                                    const float* __restrict__ W2,
                                                    const float* __restrict__ b2,
                                                    float* __restrict__ out) {
  int idx = blockIdx.x * 256 + threadIdx.x;  // 4096
  int g = idx >> 5, c = idx & 31;
  float acc = b2[c];
  for (int k = 0; k < 128; ++k) acc += roh[g * 128 + k] * W2[k * 32 + c];
  out[idx] = acc;
}

extern "C" void kernel_launch(void* const* d_in, const int* in_sizes, int n_in,
                              void* d_out, int out_size, void* d_ws, size_t ws_size,
                              hipStream_t stream) {
  const float* node_feat = (const float*)d_in[0];
  const float* edge_feat = (const float*)d_in[1];
  const int* bond_src = (const int*)d_in[2];
  const int* comp_src = (const int*)d_in[4];
  const float* in_W = (const float*)d_in[7];
  const float* in_b = (const float*)d_in[8];
  const float* ein_W = (const float*)d_in[9];
  const float* ein_b = (const float*)d_in[10];
  const float* pre_W = (const float*)d_in[11];
  const float* pre_b = (const float*)d_in[12];
  const float* pc_W1 = (const float*)d_in[13];
  const float* pc_b1 = (const float*)d_in[14];
  const float* pc_W2 = (const float*)d_in[15];
  const float* pc_b2 = (const float*)d_in[16];
  const float* se_W = (const float*)d_in[17];
  const float* se_b = (const float*)d_in[18];
  const float* post_W = (const float*)d_in[19];
  const float* post_b = (const float*)d_in[20];
  const float* outn_W1 = (const float*)d_in[21];
  const float* outn_b1 = (const float*)d_in[22];
  const float* outn_W2 = (const float*)d_in[23];
  const float* outn_b2 = (const float*)d_in[24];
  const float* ro_W1 = (const float*)d_in[25];
  const float* ro_b1 = (const float*)d_in[26];
  const float* ro_W2 = (const float*)d_in[27];
  const float* ro_b2 = (const float*)d_in[28];

  float* ws = (float*)d_ws;
  float* hbuf = ws;                                    // 1,638,400
  float* hnew = ws + 1638400;                          // 1,638,400
  unsigned short* hcatp = (unsigned short*)(ws + 3276800);  // [12800][1024] ushort
  unsigned short* efph = (unsigned short*)(ws + 9830400);   // [51200][128] ushort
                                                       //   (ends at fl 13,107,200)
  unsigned short* hp16 = (unsigned short*)(ws + 13107200);  // [12800][512] ushort
                                                       //   (3,276,800 fl, ends 16,384,000)
  float* partials = ws + 16384000;                     // 3 x 1,638,400 fp32 split-K
  unsigned short* wb = (unsigned short*)(ws + 22937600);    // 2,523,136 ushort
  float* tmp1 = ws + 24199168;                         // 1,638,400 (planesA in layers;
                                                       //   outn stage after)
  float* nodeout = ws + 25837568;                      // 1,638,400 (planesB in layers)
  float* rbuf = ws + 27475968;                         // 49,152 (biasf in layers)
  float* roh = ws + 27525120;                          // 16,384
  float* biasf = rbuf;                                 // [5][512] during layer loop only
  unsigned short* pAh = (unsigned short*)tmp1;         // [12800][128]
  unsigned short* pAl = pAh + 1638400;
  unsigned short* pBh = (unsigned short*)nodeout;
  unsigned short* pBl = pBh + 1638400;

  // node proj: tiled vector GEMM, then split to bf16 hi/lo planes
  gemm_rrr<true, false><<<400, 256, 0, stream>>>(node_feat, 64, in_W, in_b, nullptr, 0,
                                                 hbuf, 128, 64);
  h2planes<<<1600, 256, 0, stream>>>(hbuf, pAh, pAl);
  // edge proj: tiled, K=16 unrolled, bf16 hi plane only
  edge_proj_kernel<<<1600, 256, 0, stream>>>(edge_feat, ein_W, ein_b, efph);
  fold_kernel<<<4928, 256, 0, stream>>>(pre_W, pc_W1, pc_W2, post_W, outn_W1, outn_W2, wb);
  bias_kernel<<<10, 256, 0, stream>>>(pre_b, pc_b1, biasf);

  float* cur = hbuf;
  float* nxt = hnew;
  unsigned short *curh = pAh, *curl = pAl, *nxth = pBh, *nxtl = pBl;
  for (int l = 0; l < 5; ++l) {
    size_t lb = (size_t)l * 491520;
    const unsigned short* hpT_h = wb + lb;
    const unsigned short* hpT_l = wb + lb + 65536;
    const unsigned short* WcT_h = wb + lb + 131072;
    const unsigned short* W2T_h = wb + lb + 163840;
    const unsigned short* WfT_h = wb + lb + 196608;
    const unsigned short* WfT_l = wb + lb + 344064;

    mgemm<64, 1, false, false, false, 1, 1><<<dim3(200, 4), 256, 0, stream>>>(
        nullptr, 0, curh, curl, 128, 128, nullptr, 0, hpT_h, hpT_l,
        biasf + l * 512, nullptr, 0, nullptr, 512, hp16, nullptr, 128);
    bondcomp_mfma<<<2000, 512, 0, stream>>>(efph, hp16, WcT_h, W2T_h,
                                            pc_b2 + l * 128, se_W + l * 128, se_b + l,
                                            bond_src, comp_src, hcatp);
    // post-GEMM split-K=3: partials, then fused reduce (+bias+resid+planes)
    mgemm<32, 2, false, false, false, 3, 0><<<dim3(400, 3), 256, 0, stream>>>(
        nullptr, 0, curh, curl, 128, 128, hcatp, 1024, WfT_h, WfT_l,
        nullptr, nullptr, 0, partials, 128, nullptr, nullptr, 1152);
    ksplit_reduce<<<1600, 256, 0, stream>>>(partials, post_b + l * 128, cur,
                                            nxt, nxth, nxtl);
    float* t = cur; cur = nxt; nxt = t;
    unsigned short* th = curh; curh = nxth; nxth = th;
    unsigned short* tl = curl; curl = nxtl; nxtl = tl;
  }
  mgemm<32, 0, true, false, false, 1, 0><<<dim3(400, 1), 256, 0, stream>>>(
      cur, 128, nullptr, nullptr, 0, 128, nullptr, 0, wb + 2457600, wb + 2473984,
      outn_b1, nullptr, 0, tmp1, 128, nullptr, nullptr, 128);
  mgemm<32, 0, false, false, false, 1, 0><<<dim3(400, 1), 256, 0, stream>>>(
      tmp1, 128, nullptr, nullptr, 0, 128, nullptr, 0, wb + 2490368, wb + 2506752,
      outn_b2, nullptr, 0, nodeout, 128, nullptr, nullptr, 128);
  readout_kernel<<<GRAPHS, 128, 0, stream>>>(nodeout, rbuf);
  gemm_rrr<true, false><<<4, 256, 0, stream>>>(rbuf, 384, ro_W1, ro_b1, nullptr, 0,
                                               roh, 128, 384);
  final_kernel<<<16, 256, 0, stream>>>(roh, ro_W2, ro_b2, (float*)d_out);
}

// Round 22
// 596.819 us; speedup vs baseline: 1.2621x; 1.0315x over previous
//
#include <hip/hip_runtime.h>
#include <math.h>

// PNA-EGNN forward, MI355X, round 22 (resubmit of r21; broker failure, code unchanged):
//  - hproj mgemm HIONLY: output is bf16 (hp16) since r19, so the 3-MFMA split ladder
//    is precision-wasted there. A-hi x B-hi only -> 1 MFMA/k-block, no Al/Bl staging.
//    Applied ONLY to hproj (post/outn keep full split: they feed fp32 residual/readout).
//  - r20 base: no setprio; hp16[12800][512] bf16; bondcomp single-tile; split-K post.
// hcat agg plane stored as bf16-hi ushort [12800][1024]: [aggB(512)|aggC(512)].

#define N_NODES 12800
#define GRAPHS 128

typedef __attribute__((ext_vector_type(8))) short short8;
typedef __attribute__((ext_vector_type(4))) float f32x4;
#define MFMA16(a, b, c) __builtin_amdgcn_mfma_f32_16x16x32_bf16(a, b, c, 0, 0, 0)

static __device__ __forceinline__ float relu_f(float v) { return v > 0.0f ? v : 0.0f; }

static __device__ __forceinline__ unsigned short bf16rn(float x) {
  union { float f; unsigned u; } a; a.f = x;
  return (unsigned short)((a.u + 0x7fffu + ((a.u >> 16) & 1u)) >> 16);
}
static __device__ __forceinline__ float bf16tof(unsigned short h) {
  union { unsigned u; float f; } a; a.u = ((unsigned)h) << 16;
  return a.f;
}
static __device__ __forceinline__ void cvt_hl(float x, unsigned short& h, unsigned short& l) {
  h = bf16rn(x);
  l = bf16rn(x - bf16tof(h));
}

// packed 2xbf16 conversion: v_cvt_pk_bf16_f32 (no builtin on gfx950 -> inline asm)
static __device__ __forceinline__ unsigned pk2(float a, float b) {
  unsigned r;
  asm("v_cvt_pk_bf16_f32 %0, %1, %2" : "=v"(r) : "v"(a), "v"(b));
  return r;
}
static __device__ __forceinline__ float pk_lo_f(unsigned p) {
  union { unsigned u; float f; } a; a.u = p << 16; return a.f;
}
static __device__ __forceinline__ float pk_hi_f(unsigned p) {
  union { unsigned u; float f; } a; a.u = p & 0xffff0000u; return a.f;
}
// float4 -> hi-plane uint2 (4 bf16) + lo-plane uint2 (residuals)
static __device__ __forceinline__ void cvt4(float4 v, uint2& h, uint2& l) {
  h.x = pk2(v.x, v.y);
  h.y = pk2(v.z, v.w);
  l.x = pk2(v.x - pk_lo_f(h.x), v.y - pk_hi_f(h.x));
  l.y = pk2(v.z - pk_lo_f(h.y), v.w - pk_hi_f(h.y));
}

union U16 {
  uint4 u4;
  uint2 u2[2];
  short8 s8;
};
static __device__ __forceinline__ short8 mk_s8(uint2 a, uint2 b) {
  U16 t; t.u2[0] = a; t.u2[1] = b; return t.s8;
}
static __device__ __forceinline__ short8 ld_s8(const uint4* p) {
  U16 t; t.u4 = *p; return t.s8;
}

// Stage 128x128 ushort hi-plane into fragment-major LDS (2048 uint4 slots = 32KB):
// slot = (ni*4+kb)*64 + quad*16 + l15
template <int NT>
static __device__ __forceinline__ void stage_Bh(
    const unsigned short* __restrict__ Wh, uint4* __restrict__ Bf, int tid) {
  uint4 tmp[2048 / NT];
#pragma unroll
  for (int i = 0; i < 2048 / NT; ++i) {
    int slot = tid + i * NT;
    int l15n = slot & 15;
    int quad_s = (slot >> 4) & 3;
    int kbni = slot >> 6;
    int kb_s = kbni & 3;
    int ni_s = kbni >> 2;
    int n = ni_s * 16 + l15n;
    int k8 = kb_s * 4 + quad_s;
    tmp[i] = *(const uint4*)&Wh[n * 128 + k8 * 8];
  }
#pragma unroll
  for (int i = 0; i < 2048 / NT; ++i) Bf[tid + i * NT] = tmp[i];
}

// ---------------- fp32 [12800][128] -> bf16 hi/lo planes ------------------------------
__global__ __launch_bounds__(256) void h2planes(
    const float* __restrict__ X, unsigned short* __restrict__ Yh,
    unsigned short* __restrict__ Yl) {
  int idx = blockIdx.x * 256 + threadIdx.x;  // 409600 float4s
  float4 v = *(const float4*)&X[(size_t)idx * 4];
  uint2 h, l;
  cvt4(v, h, l);
  *(uint2*)&Yh[(size_t)idx * 4] = h;
  *(uint2*)&Yl[(size_t)idx * 4] = l;
}

// ---------------- split-K reduce: Y = p0+p1+p2 + bias + resid; planes out -------------
__global__ __launch_bounds__(256) void ksplit_reduce(
    const float* __restrict__ p, const float* __restrict__ bias,
    const float* __restrict__ resid, float* __restrict__ Y,
    unsigned short* __restrict__ Yh, unsigned short* __restrict__ Yl) {
  int idx = blockIdx.x * 256 + threadIdx.x;  // 409600 float4s
  const float4* p4 = (const float4*)p;
  float4 a = p4[idx];
  float4 b = p4[idx + 409600];
  float4 c = p4[idx + 819200];
  float4 rr = *(const float4*)&resid[(size_t)idx * 4];
  float4 bb = *(const float4*)&bias[(idx & 31) * 4];
  float4 v;
  v.x = a.x + b.x + c.x + rr.x + bb.x;
  v.y = a.y + b.y + c.y + rr.y + bb.y;
  v.z = a.z + b.z + c.z + rr.z + bb.z;
  v.w = a.w + b.w + c.w + rr.w + bb.w;
  *(float4*)&Y[(size_t)idx * 4] = v;
  uint2 h, l;
  cvt4(v, h, l);
  ((uint2*)Yh)[idx] = h;
  ((uint2*)Yl)[idx] = l;
}

// ---------------- edge input projection, tiled: Yh = bf16hi(relu(X@W + b)) ------------
// X [51200][16], W [16][128]. 32 rows/block, 16 outputs/thread, K=16 unrolled.
__global__ __launch_bounds__(256) void edge_proj_kernel(
    const float* __restrict__ X, const float* __restrict__ W,
    const float* __restrict__ bias, unsigned short* __restrict__ Yh) {
  __shared__ float Xs[32][17];
  __shared__ float Ws[16][128];
  int tid = threadIdx.x;
  int row0 = blockIdx.x * 32;
  for (int i = tid; i < 512; i += 256) {
    int r = i >> 4, k = i & 15;
    Xs[r][k] = X[(size_t)(row0 + r) * 16 + k];
  }
  for (int i = tid; i < 2048; i += 256) Ws[i >> 7][i & 127] = W[i];
  __syncthreads();
  int rg = tid >> 5;         // 4 rows each
  int c0 = (tid & 31) * 4;   // 4 cols
  float bj0 = bias[c0], bj1 = bias[c0 + 1], bj2 = bias[c0 + 2], bj3 = bias[c0 + 3];
#pragma unroll
  for (int rr = 0; rr < 4; ++rr) {
    int r = rg * 4 + rr;
    float a0 = bj0, a1 = bj1, a2 = bj2, a3 = bj3;
#pragma unroll
    for (int k = 0; k < 16; ++k) {
      float x = Xs[r][k];
      float4 w = *(const float4*)&Ws[k][c0];
      a0 += x * w.x; a1 += x * w.y; a2 += x * w.z; a3 += x * w.w;
    }
    uint2 h;
    h.x = pk2(relu_f(a0), relu_f(a1));
    h.y = pk2(relu_f(a2), relu_f(a3));
    *(uint2*)&Yh[(size_t)(row0 + r) * 128 + c0] = h;
  }
}

// ---------------- per-layer hproj bias: [5][512] = [0 | pre_b | 0 | pc_b1] ------------
__global__ __launch_bounds__(256) void bias_kernel(
    const float* __restrict__ pre_b, const float* __restrict__ pc_b1,
    float* __restrict__ biasf) {
  int idx = blockIdx.x * 256 + threadIdx.x;  // 2560
  if (idx >= 2560) return;
  int l = idx >> 9, c = idx & 511;
  float v = 0.f;
  if (c >= 128 && c < 256) v = pre_b[l * 128 + (c - 128)];
  else if (c >= 384) v = pc_b1[l * 128 + (c - 384)];
  biasf[idx] = v;
}

// ---------------- weight prep: fold scalers + transpose + hi/lo split -----------
// ushort plane offsets (per layer stride 491520):
//  hprojT_hi 0 / lo 65536           [512][128]
//  WcT_hi 131072 / lo 147456        [128][128]
//  W2T_hi 163840 / lo 180224        [128][128]
//  WfoldT_hi 196608 / lo 344064     [128][1152]
//  outn1T_hi 2457600 / lo 2473984; outn2T_hi 2490368 / lo 2506752
__global__ __launch_bounds__(256) void fold_kernel(
    const float* __restrict__ pre_W, const float* __restrict__ pc_W1,
    const float* __restrict__ pc_W2, const float* __restrict__ post_W,
    const float* __restrict__ outn_W1, const float* __restrict__ outn_W2,
    unsigned short* __restrict__ wb) {
  int idx = blockIdx.x * 256 + threadIdx.x;  // 1,261,568 total
  const float C1 = 1.6094379124341003f;   // log 5
  const float C2 = 2.8332133440562162f;   // log 17
  float val;
  size_t ohi, olo;
  if (idx < 1228800) {
    int l = idx / 245760;
    int r = idx % 245760;
    size_t lb = (size_t)l * 491520;
    if (r < 65536) {  // hprojT [n=512][k=128]
      int n = r >> 7, k = r & 127;
      if (n < 128) val = pre_W[(size_t)l * 49152 + k * 128 + n];
      else if (n < 256) val = pre_W[(size_t)l * 49152 + (128 + k) * 128 + (n - 128)];
      else if (n < 384) val = pc_W1[(size_t)l * 32768 + k * 128 + (n - 256)];
      else val = pc_W1[(size_t)l * 32768 + (128 + k) * 128 + (n - 384)];
      ohi = lb + r; olo = ohi + 65536;
    } else if (r < 81920) {  // WcT
      int r2 = r - 65536; int n = r2 >> 7, k = r2 & 127;
      val = pre_W[(size_t)l * 49152 + (256 + k) * 128 + n];
      ohi = lb + 131072 + r2; olo = ohi + 16384;
    } else if (r < 98304) {  // W2T
      int r2 = r - 81920; int n = r2 >> 7, k = r2 & 127;
      val = pc_W2[(size_t)l * 16384 + k * 128 + n];
      ohi = lb + 163840 + r2; olo = ohi + 16384;
    } else {  // WfoldT [n=128][kk=1152]
      int r2 = r - 98304;
      int n = r2 / 1152, kk = r2 % 1152;
      const float* Wl = post_W + (size_t)l * 409600;
      if (kk < 128) val = Wl[kk * 128 + n];
      else if (kk < 640) {
        int j = kk - 128;
        val = Wl[(128 + j) * 128 + n] + C1 * Wl[(640 + j) * 128 + n] +
              (1.0f / C1) * Wl[(1152 + j) * 128 + n];
      } else {
        int j = kk - 640;
        val = Wl[(1664 + j) * 128 + n] + C2 * Wl[(2176 + j) * 128 + n] +
              (1.0f / C2) * Wl[(2688 + j) * 128 + n];
      }
      ohi = lb + 196608 + r2; olo = ohi + 147456;
    }
  } else {
    int r = idx - 1228800;
    if (r < 16384) {
      int n = r >> 7, k = r & 127;
      val = outn_W1[k * 128 + n];
      ohi = 2457600 + r; olo = ohi + 16384;
    } else {
      int r2 = r - 16384; int n = r2 >> 7, k = r2 & 127;
      val = outn_W2[k * 128 + n];
      ohi = 2490368 + r2; olo = ohi + 16384;
    }
  }
  unsigned short h, l2;
  cvt_hl(val, h, l2);
  wb[ohi] = h;
  wb[olo] = l2;
}

// ---------------- dense MFMA GEMM: Y[M,ntot] = X @ Wt^T (+bias)(+resid)(relu) ---------
// 256 threads / 4 waves; wave w owns cols [w*32, w*32+32).
// AMODE 0: A from fp32 X0 (cvt4).  AMODE 1: A from hi/lo planes.
// AMODE 2: k<K0 from hi/lo planes, k>=K0 from X1h (hi only).
// WPLANES: epilogue also emits Y as bf16 hi/lo planes (stride 128).
// KSPLIT>1: blockIdx.y = k-chunk; writes raw fp32 partials.
// PROJ=1: ALL cols -> bf16-hi Yh[row*512+col].
// HIONLY=1: A-hi x B-hi only (1 MFMA/k-block, no Al/Bl) — for bf16-output GEMMs.
template <int BM, int AMODE, bool RELU, bool RESID, bool WPLANES, int KSPLIT, int PROJ,
          int HIONLY>
__global__ __launch_bounds__(256) void mgemm(
    const float* __restrict__ X0, int xs0,
    const unsigned short* __restrict__ Ah, const unsigned short* __restrict__ Al,
    int ahs, int K0,
    const unsigned short* __restrict__ X1h, int xs1,
    const unsigned short* __restrict__ Wth, const unsigned short* __restrict__ Wtl,
    const float* __restrict__ bias, const float* __restrict__ resid, int rstride,
    float* __restrict__ Y, int ystride,
    unsigned short* __restrict__ Yh, unsigned short* __restrict__ Yl, int K) {
  __shared__ unsigned short As_h[BM][40], As_l[HIONLY ? 1 : BM][40];
  __shared__ unsigned short Bs_h[128][40], Bs_l[HIONLY ? 1 : 128][40];
  int tid = threadIdx.x;
  int wave = tid >> 6, lane = tid & 63, quad = lane >> 4, l15 = lane & 15;
  int row0 = blockIdx.x * BM;
  int n0, kbeg, kend;
  float* Yout = Y;
  if (KSPLIT > 1) {
    n0 = 0;
    int kc = K / KSPLIT;
    kbeg = blockIdx.y * kc;
    kend = kbeg + kc;
    Yout = Y + (size_t)blockIdx.y * N_NODES * 128;
  } else {
    n0 = blockIdx.y * 128;
    kbeg = 0;
    kend = K;
  }
  f32x4 acc[BM / 16][2];
#pragma unroll
  for (int mi = 0; mi < BM / 16; ++mi)
#pragma unroll
    for (int ni = 0; ni < 2; ++ni) acc[mi][ni] = (f32x4){0.f, 0.f, 0.f, 0.f};
  for (int kb = kbeg; kb < kend; kb += 32) {
    if (kb != kbeg) __syncthreads();
    bool haslo = (!HIONLY) && ((AMODE != 2) || (kb < K0));
    if (AMODE == 0) {
      for (int i = tid; i < BM * 8; i += 256) {
        int r = i >> 3, kq = i & 7;
        float4 v = *(const float4*)&X0[(size_t)(row0 + r) * xs0 + kb + kq * 4];
        uint2 th, tl;
        cvt4(v, th, tl);
        *(uint2*)&As_h[r][kq * 4] = th;
        *(uint2*)&As_l[r][kq * 4] = tl;
      }
    } else if (HIONLY) {
      for (int i = tid; i < BM * 4; i += 256) {
        int r = i >> 2, q = i & 3;
        *(uint4*)&As_h[r][q * 8] =
            *(const uint4*)&Ah[(size_t)(row0 + r) * ahs + kb + q * 8];
      }
    } else if (haslo) {
      for (int i = tid; i < BM * 4; i += 256) {
        int r = i >> 2, q = i & 3;
        size_t o = (size_t)(row0 + r) * ahs + kb + q * 8;
        *(uint4*)&As_h[r][q * 8] = *(const uint4*)&Ah[o];
        *(uint4*)&As_l[r][q * 8] = *(const uint4*)&Al[o];
      }
    } else {
      for (int i = tid; i < BM * 4; i += 256) {
        int r = i >> 2, q = i & 3;
        *(uint4*)&As_h[r][q * 8] =
            *(const uint4*)&X1h[(size_t)(row0 + r) * xs1 + (kb - K0) + q * 8];
      }
    }
    for (int i = tid; i < 512; i += 256) {
      int r = i >> 2, q = i & 3;
      size_t o = (size_t)(n0 + r) * K + kb + q * 8;
      *(uint4*)&Bs_h[r][q * 8] = *(const uint4*)&Wth[o];
      if (!HIONLY) *(uint4*)&Bs_l[r][q * 8] = *(const uint4*)&Wtl[o];
    }
    __syncthreads();
    short8 bh[2], bl[2], ah[BM / 16], al[BM / 16];
#pragma unroll
    for (int ni = 0; ni < 2; ++ni) {
      bh[ni] = *(const short8*)&Bs_h[wave * 32 + ni * 16 + l15][quad * 8];
      if (!HIONLY) bl[ni] = *(const short8*)&Bs_l[wave * 32 + ni * 16 + l15][quad * 8];
    }
#pragma unroll
    for (int mi = 0; mi < BM / 16; ++mi)
      ah[mi] = *(const short8*)&As_h[mi * 16 + l15][quad * 8];
    if (haslo) {
#pragma unroll
      for (int mi = 0; mi < BM / 16; ++mi)
        al[mi] = *(const short8*)&As_l[mi * 16 + l15][quad * 8];
    }
#pragma unroll
    for (int mi = 0; mi < BM / 16; ++mi)
#pragma unroll
      for (int ni = 0; ni < 2; ++ni) {
        acc[mi][ni] = MFMA16(ah[mi], bh[ni], acc[mi][ni]);
        if (!HIONLY) acc[mi][ni] = MFMA16(ah[mi], bl[ni], acc[mi][ni]);
      }
    if (haslo) {
#pragma unroll
      for (int mi = 0; mi < BM / 16; ++mi)
#pragma unroll
        for (int ni = 0; ni < 2; ++ni)
          acc[mi][ni] = MFMA16(al[mi], bh[ni], acc[mi][ni]);
    }
  }
#pragma unroll
  for (int mi = 0; mi < BM / 16; ++mi)
#pragma unroll
    for (int ni = 0; ni < 2; ++ni) {
      int col = n0 + wave * 32 + ni * 16 + l15;
      if (KSPLIT > 1) {
#pragma unroll
        for (int r = 0; r < 4; ++r) {
          int row = row0 + mi * 16 + quad * 4 + r;
          Yout[(size_t)row * ystride + col] = acc[mi][ni][r];
        }
      } else if (PROJ == 1) {
        float bj = bias ? bias[col] : 0.f;
#pragma unroll
        for (int r = 0; r < 4; ++r) {
          int row = row0 + mi * 16 + quad * 4 + r;
          float v = acc[mi][ni][r] + bj;
          Yh[(size_t)row * 512 + col] = bf16rn(v);
        }
      } else {
        float bj = bias ? bias[col] : 0.f;
#pragma unroll
        for (int r = 0; r < 4; ++r) {
          int row = row0 + mi * 16 + quad * 4 + r;
          float v = acc[mi][ni][r] + bj;
          if (RESID) v += resid[(size_t)row * rstride + col];
          if (RELU) v = relu_f(v);
          Y[(size_t)row * ystride + col] = v;
          if (WPLANES) {
            unsigned short hh, ll;
            cvt_hl(v, hh, ll);
            Yh[(size_t)row * 128 + col] = hh;
            Yl[(size_t)row * 128 + col] = ll;
          }
        }
      }
    }
}

// ---------------- fused bond+comp: one dispatch, 2000 blocks --------------------------
// Blocks [0,400): bond path (128 bond edges each). Blocks [400,2000): comp path
// (128 comp edges each). Both: 512 thr / 8 waves x 16 edges, B-hi panel in 32KB
// fragment-major LDS, A bf16-hi in regs, 32 MFMA/wave, wave-local epilogues.
// hp16 bf16-hi [12800][512] holds all hproj columns.
#define BOND_BLOCKS 400
__global__ __launch_bounds__(512, 4) void bondcomp_mfma(
    const unsigned short* __restrict__ efph,
    const unsigned short* __restrict__ hp16,
    const unsigned short* __restrict__ Wch, const unsigned short* __restrict__ W2h,
    const float* __restrict__ b2,
    const float* __restrict__ seW, const float* __restrict__ seb,
    const int* __restrict__ bond_src, const int* __restrict__ comp_src,
    unsigned short* __restrict__ aggp) {
  __shared__ uint4 Bf[2048];  // 32KB fragment-major B hi
  int tid = threadIdx.x;
  int wave = tid >> 6, lane = tid & 63, quad = lane >> 4, l15 = lane & 15;
  if (blockIdx.x < BOND_BLOCKS) {
    // ---------------- bond path ----------------
    int e0 = blockIdx.x * 128;
    int ew = e0 + wave * 16;
    short8 ah[4];
#pragma unroll
    for (int kb = 0; kb < 4; ++kb) {
      size_t o = (size_t)(ew + l15) * 128 + kb * 32 + quad * 8;
      ah[kb] = ld_s8((const uint4*)&efph[o]);
    }
    stage_Bh<512>(Wch, Bf, tid);
    __syncthreads();
    f32x4 acc[8];
#pragma unroll
    for (int ni = 0; ni < 8; ++ni) acc[ni] = (f32x4){0.f, 0.f, 0.f, 0.f};
#pragma unroll
    for (int kb = 0; kb < 4; ++kb) {
#pragma unroll
      for (int ni = 0; ni < 8; ++ni) {
        short8 bh = ld_s8(&Bf[(ni * 4 + kb) * 64 + lane]);
        acc[ni] = MFMA16(ah[kb], bh, acc[ni]);
      }
    }
    int node = (ew >> 2) + quad;
    int src_r[4];
#pragma unroll
    for (int r = 0; r < 4; ++r) src_r[r] = bond_src[ew + quad * 4 + r];
#pragma unroll
    for (int ni = 0; ni < 8; ++ni) {
      int c = ni * 16 + l15;
      float wbv = bf16tof(hp16[(size_t)node * 512 + 128 + c]);  // includes pre_b
      float s = 0.f, sq = 0.f, mx = -1e30f, mn = 1e30f;
#pragma unroll
      for (int r = 0; r < 4; ++r) {
        float v = acc[ni][r] + wbv + bf16tof(hp16[(size_t)src_r[r] * 512 + c]);
        s += v; sq += v * v; mx = fmaxf(mx, v); mn = fminf(mn, v);
      }
      float mean = s * 0.25f;
      float var = relu_f(sq * 0.25f - mean * mean);
      size_t base = (size_t)node * 1024 + c;
      aggp[base] = bf16rn(mean);
      aggp[base + 128] = bf16rn(mx);
      aggp[base + 256] = bf16rn(mn);
      aggp[base + 384] = bf16rn(sqrtf(var + 1e-5f));
    }
  } else {
    // ---------------- comp path ----------------
    int e0 = (blockIdx.x - BOND_BLOCKS) * 128;
    int e = e0 + wave * 16 + l15;
    int src = comp_src[e];
    int node = e >> 4;  // same node for whole wave
    const unsigned short* pa = hp16 + (size_t)src * 512 + 256;   // hA cols 256-383
    const unsigned short* pb = hp16 + (size_t)node * 512 + 384;  // hB' cols 384-511
    short8 ah[4];
#pragma unroll
    for (int kb = 0; kb < 4; ++kb) {
      int k0 = kb * 32 + quad * 8;
      uint4 ua = *(const uint4*)&pa[k0];
      uint4 ub = *(const uint4*)&pb[k0];
      uint2 h0, h1;
      h0.x = pk2(relu_f(pk_lo_f(ua.x) + pk_lo_f(ub.x)),
                 relu_f(pk_hi_f(ua.x) + pk_hi_f(ub.x)));
      h0.y = pk2(relu_f(pk_lo_f(ua.y) + pk_lo_f(ub.y)),
                 relu_f(pk_hi_f(ua.y) + pk_hi_f(ub.y)));
      h1.x = pk2(relu_f(pk_lo_f(ua.z) + pk_lo_f(ub.z)),
                 relu_f(pk_hi_f(ua.z) + pk_hi_f(ub.z)));
      h1.y = pk2(relu_f(pk_lo_f(ua.w) + pk_lo_f(ub.w)),
                 relu_f(pk_hi_f(ua.w) + pk_hi_f(ub.w)));
      ah[kb] = mk_s8(h0, h1);
    }
    stage_Bh<512>(W2h, Bf, tid);
    __syncthreads();
    f32x4 acc[8];
#pragma unroll
    for (int ni = 0; ni < 8; ++ni) acc[ni] = (f32x4){0.f, 0.f, 0.f, 0.f};
#pragma unroll
    for (int kb = 0; kb < 4; ++kb) {
#pragma unroll
      for (int ni = 0; ni < 8; ++ni) {
        short8 bh = ld_s8(&Bf[(ni * 4 + kb) * 64 + lane]);
        acc[ni] = MFMA16(ah[kb], bh, acc[ni]);
      }
    }
    float b2v[8], swv[8];
#pragma unroll
    for (int ni = 0; ni < 8; ++ni) {
      int c = ni * 16 + l15;
      b2v[ni] = b2[c];
      swv[ni] = seW[c];
    }
    float seb0 = seb[0];
    float gate[4];
#pragma unroll
    for (int r = 0; r < 4; ++r) {
      float p = 0.f;
#pragma unroll
      for (int ni = 0; ni < 8; ++ni) p += (acc[ni][r] + b2v[ni]) * swv[ni];
      p += __shfl_xor(p, 1, 64);
      p += __shfl_xor(p, 2, 64);
      p += __shfl_xor(p, 4, 64);
      p += __shfl_xor(p, 8, 64);
      gate[r] = 1.f / (1.f + expf(-(p + seb0)));
    }
#pragma unroll
    for (int ni = 0; ni < 8; ++ni) {
      float s = 0.f, sq = 0.f, mx = -1e30f, mn = 1e30f;
#pragma unroll
      for (int r = 0; r < 4; ++r) {
        float v = (acc[ni][r] + b2v[ni]) * gate[r];
        s += v; sq += v * v; mx = fmaxf(mx, v); mn = fminf(mn, v);
      }
      s += __shfl_xor(s, 16, 64); sq += __shfl_xor(sq, 16, 64);
      mx = fmaxf(mx, __shfl_xor(mx, 16, 64)); mn = fminf(mn, __shfl_xor(mn, 16, 64));
      s += __shfl_xor(s, 32, 64); sq += __shfl_xor(sq, 32, 64);
      mx = fmaxf(mx, __shfl_xor(mx, 32, 64)); mn = fminf(mn, __shfl_xor(mn, 32, 64));
      if (quad == 0) {
        int c = ni * 16 + l15;
        float mean = s * 0.0625f;
        float var = relu_f(sq * 0.0625f - mean * mean);
        size_t base = (size_t)node * 1024 + 512 + c;
        aggp[base] = bf16rn(mean);
        aggp[base + 128] = bf16rn(mx);
        aggp[base + 256] = bf16rn(mn);
        aggp[base + 384] = bf16rn(sqrtf(var + 1e-5f));
      }
    }
  }
}

// ---------------- vector GEMM (readout MLP + node input projection) -------------------
template <bool RELU, bool RESID>
__global__ __launch_bounds__(256) void gemm_rrr(
    const float* __restrict__ X, int xstride, const float* __restrict__ W,
    const float* __restrict__ bias, const float* __restrict__ resid, int rstride,
    float* __restrict__ Y, int ystride, int Ktot) {
  __shared__ __align__(16) float Xs[32][68];
  __shared__ __align__(16) float Ws[64][128];
  int tid = threadIdx.x;
  int row0 = blockIdx.x * 32;
  int rg = tid >> 5;
  int c0 = (tid & 31) * 4;
  float acc[4][4] = {};
  for (int kb = 0; kb < Ktot; kb += 64) {
    __syncthreads();
    for (int i = tid; i < 32 * 64; i += 256) {
      int r = i >> 6, k = i & 63;
      Xs[r][k] = X[(size_t)(row0 + r) * xstride + kb + k];
    }
    for (int i = tid; i < 64 * 128; i += 256) {
      int k = i >> 7, c = i & 127;
      Ws[k][c] = W[(size_t)(kb + k) * 128 + c];
    }
    __syncthreads();
#pragma unroll
    for (int k4 = 0; k4 < 16; ++k4) {
      float4 w0 = *(const float4*)&Ws[k4 * 4 + 0][c0];
      float4 w1 = *(const float4*)&Ws[k4 * 4 + 1][c0];
      float4 w2 = *(const float4*)&Ws[k4 * 4 + 2][c0];
      float4 w3 = *(const float4*)&Ws[k4 * 4 + 3][c0];
#pragma unroll
      for (int r = 0; r < 4; ++r) {
        float4 x = *(const float4*)&Xs[rg * 4 + r][k4 * 4];
        acc[r][0] += x.x * w0.x + x.y * w1.x + x.z * w2.x + x.w * w3.x;
        acc[r][1] += x.x * w0.y + x.y * w1.y + x.z * w2.y + x.w * w3.y;
        acc[r][2] += x.x * w0.z + x.y * w1.z + x.z * w2.z + x.w * w3.z;
        acc[r][3] += x.x * w0.w + x.y * w1.w + x.z * w2.w + x.w * w3.w;
      }
    }
  }
  float bj[4] = {0.f, 0.f, 0.f, 0.f};
  if (bias) {
    bj[0] = bias[c0]; bj[1] = bias[c0 + 1]; bj[2] = bias[c0 + 2]; bj[3] = bias[c0 + 3];
  }
#pragma unroll
  for (int r = 0; r < 4; ++r) {
    int row = row0 + rg * 4 + r;
    float4 o;
    float* po = &o.x;
#pragma unroll
    for (int j = 0; j < 4; ++j) {
      float v = acc[r][j] + bj[j];
      if (RESID) v += resid[(size_t)row * rstride + c0 + j];
      if (RELU) v = relu_f(v);
      po[j] = v;
    }
    *(float4*)&Y[(size_t)row * ystride + c0] = o;
  }
}

// ---------------- readout + final ----------------------------------------------------
__global__ __launch_bounds__(128) void readout_kernel(const float* __restrict__ nodeout,
                                                      float* __restrict__ r) {
  int g = blockIdx.x, c = threadIdx.x;
  float s = 0.f, mx = -1e30f;
  for (int i = 0; i < 100; ++i) {
    float v = nodeout[(size_t)(g * 100 + i) * 128 + c];
    s += v; mx = fmaxf(mx, v);
  }
  r[g * 384 + c] = s;
  r[g * 384 + 128 + c] = s * 0.01f;
  r[g * 384 + 256 + c] = mx;
}

__global__ __launch_bounds__(256) void final_kernel(const float* __restrict__ roh,
                                                    const float* __restrict__ W2,
                                                    const float* __restrict__ b2,
                                                    float* __restrict__ out) {
  int idx = blockIdx.x * 256 + threadIdx.x;  // 4096
  int g = idx >> 5, c = idx & 31;
  float acc = b2[c];
  for (int k = 0; k < 128; ++k) acc += roh[g * 128 + k] * W2[k * 32 + c];
  out[idx] = acc;
}

extern "C" void kernel_launch(void* const* d_in, const int* in_sizes, int n_in,
                              void* d_out, int out_size, void* d_ws, size_t ws_size,
                              hipStream_t stream) {
  const float* node_feat = (const float*)d_in[0];
  const float* edge_feat = (const float*)d_in[1];
  const int* bond_src = (const int*)d_in[2];
  const int* comp_src = (const int*)d_in[4];
  const float* in_W = (const float*)d_in[7];
  const float* in_b = (const float*)d_in[8];
  const float* ein_W = (const float*)d_in[9];
  const float* ein_b = (const float*)d_in[10];
  const float* pre_W = (const float*)d_in[11];
  const float* pre_b = (const float*)d_in[12];
  const float* pc_W1 = (const float*)d_in[13];
  const float* pc_b1 = (const float*)d_in[14];
  const float* pc_W2 = (const float*)d_in[15];
  const float* pc_b2 = (const float*)d_in[16];
  const float* se_W = (const float*)d_in[17];
  const float* se_b = (const float*)d_in[18];
  const float* post_W = (const float*)d_in[19];
  const float* post_b = (const float*)d_in[20];
  const float* outn_W1 = (const float*)d_in[21];
  const float* outn_b1 = (const float*)d_in[22];
  const float* outn_W2 = (const float*)d_in[23];
  const float* outn_b2 = (const float*)d_in[24];
  const float* ro_W1 = (const float*)d_in[25];
  const float* ro_b1 = (const float*)d_in[26];
  const float* ro_W2 = (const float*)d_in[27];
  const float* ro_b2 = (const float*)d_in[28];

  float* ws = (float*)d_ws;
  float* hbuf = ws;                                    // 1,638,400
  float* hnew = ws + 1638400;                          // 1,638,400
  unsigned short* hcatp = (unsigned short*)(ws + 3276800);  // [12800][1024] ushort
  unsigned short* efph = (unsigned short*)(ws + 9830400);   // [51200][128] ushort
                                                       //   (ends at fl 13,107,200)
  unsigned short* hp16 = (unsigned short*)(ws + 13107200);  // [12800][512] ushort
                                                       //   (3,276,800 fl, ends 16,384,000)
  float* partials = ws + 16384000;                     // 3 x 1,638,400 fp32 split-K
  unsigned short* wb = (unsigned short*)(ws + 22937600);    // 2,523,136 ushort
  float* tmp1 = ws + 24199168;                         // 1,638,400 (planesA in layers;
                                                       //   outn stage after)
  float* nodeout = ws + 25837568;                      // 1,638,400 (planesB in layers)
  float* rbuf = ws + 27475968;                         // 49,152 (biasf in layers)
  float* roh = ws + 27525120;                          // 16,384
  float* biasf = rbuf;                                 // [5][512] during layer loop only
  unsigned short* pAh = (unsigned short*)tmp1;         // [12800][128]
  unsigned short* pAl = pAh + 1638400;
  unsigned short* pBh = (unsigned short*)nodeout;
  unsigned short* pBl = pBh + 1638400;

  // node proj: tiled vector GEMM, then split to bf16 hi/lo planes
  gemm_rrr<true, false><<<400, 256, 0, stream>>>(node_feat, 64, in_W, in_b, nullptr, 0,
                                                 hbuf, 128, 64);
  h2planes<<<1600, 256, 0, stream>>>(hbuf, pAh, pAl);
  // edge proj: tiled, K=16 unrolled, bf16 hi plane only
  edge_proj_kernel<<<1600, 256, 0, stream>>>(edge_feat, ein_W, ein_b, efph);
  fold_kernel<<<4928, 256, 0, stream>>>(pre_W, pc_W1, pc_W2, post_W, outn_W1, outn_W2, wb);
  bias_kernel<<<10, 256, 0, stream>>>(pre_b, pc_b1, biasf);

  float* cur = hbuf;
  float* nxt = hnew;
  unsigned short *curh = pAh, *curl = pAl, *nxth = pBh, *nxtl = pBl;
  for (int l = 0; l < 5; ++l) {
    size_t lb = (size_t)l * 491520;
    const unsigned short* hpT_h = wb + lb;
    const unsigned short* hpT_l = wb + lb + 65536;
    const unsigned short* WcT_h = wb + lb + 131072;
    const unsigned short* W2T_h = wb + lb + 163840;
    const unsigned short* WfT_h = wb + lb + 196608;
    const unsigned short* WfT_l = wb + lb + 344064;

    mgemm<64, 1, false, false, false, 1, 1, 1><<<dim3(200, 4), 256, 0, stream>>>(
        nullptr, 0, curh, curl, 128, 128, nullptr, 0, hpT_h, hpT_l,
        biasf + l * 512, nullptr, 0, nullptr, 512, hp16, nullptr, 128);
    bondcomp_mfma<<<2000, 512, 0, stream>>>(efph, hp16, WcT_h, W2T_h,
                                            pc_b2 + l * 128, se_W + l * 128, se_b + l,
                                            bond_src, comp_src, hcatp);
    // post-GEMM split-K=3: partials, then fused reduce (+bias+resid+planes)
    mgemm<32, 2, false, false, false, 3, 0, 0><<<dim3(400, 3), 256, 0, stream>>>(
        nullptr, 0, curh, curl, 128, 128, hcatp, 1024, WfT_h, WfT_l,
        nullptr, nullptr, 0, partials, 128, nullptr, nullptr, 1152);
    ksplit_reduce<<<1600, 256, 0, stream>>>(partials, post_b + l * 128, cur,
                                            nxt, nxth, nxtl);
    float* t = cur; cur = nxt; nxt = t;
    unsigned short* th = curh; curh = nxth; nxth = th;
    unsigned short* tl = curl; curl = nxtl; nxtl = tl;
  }
  mgemm<32, 0, true, false, false, 1, 0, 0><<<dim3(400, 1), 256, 0, stream>>>(
      cur, 128, nullptr, nullptr, 0, 128, nullptr, 0, wb + 2457600, wb + 2473984,
      outn_b1, nullptr, 0, tmp1, 128, nullptr, nullptr, 128);
  mgemm<32, 0, false, false, false, 1, 0, 0><<<dim3(400, 1), 256, 0, stream>>>(
      tmp1, 128, nullptr, nullptr, 0, 128, nullptr, 0, wb + 2490368, wb + 2506752,
      outn_b2, nullptr, 0, nodeout, 128, nullptr, nullptr, 128);
  readout_kernel<<<GRAPHS, 128, 0, stream>>>(nodeout, rbuf);
  gemm_rrr<true, false><<<4, 256, 0, stream>>>(rbuf, 384, ro_W1, ro_b1, nullptr, 0,
                                               roh, 128, 384);
  final_kernel<<<16, 256, 0, stream>>>(roh, ro_W2, ro_b2, (float*)d_out);
}

// Round 23
// 576.762 us; speedup vs baseline: 1.3060x; 1.0348x over previous
//
#include <hip/hip_runtime.h>
#include <math.h>

// PNA-EGNN forward, MI355X, round 23:
//  - post-GEMM HCHI: for k>=128 (hcat segment), A is already bf16-hi only, so B-lo
//    refinement is precision-wasted. Skip Bs_l staging + ah*bl MFMA there
//    (76->44 MFMA/layer-tile). k<128 (h segment) keeps full 3-MFMA split.
//  - r22 base: hproj HIONLY; hp16[12800][512] bf16; bondcomp single-tile; no setprio.
// hcat agg plane stored as bf16-hi ushort [12800][1024]: [aggB(512)|aggC(512)].

#define N_NODES 12800
#define GRAPHS 128

typedef __attribute__((ext_vector_type(8))) short short8;
typedef __attribute__((ext_vector_type(4))) float f32x4;
#define MFMA16(a, b, c) __builtin_amdgcn_mfma_f32_16x16x32_bf16(a, b, c, 0, 0, 0)

static __device__ __forceinline__ float relu_f(float v) { return v > 0.0f ? v : 0.0f; }

static __device__ __forceinline__ unsigned short bf16rn(float x) {
  union { float f; unsigned u; } a; a.f = x;
  return (unsigned short)((a.u + 0x7fffu + ((a.u >> 16) & 1u)) >> 16);
}
static __device__ __forceinline__ float bf16tof(unsigned short h) {
  union { unsigned u; float f; } a; a.u = ((unsigned)h) << 16;
  return a.f;
}
static __device__ __forceinline__ void cvt_hl(float x, unsigned short& h, unsigned short& l) {
  h = bf16rn(x);
  l = bf16rn(x - bf16tof(h));
}

// packed 2xbf16 conversion: v_cvt_pk_bf16_f32 (no builtin on gfx950 -> inline asm)
static __device__ __forceinline__ unsigned pk2(float a, float b) {
  unsigned r;
  asm("v_cvt_pk_bf16_f32 %0, %1, %2" : "=v"(r) : "v"(a), "v"(b));
  return r;
}
static __device__ __forceinline__ float pk_lo_f(unsigned p) {
  union { unsigned u; float f; } a; a.u = p << 16; return a.f;
}
static __device__ __forceinline__ float pk_hi_f(unsigned p) {
  union { unsigned u; float f; } a; a.u = p & 0xffff0000u; return a.f;
}
// float4 -> hi-plane uint2 (4 bf16) + lo-plane uint2 (residuals)
static __device__ __forceinline__ void cvt4(float4 v, uint2& h, uint2& l) {
  h.x = pk2(v.x, v.y);
  h.y = pk2(v.z, v.w);
  l.x = pk2(v.x - pk_lo_f(h.x), v.y - pk_hi_f(h.x));
  l.y = pk2(v.z - pk_lo_f(h.y), v.w - pk_hi_f(h.y));
}

union U16 {
  uint4 u4;
  uint2 u2[2];
  short8 s8;
};
static __device__ __forceinline__ short8 mk_s8(uint2 a, uint2 b) {
  U16 t; t.u2[0] = a; t.u2[1] = b; return t.s8;
}
static __device__ __forceinline__ short8 ld_s8(const uint4* p) {
  U16 t; t.u4 = *p; return t.s8;
}

// Stage 128x128 ushort hi-plane into fragment-major LDS (2048 uint4 slots = 32KB):
// slot = (ni*4+kb)*64 + quad*16 + l15
template <int NT>
static __device__ __forceinline__ void stage_Bh(
    const unsigned short* __restrict__ Wh, uint4* __restrict__ Bf, int tid) {
  uint4 tmp[2048 / NT];
#pragma unroll
  for (int i = 0; i < 2048 / NT; ++i) {
    int slot = tid + i * NT;
    int l15n = slot & 15;
    int quad_s = (slot >> 4) & 3;
    int kbni = slot >> 6;
    int kb_s = kbni & 3;
    int ni_s = kbni >> 2;
    int n = ni_s * 16 + l15n;
    int k8 = kb_s * 4 + quad_s;
    tmp[i] = *(const uint4*)&Wh[n * 128 + k8 * 8];
  }
#pragma unroll
  for (int i = 0; i < 2048 / NT; ++i) Bf[tid + i * NT] = tmp[i];
}

// ---------------- fp32 [12800][128] -> bf16 hi/lo planes ------------------------------
__global__ __launch_bounds__(256) void h2planes(
    const float* __restrict__ X, unsigned short* __restrict__ Yh,
    unsigned short* __restrict__ Yl) {
  int idx = blockIdx.x * 256 + threadIdx.x;  // 409600 float4s
  float4 v = *(const float4*)&X[(size_t)idx * 4];
  uint2 h, l;
  cvt4(v, h, l);
  *(uint2*)&Yh[(size_t)idx * 4] = h;
  *(uint2*)&Yl[(size_t)idx * 4] = l;
}

// ---------------- split-K reduce: Y = p0+p1+p2 + bias + resid; planes out -------------
__global__ __launch_bounds__(256) void ksplit_reduce(
    const float* __restrict__ p, const float* __restrict__ bias,
    const float* __restrict__ resid, float* __restrict__ Y,
    unsigned short* __restrict__ Yh, unsigned short* __restrict__ Yl) {
  int idx = blockIdx.x * 256 + threadIdx.x;  // 409600 float4s
  const float4* p4 = (const float4*)p;
  float4 a = p4[idx];
  float4 b = p4[idx + 409600];
  float4 c = p4[idx + 819200];
  float4 rr = *(const float4*)&resid[(size_t)idx * 4];
  float4 bb = *(const float4*)&bias[(idx & 31) * 4];
  float4 v;
  v.x = a.x + b.x + c.x + rr.x + bb.x;
  v.y = a.y + b.y + c.y + rr.y + bb.y;
  v.z = a.z + b.z + c.z + rr.z + bb.z;
  v.w = a.w + b.w + c.w + rr.w + bb.w;
  *(float4*)&Y[(size_t)idx * 4] = v;
  uint2 h, l;
  cvt4(v, h, l);
  ((uint2*)Yh)[idx] = h;
  ((uint2*)Yl)[idx] = l;
}

// ---------------- edge input projection, tiled: Yh = bf16hi(relu(X@W + b)) ------------
// X [51200][16], W [16][128]. 32 rows/block, 16 outputs/thread, K=16 unrolled.
__global__ __launch_bounds__(256) void edge_proj_kernel(
    const float* __restrict__ X, const float* __restrict__ W,
    const float* __restrict__ bias, unsigned short* __restrict__ Yh) {
  __shared__ float Xs[32][17];
  __shared__ float Ws[16][128];
  int tid = threadIdx.x;
  int row0 = blockIdx.x * 32;
  for (int i = tid; i < 512; i += 256) {
    int r = i >> 4, k = i & 15;
    Xs[r][k] = X[(size_t)(row0 + r) * 16 + k];
  }
  for (int i = tid; i < 2048; i += 256) Ws[i >> 7][i & 127] = W[i];
  __syncthreads();
  int rg = tid >> 5;         // 4 rows each
  int c0 = (tid & 31) * 4;   // 4 cols
  float bj0 = bias[c0], bj1 = bias[c0 + 1], bj2 = bias[c0 + 2], bj3 = bias[c0 + 3];
#pragma unroll
  for (int rr = 0; rr < 4; ++rr) {
    int r = rg * 4 + rr;
    float a0 = bj0, a1 = bj1, a2 = bj2, a3 = bj3;
#pragma unroll
    for (int k = 0; k < 16; ++k) {
      float x = Xs[r][k];
      float4 w = *(const float4*)&Ws[k][c0];
      a0 += x * w.x; a1 += x * w.y; a2 += x * w.z; a3 += x * w.w;
    }
    uint2 h;
    h.x = pk2(relu_f(a0), relu_f(a1));
    h.y = pk2(relu_f(a2), relu_f(a3));
    *(uint2*)&Yh[(size_t)(row0 + r) * 128 + c0] = h;
  }
}

// ---------------- per-layer hproj bias: [5][512] = [0 | pre_b | 0 | pc_b1] ------------
__global__ __launch_bounds__(256) void bias_kernel(
    const float* __restrict__ pre_b, const float* __restrict__ pc_b1,
    float* __restrict__ biasf) {
  int idx = blockIdx.x * 256 + threadIdx.x;  // 2560
  if (idx >= 2560) return;
  int l = idx >> 9, c = idx & 511;
  float v = 0.f;
  if (c >= 128 && c < 256) v = pre_b[l * 128 + (c - 128)];
  else if (c >= 384) v = pc_b1[l * 128 + (c - 384)];
  biasf[idx] = v;
}

// ---------------- weight prep: fold scalers + transpose + hi/lo split -----------
// ushort plane offsets (per layer stride 491520):
//  hprojT_hi 0 / lo 65536           [512][128]
//  WcT_hi 131072 / lo 147456        [128][128]
//  W2T_hi 163840 / lo 180224        [128][128]
//  WfoldT_hi 196608 / lo 344064     [128][1152]
//  outn1T_hi 2457600 / lo 2473984; outn2T_hi 2490368 / lo 2506752
__global__ __launch_bounds__(256) void fold_kernel(
    const float* __restrict__ pre_W, const float* __restrict__ pc_W1,
    const float* __restrict__ pc_W2, const float* __restrict__ post_W,
    const float* __restrict__ outn_W1, const float* __restrict__ outn_W2,
    unsigned short* __restrict__ wb) {
  int idx = blockIdx.x * 256 + threadIdx.x;  // 1,261,568 total
  const float C1 = 1.6094379124341003f;   // log 5
  const float C2 = 2.8332133440562162f;   // log 17
  float val;
  size_t ohi, olo;
  if (idx < 1228800) {
    int l = idx / 245760;
    int r = idx % 245760;
    size_t lb = (size_t)l * 491520;
    if (r < 65536) {  // hprojT [n=512][k=128]
      int n = r >> 7, k = r & 127;
      if (n < 128) val = pre_W[(size_t)l * 49152 + k * 128 + n];
      else if (n < 256) val = pre_W[(size_t)l * 49152 + (128 + k) * 128 + (n - 128)];
      else if (n < 384) val = pc_W1[(size_t)l * 32768 + k * 128 + (n - 256)];
      else val = pc_W1[(size_t)l * 32768 + (128 + k) * 128 + (n - 384)];
      ohi = lb + r; olo = ohi + 65536;
    } else if (r < 81920) {  // WcT
      int r2 = r - 65536; int n = r2 >> 7, k = r2 & 127;
      val = pre_W[(size_t)l * 49152 + (256 + k) * 128 + n];
      ohi = lb + 131072 + r2; olo = ohi + 16384;
    } else if (r < 98304) {  // W2T
      int r2 = r - 81920; int n = r2 >> 7, k = r2 & 127;
      val = pc_W2[(size_t)l * 16384 + k * 128 + n];
      ohi = lb + 163840 + r2; olo = ohi + 16384;
    } else {  // WfoldT [n=128][kk=1152]
      int r2 = r - 98304;
      int n = r2 / 1152, kk = r2 % 1152;
      const float* Wl = post_W + (size_t)l * 409600;
      if (kk < 128) val = Wl[kk * 128 + n];
      else if (kk < 640) {
        int j = kk - 128;
        val = Wl[(128 + j) * 128 + n] + C1 * Wl[(640 + j) * 128 + n] +
              (1.0f / C1) * Wl[(1152 + j) * 128 + n];
      } else {
        int j = kk - 640;
        val = Wl[(1664 + j) * 128 + n] + C2 * Wl[(2176 + j) * 128 + n] +
              (1.0f / C2) * Wl[(2688 + j) * 128 + n];
      }
      ohi = lb + 196608 + r2; olo = ohi + 147456;
    }
  } else {
    int r = idx - 1228800;
    if (r < 16384) {
      int n = r >> 7, k = r & 127;
      val = outn_W1[k * 128 + n];
      ohi = 2457600 + r; olo = ohi + 16384;
    } else {
      int r2 = r - 16384; int n = r2 >> 7, k = r2 & 127;
      val = outn_W2[k * 128 + n];
      ohi = 2490368 + r2; olo = ohi + 16384;
    }
  }
  unsigned short h, l2;
  cvt_hl(val, h, l2);
  wb[ohi] = h;
  wb[olo] = l2;
}

// ---------------- dense MFMA GEMM: Y[M,ntot] = X @ Wt^T (+bias)(+resid)(relu) ---------
// 256 threads / 4 waves; wave w owns cols [w*32, w*32+32).
// AMODE 0: A from fp32 X0 (cvt4).  AMODE 1: A from hi/lo planes.
// AMODE 2: k<K0 from hi/lo planes, k>=K0 from X1h (hi only).
// WPLANES: epilogue also emits Y as bf16 hi/lo planes (stride 128).
// KSPLIT>1: blockIdx.y = k-chunk; writes raw fp32 partials.
// PROJ=1: ALL cols -> bf16-hi Yh[row*512+col].
// HIONLY=1: A-hi x B-hi only (1 MFMA/k-block, no Al/Bl) — for bf16-output GEMMs.
// HCHI=1: for k>=K0 (AMODE 2 hcat segment) drop B-lo too (A there is hi-only).
template <int BM, int AMODE, bool RELU, bool RESID, bool WPLANES, int KSPLIT, int PROJ,
          int HIONLY, int HCHI>
__global__ __launch_bounds__(256) void mgemm(
    const float* __restrict__ X0, int xs0,
    const unsigned short* __restrict__ Ah, const unsigned short* __restrict__ Al,
    int ahs, int K0,
    const unsigned short* __restrict__ X1h, int xs1,
    const unsigned short* __restrict__ Wth, const unsigned short* __restrict__ Wtl,
    const float* __restrict__ bias, const float* __restrict__ resid, int rstride,
    float* __restrict__ Y, int ystride,
    unsigned short* __restrict__ Yh, unsigned short* __restrict__ Yl, int K) {
  __shared__ unsigned short As_h[BM][40], As_l[HIONLY ? 1 : BM][40];
  __shared__ unsigned short Bs_h[128][40], Bs_l[HIONLY ? 1 : 128][40];
  int tid = threadIdx.x;
  int wave = tid >> 6, lane = tid & 63, quad = lane >> 4, l15 = lane & 15;
  int row0 = blockIdx.x * BM;
  int n0, kbeg, kend;
  float* Yout = Y;
  if (KSPLIT > 1) {
    n0 = 0;
    int kc = K / KSPLIT;
    kbeg = blockIdx.y * kc;
    kend = kbeg + kc;
    Yout = Y + (size_t)blockIdx.y * N_NODES * 128;
  } else {
    n0 = blockIdx.y * 128;
    kbeg = 0;
    kend = K;
  }
  f32x4 acc[BM / 16][2];
#pragma unroll
  for (int mi = 0; mi < BM / 16; ++mi)
#pragma unroll
    for (int ni = 0; ni < 2; ++ni) acc[mi][ni] = (f32x4){0.f, 0.f, 0.f, 0.f};
  for (int kb = kbeg; kb < kend; kb += 32) {
    if (kb != kbeg) __syncthreads();
    bool haslo = (!HIONLY) && ((AMODE != 2) || (kb < K0));
    bool hasblo = (!HIONLY) && ((!HCHI) || (AMODE != 2) || (kb < K0));
    if (AMODE == 0) {
      for (int i = tid; i < BM * 8; i += 256) {
        int r = i >> 3, kq = i & 7;
        float4 v = *(const float4*)&X0[(size_t)(row0 + r) * xs0 + kb + kq * 4];
        uint2 th, tl;
        cvt4(v, th, tl);
        *(uint2*)&As_h[r][kq * 4] = th;
        *(uint2*)&As_l[r][kq * 4] = tl;
      }
    } else if (HIONLY) {
      for (int i = tid; i < BM * 4; i += 256) {
        int r = i >> 2, q = i & 3;
        *(uint4*)&As_h[r][q * 8] =
            *(const uint4*)&Ah[(size_t)(row0 + r) * ahs + kb + q * 8];
      }
    } else if (haslo) {
      for (int i = tid; i < BM * 4; i += 256) {
        int r = i >> 2, q = i & 3;
        size_t o = (size_t)(row0 + r) * ahs + kb + q * 8;
        *(uint4*)&As_h[r][q * 8] = *(const uint4*)&Ah[o];
        *(uint4*)&As_l[r][q * 8] = *(const uint4*)&Al[o];
      }
    } else {
      for (int i = tid; i < BM * 4; i += 256) {
        int r = i >> 2, q = i & 3;
        *(uint4*)&As_h[r][q * 8] =
            *(const uint4*)&X1h[(size_t)(row0 + r) * xs1 + (kb - K0) + q * 8];
      }
    }
    for (int i = tid; i < 512; i += 256) {
      int r = i >> 2, q = i & 3;
      size_t o = (size_t)(n0 + r) * K + kb + q * 8;
      *(uint4*)&Bs_h[r][q * 8] = *(const uint4*)&Wth[o];
      if (!HIONLY && hasblo) *(uint4*)&Bs_l[r][q * 8] = *(const uint4*)&Wtl[o];
    }
    __syncthreads();
    short8 bh[2], bl[2], ah[BM / 16], al[BM / 16];
#pragma unroll
    for (int ni = 0; ni < 2; ++ni) {
      bh[ni] = *(const short8*)&Bs_h[wave * 32 + ni * 16 + l15][quad * 8];
      if (!HIONLY && hasblo)
        bl[ni] = *(const short8*)&Bs_l[wave * 32 + ni * 16 + l15][quad * 8];
    }
#pragma unroll
    for (int mi = 0; mi < BM / 16; ++mi)
      ah[mi] = *(const short8*)&As_h[mi * 16 + l15][quad * 8];
    if (haslo) {
#pragma unroll
      for (int mi = 0; mi < BM / 16; ++mi)
        al[mi] = *(const short8*)&As_l[mi * 16 + l15][quad * 8];
    }
#pragma unroll
    for (int mi = 0; mi < BM / 16; ++mi)
#pragma unroll
      for (int ni = 0; ni < 2; ++ni) {
        acc[mi][ni] = MFMA16(ah[mi], bh[ni], acc[mi][ni]);
        if (!HIONLY) {
          if (hasblo) acc[mi][ni] = MFMA16(ah[mi], bl[ni], acc[mi][ni]);
        }
      }
    if (haslo) {
#pragma unroll
      for (int mi = 0; mi < BM / 16; ++mi)
#pragma unroll
        for (int ni = 0; ni < 2; ++ni)
          acc[mi][ni] = MFMA16(al[mi], bh[ni], acc[mi][ni]);
    }
  }
#pragma unroll
  for (int mi = 0; mi < BM / 16; ++mi)
#pragma unroll
    for (int ni = 0; ni < 2; ++ni) {
      int col = n0 + wave * 32 + ni * 16 + l15;
      if (KSPLIT > 1) {
#pragma unroll
        for (int r = 0; r < 4; ++r) {
          int row = row0 + mi * 16 + quad * 4 + r;
          Yout[(size_t)row * ystride + col] = acc[mi][ni][r];
        }
      } else if (PROJ == 1) {
        float bj = bias ? bias[col] : 0.f;
#pragma unroll
        for (int r = 0; r < 4; ++r) {
          int row = row0 + mi * 16 + quad * 4 + r;
          float v = acc[mi][ni][r] + bj;
          Yh[(size_t)row * 512 + col] = bf16rn(v);
        }
      } else {
        float bj = bias ? bias[col] : 0.f;
#pragma unroll
        for (int r = 0; r < 4; ++r) {
          int row = row0 + mi * 16 + quad * 4 + r;
          float v = acc[mi][ni][r] + bj;
          if (RESID) v += resid[(size_t)row * rstride + col];
          if (RELU) v = relu_f(v);
          Y[(size_t)row * ystride + col] = v;
          if (WPLANES) {
            unsigned short hh, ll;
            cvt_hl(v, hh, ll);
            Yh[(size_t)row * 128 + col] = hh;
            Yl[(size_t)row * 128 + col] = ll;
          }
        }
      }
    }
}

// ---------------- fused bond+comp: one dispatch, 2000 blocks --------------------------
// Blocks [0,400): bond path (128 bond edges each). Blocks [400,2000): comp path
// (128 comp edges each). Both: 512 thr / 8 waves x 16 edges, B-hi panel in 32KB
// fragment-major LDS, A bf16-hi in regs, 32 MFMA/wave, wave-local epilogues.
// hp16 bf16-hi [12800][512] holds all hproj columns.
#define BOND_BLOCKS 400
__global__ __launch_bounds__(512, 4) void bondcomp_mfma(
    const unsigned short* __restrict__ efph,
    const unsigned short* __restrict__ hp16,
    const unsigned short* __restrict__ Wch, const unsigned short* __restrict__ W2h,
    const float* __restrict__ b2,
    const float* __restrict__ seW, const float* __restrict__ seb,
    const int* __restrict__ bond_src, const int* __restrict__ comp_src,
    unsigned short* __restrict__ aggp) {
  __shared__ uint4 Bf[2048];  // 32KB fragment-major B hi
  int tid = threadIdx.x;
  int wave = tid >> 6, lane = tid & 63, quad = lane >> 4, l15 = lane & 15;
  if (blockIdx.x < BOND_BLOCKS) {
    // ---------------- bond path ----------------
    int e0 = blockIdx.x * 128;
    int ew = e0 + wave * 16;
    short8 ah[4];
#pragma unroll
    for (int kb = 0; kb < 4; ++kb) {
      size_t o = (size_t)(ew + l15) * 128 + kb * 32 + quad * 8;
      ah[kb] = ld_s8((const uint4*)&efph[o]);
    }
    stage_Bh<512>(Wch, Bf, tid);
    __syncthreads();
    f32x4 acc[8];
#pragma unroll
    for (int ni = 0; ni < 8; ++ni) acc[ni] = (f32x4){0.f, 0.f, 0.f, 0.f};
#pragma unroll
    for (int kb = 0; kb < 4; ++kb) {
#pragma unroll
      for (int ni = 0; ni < 8; ++ni) {
        short8 bh = ld_s8(&Bf[(ni * 4 + kb) * 64 + lane]);
        acc[ni] = MFMA16(ah[kb], bh, acc[ni]);
      }
    }
    int node = (ew >> 2) + quad;
    int src_r[4];
#pragma unroll
    for (int r = 0; r < 4; ++r) src_r[r] = bond_src[ew + quad * 4 + r];
#pragma unroll
    for (int ni = 0; ni < 8; ++ni) {
      int c = ni * 16 + l15;
      float wbv = bf16tof(hp16[(size_t)node * 512 + 128 + c]);  // includes pre_b
      float s = 0.f, sq = 0.f, mx = -1e30f, mn = 1e30f;
#pragma unroll
      for (int r = 0; r < 4; ++r) {
        float v = acc[ni][r] + wbv + bf16tof(hp16[(size_t)src_r[r] * 512 + c]);
        s += v; sq += v * v; mx = fmaxf(mx, v); mn = fminf(mn, v);
      }
      float mean = s * 0.25f;
      float var = relu_f(sq * 0.25f - mean * mean);
      size_t base = (size_t)node * 1024 + c;
      aggp[base] = bf16rn(mean);
      aggp[base + 128] = bf16rn(mx);
      aggp[base + 256] = bf16rn(mn);
      aggp[base + 384] = bf16rn(sqrtf(var + 1e-5f));
    }
  } else {
    // ---------------- comp path ----------------
    int e0 = (blockIdx.x - BOND_BLOCKS) * 128;
    int e = e0 + wave * 16 + l15;
    int src = comp_src[e];
    int node = e >> 4;  // same node for whole wave
    const unsigned short* pa = hp16 + (size_t)src * 512 + 256;   // hA cols 256-383
    const unsigned short* pb = hp16 + (size_t)node * 512 + 384;  // hB' cols 384-511
    short8 ah[4];
#pragma unroll
    for (int kb = 0; kb < 4; ++kb) {
      int k0 = kb * 32 + quad * 8;
      uint4 ua = *(const uint4*)&pa[k0];
      uint4 ub = *(const uint4*)&pb[k0];
      uint2 h0, h1;
      h0.x = pk2(relu_f(pk_lo_f(ua.x) + pk_lo_f(ub.x)),
                 relu_f(pk_hi_f(ua.x) + pk_hi_f(ub.x)));
      h0.y = pk2(relu_f(pk_lo_f(ua.y) + pk_lo_f(ub.y)),
                 relu_f(pk_hi_f(ua.y) + pk_hi_f(ub.y)));
      h1.x = pk2(relu_f(pk_lo_f(ua.z) + pk_lo_f(ub.z)),
                 relu_f(pk_hi_f(ua.z) + pk_hi_f(ub.z)));
      h1.y = pk2(relu_f(pk_lo_f(ua.w) + pk_lo_f(ub.w)),
                 relu_f(pk_hi_f(ua.w) + pk_hi_f(ub.w)));
      ah[kb] = mk_s8(h0, h1);
    }
    stage_Bh<512>(W2h, Bf, tid);
    __syncthreads();
    f32x4 acc[8];
#pragma unroll
    for (int ni = 0; ni < 8; ++ni) acc[ni] = (f32x4){0.f, 0.f, 0.f, 0.f};
#pragma unroll
    for (int kb = 0; kb < 4; ++kb) {
#pragma unroll
      for (int ni = 0; ni < 8; ++ni) {
        short8 bh = ld_s8(&Bf[(ni * 4 + kb) * 64 + lane]);
        acc[ni] = MFMA16(ah[kb], bh, acc[ni]);
      }
    }
    float b2v[8], swv[8];
#pragma unroll
    for (int ni = 0; ni < 8; ++ni) {
      int c = ni * 16 + l15;
      b2v[ni] = b2[c];
      swv[ni] = seW[c];
    }
    float seb0 = seb[0];
    float gate[4];
#pragma unroll
    for (int r = 0; r < 4; ++r) {
      float p = 0.f;
#pragma unroll
      for (int ni = 0; ni < 8; ++ni) p += (acc[ni][r] + b2v[ni]) * swv[ni];
      p += __shfl_xor(p, 1, 64);
      p += __shfl_xor(p, 2, 64);
      p += __shfl_xor(p, 4, 64);
      p += __shfl_xor(p, 8, 64);
      gate[r] = 1.f / (1.f + expf(-(p + seb0)));
    }
#pragma unroll
    for (int ni = 0; ni < 8; ++ni) {
      float s = 0.f, sq = 0.f, mx = -1e30f, mn = 1e30f;
#pragma unroll
      for (int r = 0; r < 4; ++r) {
        float v = (acc[ni][r] + b2v[ni]) * gate[r];
        s += v; sq += v * v; mx = fmaxf(mx, v); mn = fminf(mn, v);
      }
      s += __shfl_xor(s, 16, 64); sq += __shfl_xor(sq, 16, 64);
      mx = fmaxf(mx, __shfl_xor(mx, 16, 64)); mn = fminf(mn, __shfl_xor(mn, 16, 64));
      s += __shfl_xor(s, 32, 64); sq += __shfl_xor(sq, 32, 64);
      mx = fmaxf(mx, __shfl_xor(mx, 32, 64)); mn = fminf(mn, __shfl_xor(mn, 32, 64));
      if (quad == 0) {
        int c = ni * 16 + l15;
        float mean = s * 0.0625f;
        float var = relu_f(sq * 0.0625f - mean * mean);
        size_t base = (size_t)node * 1024 + 512 + c;
        aggp[base] = bf16rn(mean);
        aggp[base + 128] = bf16rn(mx);
        aggp[base + 256] = bf16rn(mn);
        aggp[base + 384] = bf16rn(sqrtf(var + 1e-5f));
      }
    }
  }
}

// ---------------- vector GEMM (readout MLP + node input projection) -------------------
template <bool RELU, bool RESID>
__global__ __launch_bounds__(256) void gemm_rrr(
    const float* __restrict__ X, int xstride, const float* __restrict__ W,
    const float* __restrict__ bias, const float* __restrict__ resid, int rstride,
    float* __restrict__ Y, int ystride, int Ktot) {
  __shared__ __align__(16) float Xs[32][68];
  __shared__ __align__(16) float Ws[64][128];
  int tid = threadIdx.x;
  int row0 = blockIdx.x * 32;
  int rg = tid >> 5;
  int c0 = (tid & 31) * 4;
  float acc[4][4] = {};
  for (int kb = 0; kb < Ktot; kb += 64) {
    __syncthreads();
    for (int i = tid; i < 32 * 64; i += 256) {
      int r = i >> 6, k = i & 63;
      Xs[r][k] = X[(size_t)(row0 + r) * xstride + kb + k];
    }
    for (int i = tid; i < 64 * 128; i += 256) {
      int k = i >> 7, c = i & 127;
      Ws[k][c] = W[(size_t)(kb + k) * 128 + c];
    }
    __syncthreads();
#pragma unroll
    for (int k4 = 0; k4 < 16; ++k4) {
      float4 w0 = *(const float4*)&Ws[k4 * 4 + 0][c0];
      float4 w1 = *(const float4*)&Ws[k4 * 4 + 1][c0];
      float4 w2 = *(const float4*)&Ws[k4 * 4 + 2][c0];
      float4 w3 = *(const float4*)&Ws[k4 * 4 + 3][c0];
#pragma unroll
      for (int r = 0; r < 4; ++r) {
        float4 x = *(const float4*)&Xs[rg * 4 + r][k4 * 4];
        acc[r][0] += x.x * w0.x + x.y * w1.x + x.z * w2.x + x.w * w3.x;
        acc[r][1] += x.x * w0.y + x.y * w1.y + x.z * w2.y + x.w * w3.y;
        acc[r][2] += x.x * w0.z + x.y * w1.z + x.z * w2.z + x.w * w3.z;
        acc[r][3] += x.x * w0.w + x.y * w1.w + x.z * w2.w + x.w * w3.w;
      }
    }
  }
  float bj[4] = {0.f, 0.f, 0.f, 0.f};
  if (bias) {
    bj[0] = bias[c0]; bj[1] = bias[c0 + 1]; bj[2] = bias[c0 + 2]; bj[3] = bias[c0 + 3];
  }
#pragma unroll
  for (int r = 0; r < 4; ++r) {
    int row = row0 + rg * 4 + r;
    float4 o;
    float* po = &o.x;
#pragma unroll
    for (int j = 0; j < 4; ++j) {
      float v = acc[r][j] + bj[j];
      if (RESID) v += resid[(size_t)row * rstride + c0 + j];
      if (RELU) v = relu_f(v);
      po[j] = v;
    }
    *(float4*)&Y[(size_t)row * ystride + c0] = o;
  }
}

// ---------------- readout + final ----------------------------------------------------
__global__ __launch_bounds__(128) void readout_kernel(const float* __restrict__ nodeout,
                                                      float* __restrict__ r) {
  int g = blockIdx.x, c = threadIdx.x;
  float s = 0.f, mx = -1e30f;
  for (int i = 0; i < 100; ++i) {
    float v = nodeout[(size_t)(g * 100 + i) * 128 + c];
    s += v; mx = fmaxf(mx, v);
  }
  r[g * 384 + c] = s;
  r[g * 384 + 128 + c] = s * 0.01f;
  r[g * 384 + 256 + c] = mx;
}

__global__ __launch_bounds__(256) void final_kernel(const float* __restrict__ roh,
                                                    const float* __restrict__ W2,
                                                    const float* __restrict__ b2,
                                                    float* __restrict__ out) {
  int idx = blockIdx.x * 256 + threadIdx.x;  // 4096
  int g = idx >> 5, c = idx & 31;
  float acc = b2[c];
  for (int k = 0; k < 128; ++k) acc += roh[g * 128 + k] * W2[k * 32 + c];
  out[idx] = acc;
}

extern "C" void kernel_launch(void* const* d_in, const int* in_sizes, int n_in,
                              void* d_out, int out_size, void* d_ws, size_t ws_size,
                              hipStream_t stream) {
  const float* node_feat = (const float*)d_in[0];
  const float* edge_feat = (const float*)d_in[1];
  const int* bond_src = (const int*)d_in[2];
  const int* comp_src = (const int*)d_in[4];
  const float* in_W = (const float*)d_in[7];
  const float* in_b = (const float*)d_in[8];
  const float* ein_W = (const float*)d_in[9];
  const float* ein_b = (const float*)d_in[10];
  const float* pre_W = (const float*)d_in[11];
  const float* pre_b = (const float*)d_in[12];
  const float* pc_W1 = (const float*)d_in[13];
  const float* pc_b1 = (const float*)d_in[14];
  const float* pc_W2 = (const float*)d_in[15];
  const float* pc_b2 = (const float*)d_in[16];
  const float* se_W = (const float*)d_in[17];
  const float* se_b = (const float*)d_in[18];
  const float* post_W = (const float*)d_in[19];
  const float* post_b = (const float*)d_in[20];
  const float* outn_W1 = (const float*)d_in[21];
  const float* outn_b1 = (const float*)d_in[22];
  const float* outn_W2 = (const float*)d_in[23];
  const float* outn_b2 = (const float*)d_in[24];
  const float* ro_W1 = (const float*)d_in[25];
  const float* ro_b1 = (const float*)d_in[26];
  const float* ro_W2 = (const float*)d_in[27];
  const float* ro_b2 = (const float*)d_in[28];

  float* ws = (float*)d_ws;
  float* hbuf = ws;                                    // 1,638,400
  float* hnew = ws + 1638400;                          // 1,638,400
  unsigned short* hcatp = (unsigned short*)(ws + 3276800);  // [12800][1024] ushort
  unsigned short* efph = (unsigned short*)(ws + 9830400);   // [51200][128] ushort
                                                       //   (ends at fl 13,107,200)
  unsigned short* hp16 = (unsigned short*)(ws + 13107200);  // [12800][512] ushort
                                                       //   (3,276,800 fl, ends 16,384,000)
  float* partials = ws + 16384000;                     // 3 x 1,638,400 fp32 split-K
  unsigned short* wb = (unsigned short*)(ws + 22937600);    // 2,523,136 ushort
  float* tmp1 = ws + 24199168;                         // 1,638,400 (planesA in layers;
                                                       //   outn stage after)
  float* nodeout = ws + 25837568;                      // 1,638,400 (planesB in layers)
  float* rbuf = ws + 27475968;                         // 49,152 (biasf in layers)
  float* roh = ws + 27525120;                          // 16,384
  float* biasf = rbuf;                                 // [5][512] during layer loop only
  unsigned short* pAh = (unsigned short*)tmp1;         // [12800][128]
  unsigned short* pAl = pAh + 1638400;
  unsigned short* pBh = (unsigned short*)nodeout;
  unsigned short* pBl = pBh + 1638400;

  // node proj: tiled vector GEMM, then split to bf16 hi/lo planes
  gemm_rrr<true, false><<<400, 256, 0, stream>>>(node_feat, 64, in_W, in_b, nullptr, 0,
                                                 hbuf, 128, 64);
  h2planes<<<1600, 256, 0, stream>>>(hbuf, pAh, pAl);
  // edge proj: tiled, K=16 unrolled, bf16 hi plane only
  edge_proj_kernel<<<1600, 256, 0, stream>>>(edge_feat, ein_W, ein_b, efph);
  fold_kernel<<<4928, 256, 0, stream>>>(pre_W, pc_W1, pc_W2, post_W, outn_W1, outn_W2, wb);
  bias_kernel<<<10, 256, 0, stream>>>(pre_b, pc_b1, biasf);

  float* cur = hbuf;
  float* nxt = hnew;
  unsigned short *curh = pAh, *curl = pAl, *nxth = pBh, *nxtl = pBl;
  for (int l = 0; l < 5; ++l) {
    size_t lb = (size_t)l * 491520;
    const unsigned short* hpT_h = wb + lb;
    const unsigned short* hpT_l = wb + lb + 65536;
    const unsigned short* WcT_h = wb + lb + 131072;
    const unsigned short* W2T_h = wb + lb + 163840;
    const unsigned short* WfT_h = wb + lb + 196608;
    const unsigned short* WfT_l = wb + lb + 344064;

    mgemm<64, 1, false, false, false, 1, 1, 1, 0><<<dim3(200, 4), 256, 0, stream>>>(
        nullptr, 0, curh, curl, 128, 128, nullptr, 0, hpT_h, hpT_l,
        biasf + l * 512, nullptr, 0, nullptr, 512, hp16, nullptr, 128);
    bondcomp_mfma<<<2000, 512, 0, stream>>>(efph, hp16, WcT_h, W2T_h,
                                            pc_b2 + l * 128, se_W + l * 128, se_b + l,
                                            bond_src, comp_src, hcatp);
    // post-GEMM split-K=3 (HCHI: hcat segment B-hi only), then fused reduce
    mgemm<32, 2, false, false, false, 3, 0, 0, 1><<<dim3(400, 3), 256, 0, stream>>>(
        nullptr, 0, curh, curl, 128, 128, hcatp, 1024, WfT_h, WfT_l,
        nullptr, nullptr, 0, partials, 128, nullptr, nullptr, 1152);
    ksplit_reduce<<<1600, 256, 0, stream>>>(partials, post_b + l * 128, cur,
                                            nxt, nxth, nxtl);
    float* t = cur; cur = nxt; nxt = t;
    unsigned short* th = curh; curh = nxth; nxth = th;
    unsigned short* tl = curl; curl = nxtl; nxtl = tl;
  }
  mgemm<32, 0, true, false, false, 1, 0, 0, 0><<<dim3(400, 1), 256, 0, stream>>>(
      cur, 128, nullptr, nullptr, 0, 128, nullptr, 0, wb + 2457600, wb + 2473984,
      outn_b1, nullptr, 0, tmp1, 128, nullptr, nullptr, 128);
  mgemm<32, 0, false, false, false, 1, 0, 0, 0><<<dim3(400, 1), 256, 0, stream>>>(
      tmp1, 128, nullptr, nullptr, 0, 128, nullptr, 0, wb + 2490368, wb + 2506752,
      outn_b2, nullptr, 0, nodeout, 128, nullptr, nullptr, 128);
  readout_kernel<<<GRAPHS, 128, 0, stream>>>(nodeout, rbuf);
  gemm_rrr<true, false><<<4, 256, 0, stream>>>(rbuf, 384, ro_W1, ro_b1, nullptr, 0,
                                               roh, 128, 384);
  final_kernel<<<16, 256, 0, stream>>>(roh, ro_W2, ro_b2, (float*)d_out);
}